// Round 2
// baseline (5095.452 us; speedup 1.0000x reference)
//
#include <hip/hip_runtime.h>
#include <math.h>

typedef unsigned int u32;

struct U2 { u32 a, b; };

// Threefry-2x32, 20 rounds — matches jax._src.prng.threefry2x32 exactly.
__host__ __device__ __forceinline__ U2 tf2x32(u32 k0, u32 k1, u32 c0, u32 c1) {
  u32 ks2 = k0 ^ k1 ^ 0x1BD11BDAu;
  u32 x0 = c0 + k0, x1 = c1 + k1;
#define TFR(r) { x0 += x1; x1 = (x1 << (r)) | (x1 >> (32 - (r))); x1 ^= x0; }
  TFR(13) TFR(15) TFR(26) TFR(6)
  x0 += k1; x1 += ks2 + 1u;
  TFR(17) TFR(29) TFR(16) TFR(24)
  x0 += ks2; x1 += k0 + 2u;
  TFR(13) TFR(15) TFR(26) TFR(6)
  x0 += k0; x1 += k1 + 3u;
  TFR(17) TFR(29) TFR(16) TFR(24)
  x0 += k1; x1 += ks2 + 4u;
  TFR(13) TFR(15) TFR(26) TFR(6)
  x0 += ks2; x1 += k0 + 5u;
#undef TFR
  return {x0, x1};
}

// jax_threefry_partitionable=True (default in modern JAX):
// random_bits(key,32,shape)[i] = b1^b2 with (b1,b2)=threefry2x32(key, (hi32(i), lo32(i)))
// split(key,n)[i]              = (b1,b2) at counter i
// All counters in this problem are < 2^32 so hi32 == 0.
__host__ __device__ __forceinline__ u32 prf32(u32 k0, u32 k1, u32 i) {
  U2 r = tf2x32(k0, k1, 0u, i);
  return r.a ^ r.b;
}

__device__ __forceinline__ float u01_from_bits(u32 bits) {
  u32 r = (bits >> 9) | 0x3f800000u;
  return __uint_as_float(r) - 1.0f;
}

// XLA ErfInv f32 (Giles polynomial)
__device__ __forceinline__ float erfinv_f32(float x) {
  float w = -log1pf(-x * x);
  float p;
  if (w < 5.0f) {
    w -= 2.5f;
    p = 2.81022636e-08f;
    p = fmaf(p, w, 3.43273939e-07f);
    p = fmaf(p, w, -3.5233877e-06f);
    p = fmaf(p, w, -4.39150654e-06f);
    p = fmaf(p, w, 0.00021858087f);
    p = fmaf(p, w, -0.00125372503f);
    p = fmaf(p, w, -0.00417768164f);
    p = fmaf(p, w, 0.246640727f);
    p = fmaf(p, w, 1.50140941f);
  } else {
    w = sqrtf(w) - 3.0f;
    p = -0.000200214257f;
    p = fmaf(p, w, 0.000100950558f);
    p = fmaf(p, w, 0.00134934322f);
    p = fmaf(p, w, -0.00367342844f);
    p = fmaf(p, w, 0.00573950773f);
    p = fmaf(p, w, -0.0076224613f);
    p = fmaf(p, w, 0.00943887047f);
    p = fmaf(p, w, 1.00167406f);
    p = fmaf(p, w, 2.83297682f);
  }
  return p * x;
}

// jax.random.normal: u = max(lo, u01*(hi-lo)+lo); hi-lo rounds to 2.0f exactly.
__device__ __forceinline__ float normal_from_bits(u32 bits) {
  const float lo = -0.99999994f; // nextafter(-1,0) in f32
  float u = u01_from_bits(bits) * 2.0f + lo;
  u = fmaxf(lo, u);
  return 1.41421356237f * erfinv_f32(u);
}

// jax.nn.softplus = logaddexp(x, 0) = max(x,0) + log1p(exp(-|x|))
__device__ __forceinline__ float softplus_f(float x) {
  return fmaxf(x, 0.0f) + log1pf(expf(-fabsf(x)));
}

// jax.random._gamma_one for alpha >= 1 (boost == 1), partitionable keys.
__device__ float gamma_sample(u32 k0, u32 k1, float alpha) {
  // key, subkey = split(key); u_boost = uniform(subkey)  [unconditional in jax;
  // u_boost unused since alpha >= 1, but the split consumes the key chain]
  U2 kk = tf2x32(k0, k1, 0u, 0u);
  k0 = kk.a; k1 = kk.b;
  float d = alpha - 0.33333334f;      // alpha - f32(1/3)
  float c = 0.33333334f / sqrtf(d);   // lax.div(one_over_three, sqrt(d))
  float X, V, U;
  do {
    // key, x_key, U_key = split(key, 3): counters 0,1,2
    U2 nk = tf2x32(k0, k1, 0u, 0u);
    U2 xk = tf2x32(k0, k1, 0u, 1u);
    U2 uk = tf2x32(k0, k1, 0u, 2u);
    k0 = nk.a; k1 = nk.b;
    u32 xk0 = xk.a, xk1 = xk.b;
    float x, v;
    do {
      // key, subkey = split(x_key); x = normal(subkey, ())
      U2 nxt = tf2x32(xk0, xk1, 0u, 0u);
      U2 sub = tf2x32(xk0, xk1, 0u, 1u);
      xk0 = nxt.a; xk1 = nxt.b;
      x = normal_from_bits(prf32(sub.a, sub.b, 0u));
      v = 1.0f + x * c;               // unfused, as lax.add(one, lax.mul(x,c))
    } while (v <= 0.0f);
    X = x * x;
    V = (v * v) * v;
    U = u01_from_bits(prf32(uk.a, uk.b, 0u));
  } while (U >= 1.0f - 0.0331f * (X * X) &&
           logf(U) >= 0.5f * X + d * ((1.0f - V) + logf(V)));
  return d * V;
}

// ---------------- GEMM: C = act(A*B + bias), 64x64 tile, BK=16, f32 ----------------
template<int ACT>
__global__ __launch_bounds__(256) void gemm64(const float* __restrict__ A,
                                              const float* __restrict__ Bm,
                                              const float* __restrict__ bias,
                                              float* __restrict__ C,
                                              int M, int N, int K) {
  __shared__ float As[16][68];
  __shared__ float Bs[16][68];
  const int tid = threadIdx.x;
  const int m0 = blockIdx.y * 64, n0 = blockIdx.x * 64;
  const int tx = tid & 15, ty = tid >> 4;
  const int arow = tid >> 4, acol = tid & 15;   // A tile: 16 rows/pass, col=k
  const int brow = tid >> 6, bcol = tid & 63;   // B tile: 4 rows/pass
  float acc[4][4] = {};
  for (int k0 = 0; k0 < K; k0 += 16) {
#pragma unroll
    for (int s = 0; s < 4; ++s)
      As[acol][arow + s * 16] = A[(size_t)(m0 + arow + s * 16) * K + k0 + acol];
#pragma unroll
    for (int s = 0; s < 4; ++s)
      Bs[brow + s * 4][bcol] = Bm[(size_t)(k0 + brow + s * 4) * N + n0 + bcol];
    __syncthreads();
#pragma unroll
    for (int kk = 0; kk < 16; ++kk) {
      float4 a4 = *(const float4*)&As[kk][ty * 4];
      float4 b4 = *(const float4*)&Bs[kk][tx * 4];
      float av[4] = {a4.x, a4.y, a4.z, a4.w};
      float bv[4] = {b4.x, b4.y, b4.z, b4.w};
#pragma unroll
      for (int i = 0; i < 4; ++i)
#pragma unroll
        for (int j = 0; j < 4; ++j) acc[i][j] = fmaf(av[i], bv[j], acc[i][j]);
    }
    __syncthreads();
  }
  float4 bb = *(const float4*)&bias[n0 + tx * 4];
  float bv[4] = {bb.x, bb.y, bb.z, bb.w};
#pragma unroll
  for (int i = 0; i < 4; ++i) {
    int m = m0 + ty * 4 + i;
    float4 o;
    float* op = &o.x;
#pragma unroll
    for (int j = 0; j < 4; ++j) {
      float v = acc[i][j] + bv[j];
      if (ACT == 1) v = fmaxf(v, 0.0f);
      op[j] = v;
    }
    *(float4*)&C[(size_t)m * N + n0 + tx * 4] = o;
  }
}

// --------------- eps/z generation + logpz/logq, one block per (l,b), D=256 ---------------
__global__ __launch_bounds__(256) void k_eps_z(const float* __restrict__ out_enc,
                                               float* __restrict__ z,
                                               float* __restrict__ logpz,
                                               float* __restrict__ logq,
                                               u32 ke0, u32 ke1) {
  const int lb = blockIdx.x;          // l*2048 + b
  const int b = lb & 2047;
  const int d = threadIdx.x;
  const u32 m = (u32)lb * 256u + (u32)d;   // < 5,242,880
  float mu = out_enc[b * 512 + d];
  float sg = softplus_f(out_enc[b * 512 + 256 + d]);  // +1e-64 underflows to +0 in f32
  float e = normal_from_bits(prf32(ke0, ke1, m));
  float zz = mu + sg * e;
  z[m] = zz;
  float t1 = -0.5f * e * e - logf(sg);
  float t2 = -0.5f * zz * zz;
#pragma unroll
  for (int o = 32; o; o >>= 1) { t1 += __shfl_down(t1, o); t2 += __shfl_down(t2, o); }
  __shared__ float sm1[4], sm2[4];
  int lane = d & 63, w = d >> 6;
  if (!lane) { sm1[w] = t1; sm2[w] = t2; }
  __syncthreads();
  if (d == 0) {
    float a = sm1[0] + sm1[1] + sm1[2] + sm1[3];
    float q = sm2[0] + sm2[1] + sm2[2] + sm2[3];
    logq[lb]  = a - 235.2482645003962f;   // 0.5*D*log(2*pi)
    logpz[lb] = q - 235.2482645003962f;
  }
}

// --------------- per-l: logpxobs row sums + t sampling + xms (missing entries only) ---------------
__global__ __launch_bounds__(256) void k_logpx_xms(const float* __restrict__ odec,
                                                   const float* __restrict__ data,
                                                   const int* __restrict__ mask,
                                                   float* __restrict__ xms,
                                                   float* __restrict__ lpxobs,
                                                   int l, u32 kn0, u32 kn1, u32 kg0, u32 kg1) {
  const int b = blockIdx.x;
  const int tid = threadIdx.x;
  float lpsum = 0.0f;
  for (int j = 0; j < 4; ++j) {
    int p = tid + j * 256;
    float mean = odec[b * 3072 + p];
    float scale = softplus_f(odec[b * 3072 + 1024 + p]) + 0.001f;
    float dfv = softplus_f(odec[b * 3072 + 2048 + p]) + 3.0f;
    u32 i = ((u32)l * 2048u + (u32)b) * 1024u + (u32)p;  // < 20,971,520
    if (mask[b * 1024 + p]) {
      float x = data[b * 1024 + p];
      float y = (x - mean) / scale;
      float lp = lgammaf((dfv + 1.0f) * 0.5f) - lgammaf(dfv * 0.5f)
               - 0.5f * logf(dfv * 3.14159274f) - logf(scale)
               - 0.5f * (dfv + 1.0f) * log1pf(y * y / dfv);
      lpsum += lp;
    } else {
      // n = normal(key_n, shape)[i]
      float n = normal_from_bits(prf32(kn0, kn1, i));
      // per-sample gamma key = split(key_g, N)[i] = PRF pair at counter i
      U2 gk = tf2x32(kg0, kg1, 0u, i);
      float half_df = dfv * 0.5f;
      float g = gamma_sample(gk.a, gk.b, half_df);
      float t = n * sqrtf(half_df / g);
      xms[i] = mean + scale * t;
    }
  }
#pragma unroll
  for (int o = 32; o; o >>= 1) lpsum += __shfl_down(lpsum, o);
  __shared__ float sm[4];
  int lane = tid & 63, w = tid >> 6;
  if (!lane) sm[w] = lpsum;
  __syncthreads();
  if (tid == 0) lpxobs[l * 2048 + b] = sm[0] + sm[1] + sm[2] + sm[3];
}

// --------------- importance weights: softmax over L=10 per column b ---------------
__global__ __launch_bounds__(256) void k_impw(const float* __restrict__ lpx,
                                              const float* __restrict__ lpz,
                                              const float* __restrict__ lq,
                                              float* __restrict__ w) {
  int b = blockIdx.x * 256 + threadIdx.x;
  float s[10], mx = -INFINITY;
#pragma unroll
  for (int l = 0; l < 10; ++l) {
    s[l] = lpx[l * 2048 + b] + lpz[l * 2048 + b] - lq[l * 2048 + b];
    mx = fmaxf(mx, s[l]);
  }
  float se = 0.0f;
#pragma unroll
  for (int l = 0; l < 10; ++l) { s[l] = expf(s[l] - mx); se += s[l]; }
#pragma unroll
  for (int l = 0; l < 10; ++l) w[l * 2048 + b] = s[l] / se;
}

// --------------- xm + data_imputed ---------------
__global__ __launch_bounds__(256) void k_xm(const int* __restrict__ mask,
                                            const float* __restrict__ data,
                                            const float* __restrict__ impw,
                                            const float* __restrict__ xms,
                                            float* __restrict__ out) {
  int idx = blockIdx.x * 256 + threadIdx.x;  // < 2048*1024
  int b = idx >> 10, p = idx & 1023;
  float o;
  if (mask[idx]) {
    o = data[idx];
  } else {
    float acc = 0.0f;
#pragma unroll
    for (int l = 0; l < 10; ++l)
      acc += impw[l * 2048 + b] * xms[((size_t)l * 2048 + b) * 1024 + p];
    o = acc;
  }
  out[idx] = o;
}

// --------------- classifier head: logits (N=10) ---------------
__global__ __launch_bounds__(256) void k_cls2(const float* __restrict__ hc,
                                              const float* __restrict__ w2,
                                              const float* __restrict__ b2,
                                              float* __restrict__ out) {
  int b = blockIdx.x, tid = threadIdx.x;
  float acc[10];
#pragma unroll
  for (int c = 0; c < 10; ++c) acc[c] = 0.0f;
  for (int k = tid; k < 2048; k += 256) {
    float h = hc[(size_t)b * 2048 + k];
#pragma unroll
    for (int c = 0; c < 10; ++c) acc[c] = fmaf(h, w2[k * 10 + c], acc[c]);
  }
  __shared__ float red[4][10];
  int lane = tid & 63, w = tid >> 6;
#pragma unroll
  for (int c = 0; c < 10; ++c) {
    float v = acc[c];
#pragma unroll
    for (int o = 32; o; o >>= 1) v += __shfl_down(v, o);
    if (!lane) red[w][c] = v;
  }
  __syncthreads();
  if (tid < 10) out[b * 10 + tid] = red[0][tid] + red[1][tid] + red[2][tid] + red[3][tid] + b2[tid];
}

extern "C" void kernel_launch(void* const* d_in, const int* in_sizes, int n_in,
                              void* d_out, int out_size, void* d_ws, size_t ws_size,
                              hipStream_t stream) {
  const float* data   = (const float*)d_in[0];
  const int*   mask   = (const int*)d_in[1];
  const float* enc_w1 = (const float*)d_in[2];
  const float* enc_b1 = (const float*)d_in[3];
  const float* enc_w2 = (const float*)d_in[4];
  const float* enc_b2 = (const float*)d_in[5];
  const float* dec_w1 = (const float*)d_in[6];
  const float* dec_b1 = (const float*)d_in[7];
  const float* dec_w2 = (const float*)d_in[8];
  const float* dec_b2 = (const float*)d_in[9];
  const float* cls_w1 = (const float*)d_in[10];
  const float* cls_b1 = (const float*)d_in[11];
  const float* cls_w2 = (const float*)d_in[12];
  const float* cls_b2 = (const float*)d_in[13];

  float* out = (float*)d_out;           // [2048*1024 data_imputed | 2048*10 logits]
  float* ws = (float*)d_ws;             // needs ~168.1 MB

  float* he      = ws;                  // 4,194,304
  float* out_enc = ws + 4194304;        // 1,048,576
  float* z       = ws + 5242880;        // 5,242,880
  float* hd      = ws + 10485760;       // 4,194,304
  float* odec    = ws + 14680064;       // 6,291,456
  float* xms     = ws + 20971520;       // 20,971,520
  float* logpz   = ws + 41943040;       // 20,480
  float* logq    = ws + 41963520;       // 20,480
  float* lpxobs  = ws + 41984000;       // 20,480
  float* impw    = ws + 42004480;       // 20,480
  float* hc      = he;                  // reuse (he dead after enc2)

  // key(42) = (0,42); partitionable split: k_eps=PRF(key,0), k_t=PRF(key,1);
  // inside jax.random.t: key_n=PRF(k_t,0), key_g=PRF(k_t,1)
  U2 ke = tf2x32(0u, 42u, 0u, 0u);
  U2 kt = tf2x32(0u, 42u, 0u, 1u);
  U2 kn = tf2x32(kt.a, kt.b, 0u, 0u);
  U2 kg = tf2x32(kt.a, kt.b, 0u, 1u);

  dim3 blk(256);
  // encoder
  gemm64<1><<<dim3(32, 32), blk, 0, stream>>>(data, enc_w1, enc_b1, he, 2048, 2048, 1024);
  gemm64<0><<<dim3(8, 32),  blk, 0, stream>>>(he, enc_w2, enc_b2, out_enc, 2048, 512, 2048);
  // eps, z, logpz, logq
  k_eps_z<<<20480, blk, 0, stream>>>(out_enc, z, logpz, logq, ke.a, ke.b);
  // decoder, chunked over l
  for (int l = 0; l < 10; ++l) {
    gemm64<1><<<dim3(32, 32), blk, 0, stream>>>(z + (size_t)l * 2048 * 256, dec_w1, dec_b1, hd, 2048, 2048, 256);
    gemm64<0><<<dim3(48, 32), blk, 0, stream>>>(hd, dec_w2, dec_b2, odec, 2048, 3072, 2048);
    k_logpx_xms<<<2048, blk, 0, stream>>>(odec, data, mask, xms, lpxobs, l, kn.a, kn.b, kg.a, kg.b);
  }
  // importance weights, imputation
  k_impw<<<8, blk, 0, stream>>>(lpxobs, logpz, logq, impw);
  k_xm<<<8192, blk, 0, stream>>>(mask, data, impw, xms, out);
  // classifier
  gemm64<1><<<dim3(32, 32), blk, 0, stream>>>(out, cls_w1, cls_b1, hc, 2048, 2048, 1024);
  k_cls2<<<2048, blk, 0, stream>>>(hc, cls_w2, cls_b2, out + 2048 * 1024);
}

// Round 4
// 4109.510 us; speedup vs baseline: 1.2399x; 1.2399x over previous
//
#include <hip/hip_runtime.h>
#include <math.h>

typedef unsigned int u32;
typedef unsigned short u16;
typedef __attribute__((ext_vector_type(8))) short bf16x8;
typedef __attribute__((ext_vector_type(16))) float f32x16;

struct U2 { u32 a, b; };

// Threefry-2x32, 20 rounds — matches jax._src.prng.threefry2x32 exactly.
__host__ __device__ __forceinline__ U2 tf2x32(u32 k0, u32 k1, u32 c0, u32 c1) {
  u32 ks2 = k0 ^ k1 ^ 0x1BD11BDAu;
  u32 x0 = c0 + k0, x1 = c1 + k1;
#define TFR(r) { x0 += x1; x1 = (x1 << (r)) | (x1 >> (32 - (r))); x1 ^= x0; }
  TFR(13) TFR(15) TFR(26) TFR(6)
  x0 += k1; x1 += ks2 + 1u;
  TFR(17) TFR(29) TFR(16) TFR(24)
  x0 += ks2; x1 += k0 + 2u;
  TFR(13) TFR(15) TFR(26) TFR(6)
  x0 += k0; x1 += k1 + 3u;
  TFR(17) TFR(29) TFR(16) TFR(24)
  x0 += k1; x1 += ks2 + 4u;
  TFR(13) TFR(15) TFR(26) TFR(6)
  x0 += ks2; x1 += k0 + 5u;
#undef TFR
  return {x0, x1};
}

// jax_threefry_partitionable=True:
// random_bits(key,32,shape)[i] = b1^b2 at counter (0,i); split(key,n)[i] = pair at counter i.
__host__ __device__ __forceinline__ u32 prf32(u32 k0, u32 k1, u32 i) {
  U2 r = tf2x32(k0, k1, 0u, i);
  return r.a ^ r.b;
}

__device__ __forceinline__ float u01_from_bits(u32 bits) {
  u32 r = (bits >> 9) | 0x3f800000u;
  return __uint_as_float(r) - 1.0f;
}

// XLA ErfInv f32 (Giles polynomial)
__device__ __forceinline__ float erfinv_f32(float x) {
  float w = -log1pf(-x * x);
  float p;
  if (w < 5.0f) {
    w -= 2.5f;
    p = 2.81022636e-08f;
    p = fmaf(p, w, 3.43273939e-07f);
    p = fmaf(p, w, -3.5233877e-06f);
    p = fmaf(p, w, -4.39150654e-06f);
    p = fmaf(p, w, 0.00021858087f);
    p = fmaf(p, w, -0.00125372503f);
    p = fmaf(p, w, -0.00417768164f);
    p = fmaf(p, w, 0.246640727f);
    p = fmaf(p, w, 1.50140941f);
  } else {
    w = sqrtf(w) - 3.0f;
    p = -0.000200214257f;
    p = fmaf(p, w, 0.000100950558f);
    p = fmaf(p, w, 0.00134934322f);
    p = fmaf(p, w, -0.00367342844f);
    p = fmaf(p, w, 0.00573950773f);
    p = fmaf(p, w, -0.0076224613f);
    p = fmaf(p, w, 0.00943887047f);
    p = fmaf(p, w, 1.00167406f);
    p = fmaf(p, w, 2.83297682f);
  }
  return p * x;
}

__device__ __forceinline__ float normal_from_bits(u32 bits) {
  const float lo = -0.99999994f;
  float u = u01_from_bits(bits) * 2.0f + lo;
  u = fmaxf(lo, u);
  return 1.41421356237f * erfinv_f32(u);
}

__device__ __forceinline__ float softplus_f(float x) {
  return fmaxf(x, 0.0f) + log1pf(expf(-fabsf(x)));
}

// jax.random._gamma_one for alpha >= 1 (boost == 1), partitionable keys.
// Validated in round 2 (absmax 0.5).
__device__ float gamma_sample(u32 k0, u32 k1, float alpha) {
  U2 kk = tf2x32(k0, k1, 0u, 0u);   // key, subkey = split(key) [u_boost consumed]
  k0 = kk.a; k1 = kk.b;
  float d = alpha - 0.33333334f;
  float c = 0.33333334f / sqrtf(d);
  float X, V, U;
  do {
    U2 nk = tf2x32(k0, k1, 0u, 0u);
    U2 xk = tf2x32(k0, k1, 0u, 1u);
    U2 uk = tf2x32(k0, k1, 0u, 2u);
    k0 = nk.a; k1 = nk.b;
    u32 xk0 = xk.a, xk1 = xk.b;
    float x, v;
    do {
      U2 nxt = tf2x32(xk0, xk1, 0u, 0u);
      U2 sub = tf2x32(xk0, xk1, 0u, 1u);
      xk0 = nxt.a; xk1 = nxt.b;
      x = normal_from_bits(prf32(sub.a, sub.b, 0u));
      v = 1.0f + x * c;
    } while (v <= 0.0f);
    X = x * x;
    V = (v * v) * v;
    U = u01_from_bits(prf32(uk.a, uk.b, 0u));
  } while (U >= 1.0f - 0.0331f * (X * X) &&
           logf(U) >= 0.5f * X + d * ((1.0f - V) + logf(V)));
  return d * V;
}

// ---------------- bf16 split-3 helpers ----------------
__device__ __forceinline__ u16 f2bf(float f) {
  u32 u = __float_as_uint(f);
  u32 r = ((u >> 16) & 1u) + 0x7fffu;
  return (u16)((u + r) >> 16);
}
__device__ __forceinline__ float bf2f(u16 h) { return __uint_as_float(((u32)h) << 16); }

__device__ __forceinline__ void split3(float v, u16& h, u16& m, u16& lo) {
  h = f2bf(v); float r1 = v - bf2f(h);     // exact residual
  m = f2bf(r1); lo = f2bf(r1 - bf2f(m));
}

#define GLOAD16(gp, lp) __builtin_amdgcn_global_load_lds( \
    (const __attribute__((address_space(1))) void*)(gp),  \
    (__attribute__((address_space(3))) void*)(lp), 16, 0, 0)

// ---------------- split-3 bf16 MFMA GEMM (slot-major planes) ----------------
// A3 [M][3K] rm (planes h|m|l), B3T [N][3K] rm (planes h|m|l), bias[N] f32.
// Virtual K6=6K; slot s = vk/K: A-plane {h,h,m,h,l,m}, B-plane {h,m,h,l,h,m}
// -> products hh,hm,mh,hl,lh,mm (compensated f32 product to ~2^-24).
// 128x128 tile, BK=64, 4 waves, 32x32x16 bf16 MFMA, XOR-swizzled LDS (T2).
template<bool RELU, bool SIX>
__global__ __launch_bounds__(256, 3) void gemm_s3(const u16* __restrict__ A3,
                                                  const u16* __restrict__ B3T,
                                                  const float* __restrict__ bias,
                                                  float* __restrict__ Cf,
                                                  u16* __restrict__ C3,
                                                  int N, int kbits) {
  __shared__ u16 As[128 * 64];
  __shared__ u16 Bs[128 * 64];
  const int tid = threadIdx.x;
  const int l = tid & 63, w = tid >> 6;
  const int m0 = blockIdx.y * 128, n0 = blockIdx.x * 128;
  const int K3 = 3 << kbits;
  // staging: per-lane inverse-swizzled source column (16B blocks)
  const int srow = l >> 3;
  const int scol = ((l & 7) ^ srow) << 3;
  const u16* agr[4]; const u16* bgr[4]; u16* al[4]; u16* bl[4];
#pragma unroll
  for (int j = 0; j < 4; ++j) {
    int r = w * 32 + j * 8 + srow;
    agr[j] = A3 + (size_t)(m0 + r) * K3 + scol;
    bgr[j] = B3T + (size_t)(n0 + r) * K3 + scol;
    al[j] = &As[(w * 4 + j) * 512];
    bl[j] = &Bs[(w * 4 + j) * 512];
  }
  f32x16 acc[2][2] = {};
  const int fr = l & 31;
  const int wm = w >> 1, wn = w & 1;
  const int swz = (l & 7) << 4;
  const int hk16 = (l >> 5) << 4;
  const int nk = (6 << kbits) >> 6;
  const int kmask = (1 << kbits) - 1;
  for (int kt = 0; kt < nk; ++kt) {
    int vb = kt << 6;
    int s = vb >> kbits;
    int ko = vb & kmask;
    int pa = (int)((s == 2) | (s == 5)) + ((s == 4) << 1);
    int pb = (int)((s == 1) | (s == 5)) + ((s == 3) << 1);
    int ao = (pa << kbits) + ko;
    int bo = (pb << kbits) + ko;
    __syncthreads();   // previous tile consumed
#pragma unroll
    for (int j = 0; j < 4; ++j) {
      GLOAD16(agr[j] + ao, al[j]);
      GLOAD16(bgr[j] + bo, bl[j]);
    }
    __syncthreads();   // compiler drains vmcnt(0) before barrier: tile ready
#pragma unroll
    for (int ks = 0; ks < 4; ++ks) {
      bf16x8 af[2], bf[2];
#pragma unroll
      for (int mi = 0; mi < 2; ++mi) {
        int ar = wm * 64 + mi * 32 + fr;
        af[mi] = *(const bf16x8*)((const char*)As + ar * 128 + ((ks * 32 + hk16) ^ swz));
      }
#pragma unroll
      for (int ni = 0; ni < 2; ++ni) {
        int br = wn * 64 + ni * 32 + fr;
        bf[ni] = *(const bf16x8*)((const char*)Bs + br * 128 + ((ks * 32 + hk16) ^ swz));
      }
#pragma unroll
      for (int mi = 0; mi < 2; ++mi)
#pragma unroll
        for (int ni = 0; ni < 2; ++ni)
          acc[mi][ni] = __builtin_amdgcn_mfma_f32_32x32x16_bf16(af[mi], bf[ni], acc[mi][ni], 0, 0, 0);
    }
  }
  // epilogue: C/D layout col=lane&31, row=(r&3)+8*(r>>2)+4*(lane>>5)
#pragma unroll
  for (int mi = 0; mi < 2; ++mi)
#pragma unroll
  for (int ni = 0; ni < 2; ++ni) {
    int gcol = n0 + wn * 64 + ni * 32 + fr;
    float bsv = bias[gcol];
#pragma unroll
    for (int r = 0; r < 16; ++r) {
      int grow = m0 + wm * 64 + mi * 32 + (r & 3) + 8 * (r >> 2) + 4 * (l >> 5);
      float v = acc[mi][ni][r] + bsv;
      if (RELU) v = fmaxf(v, 0.0f);
      if (!SIX) {
        Cf[(size_t)grow * N + gcol] = v;
      } else {
        u16 h, mm, lo; split3(v, h, mm, lo);
        u16* q = C3 + (size_t)grow * 3 * N + gcol;
        q[0] = h; q[N] = mm; q[2 * N] = lo;
      }
    }
  }
}

// -------- weight conversion: W [K][N] f32 -> W3T [N][3K] bf16 planes --------
__global__ __launch_bounds__(256) void k_wconv(const float* __restrict__ W, u16* __restrict__ W3T,
                                               int K, int N) {
  __shared__ float t[64][65];
  const int k0 = blockIdx.y * 64, n0 = blockIdx.x * 64;
  const int tid = threadIdx.x;
  for (int i = tid; i < 4096; i += 256) {
    int kk = i >> 6, nn = i & 63;
    t[kk][nn] = W[(size_t)(k0 + kk) * N + (n0 + nn)];
  }
  __syncthreads();
  const int nn = tid >> 2, kc = (tid & 3) << 4;
  u16* base = W3T + (size_t)(n0 + nn) * 3 * K + (k0 + kc);
#pragma unroll
  for (int kk = 0; kk < 16; ++kk) {
    u16 h, m, lo; split3(t[kc + kk][nn], h, m, lo);
    base[kk] = h; base[K + kk] = m; base[2 * K + kk] = lo;
  }
}

// -------- activation conversion: X [rows][K] f32 -> X3 [rows][3K] planes --------
__global__ __launch_bounds__(256) void k_aconv(const float* __restrict__ X, u16* __restrict__ X3,
                                               int total, int kbits) {
  int i = blockIdx.x * 256 + threadIdx.x;
  if (i >= total) return;
  int K = 1 << kbits;
  int r = i >> kbits, k = i & (K - 1);
  u16 h, m, lo; split3(X[i], h, m, lo);
  u16* q = X3 + ((size_t)r * 3 << kbits) + k;
  q[0] = h; q[K] = m; q[2 * K] = lo;
}

// ------- eps/z for chunk l: writes z3c [2048][3*256] + logpz/logq -------
__global__ __launch_bounds__(256) void k_eps_z(const float* __restrict__ out_enc,
                                               u16* __restrict__ z3c,
                                               float* __restrict__ logpz,
                                               float* __restrict__ logq,
                                               int l, u32 ke0, u32 ke1) {
  const int b = blockIdx.x;
  const int d = threadIdx.x;
  const u32 m = ((u32)(l * 2048 + b) << 8) + (u32)d;
  float mu = out_enc[b * 512 + d];
  float sg = softplus_f(out_enc[b * 512 + 256 + d]);  // +1e-64 underflows in f32
  float e = normal_from_bits(prf32(ke0, ke1, m));
  float zz = mu + sg * e;
  u16 h, mm, lo; split3(zz, h, mm, lo);
  u16* q = z3c + b * 768 + d;
  q[0] = h; q[256] = mm; q[512] = lo;
  float t1 = -0.5f * e * e - logf(sg);
  float t2 = -0.5f * zz * zz;
#pragma unroll
  for (int o = 32; o; o >>= 1) { t1 += __shfl_down(t1, o); t2 += __shfl_down(t2, o); }
  __shared__ float sm1[4], sm2[4];
  int lane = d & 63, wv = d >> 6;
  if (!lane) { sm1[wv] = t1; sm2[wv] = t2; }
  __syncthreads();
  if (d == 0) {
    float a = sm1[0] + sm1[1] + sm1[2] + sm1[3];
    float qq = sm2[0] + sm2[1] + sm2[2] + sm2[3];
    logq[l * 2048 + b]  = a - 235.2482645003962f;   // 0.5*D*log(2*pi)
    logpz[l * 2048 + b] = qq - 235.2482645003962f;
  }
}

// ------- per-chunk: logpxobs + t sampling + xms (bf16, missing entries) -------
__global__ __launch_bounds__(256) void k_logpx_xms(const float* __restrict__ odec,
                                                   const float* __restrict__ data,
                                                   const int* __restrict__ mask,
                                                   u16* __restrict__ xms,
                                                   float* __restrict__ lpxobs,
                                                   int l, u32 kn0, u32 kn1, u32 kg0, u32 kg1) {
  const int b = blockIdx.x;
  const int tid = threadIdx.x;
  float lpsum = 0.0f;
  for (int j = 0; j < 4; ++j) {
    int p = tid + j * 256;
    float mean  = odec[(size_t)b * 3072 + p];
    float scale = softplus_f(odec[(size_t)b * 3072 + 1024 + p]) + 0.001f;
    float dfv   = softplus_f(odec[(size_t)b * 3072 + 2048 + p]) + 3.0f;
    u32 i = ((u32)(l * 2048 + b) << 10) + (u32)p;
    if (mask[b * 1024 + p]) {
      float x = data[b * 1024 + p];
      float y = (x - mean) / scale;
      float lp = lgammaf((dfv + 1.0f) * 0.5f) - lgammaf(dfv * 0.5f)
               - 0.5f * logf(dfv * 3.14159274f) - logf(scale)
               - 0.5f * (dfv + 1.0f) * log1pf(y * y / dfv);
      lpsum += lp;
    } else {
      float n = normal_from_bits(prf32(kn0, kn1, i));
      U2 gk = tf2x32(kg0, kg1, 0u, i);     // split(key_g, N)[i]
      float half_df = dfv * 0.5f;
      float g = gamma_sample(gk.a, gk.b, half_df);
      float t = n * sqrtf(half_df / g);
      xms[i] = f2bf(mean + scale * t);
    }
  }
#pragma unroll
  for (int o = 32; o; o >>= 1) lpsum += __shfl_down(lpsum, o);
  __shared__ float sm[4];
  int lane = tid & 63, wv = tid >> 6;
  if (!lane) sm[wv] = lpsum;
  __syncthreads();
  if (tid == 0) lpxobs[l * 2048 + b] = sm[0] + sm[1] + sm[2] + sm[3];
}

// --------------- importance weights: softmax over L=10 ---------------
__global__ __launch_bounds__(256) void k_impw(const float* __restrict__ lpx,
                                              const float* __restrict__ lpz,
                                              const float* __restrict__ lq,
                                              float* __restrict__ w) {
  int b = blockIdx.x * 256 + threadIdx.x;
  float s[10], mx = -INFINITY;
#pragma unroll
  for (int l = 0; l < 10; ++l) {
    s[l] = lpx[l * 2048 + b] + lpz[l * 2048 + b] - lq[l * 2048 + b];
    mx = fmaxf(mx, s[l]);
  }
  float se = 0.0f;
#pragma unroll
  for (int l = 0; l < 10; ++l) { s[l] = expf(s[l] - mx); se += s[l]; }
#pragma unroll
  for (int l = 0; l < 10; ++l) w[l * 2048 + b] = s[l] / se;
}

// ------- xm + data_imputed (+ 3-plane split for classifier input) -------
__global__ __launch_bounds__(256) void k_xm(const int* __restrict__ mask,
                                            const float* __restrict__ data,
                                            const float* __restrict__ impw,
                                            const u16* __restrict__ xms,
                                            u16* __restrict__ imp3,
                                            float* __restrict__ out) {
  int idx = blockIdx.x * 256 + threadIdx.x;
  int b = idx >> 10, p = idx & 1023;
  float o;
  if (mask[idx]) {
    o = data[idx];
  } else {
    float acc = 0.0f;
#pragma unroll
    for (int l = 0; l < 10; ++l)
      acc += impw[l * 2048 + b] * bf2f(xms[((size_t)l * 2048 + b) * 1024 + p]);
    o = acc;
  }
  out[idx] = o;
  u16 h, m, lo; split3(o, h, m, lo);
  u16* q = imp3 + (size_t)b * 3072 + p;
  q[0] = h; q[1024] = m; q[2048] = lo;
}

// --------------- classifier head: logits (N=10) ---------------
__global__ __launch_bounds__(256) void k_cls2(const float* __restrict__ hc,
                                              const float* __restrict__ w2,
                                              const float* __restrict__ b2,
                                              float* __restrict__ out) {
  int b = blockIdx.x, tid = threadIdx.x;
  float acc[10];
#pragma unroll
  for (int c = 0; c < 10; ++c) acc[c] = 0.0f;
  for (int k = tid; k < 2048; k += 256) {
    float h = hc[(size_t)b * 2048 + k];
#pragma unroll
    for (int c = 0; c < 10; ++c) acc[c] = fmaf(h, w2[k * 10 + c], acc[c]);
  }
  __shared__ float red[4][10];
  int lane = tid & 63, wv = tid >> 6;
#pragma unroll
  for (int c = 0; c < 10; ++c) {
    float v = acc[c];
#pragma unroll
    for (int o = 32; o; o >>= 1) v += __shfl_down(v, o);
    if (!lane) red[wv][c] = v;
  }
  __syncthreads();
  if (tid < 10) out[b * 10 + tid] = red[0][tid] + red[1][tid] + red[2][tid] + red[3][tid] + b2[tid];
}

extern "C" void kernel_launch(void* const* d_in, const int* in_sizes, int n_in,
                              void* d_out, int out_size, void* d_ws, size_t ws_size,
                              hipStream_t stream) {
  const float* data   = (const float*)d_in[0];
  const int*   mask   = (const int*)d_in[1];
  const float* enc_w1 = (const float*)d_in[2];
  const float* enc_b1 = (const float*)d_in[3];
  const float* enc_w2 = (const float*)d_in[4];
  const float* enc_b2 = (const float*)d_in[5];
  const float* dec_w1 = (const float*)d_in[6];
  const float* dec_b1 = (const float*)d_in[7];
  const float* dec_w2 = (const float*)d_in[8];
  const float* dec_b2 = (const float*)d_in[9];
  const float* cls_w1 = (const float*)d_in[10];
  const float* cls_b1 = (const float*)d_in[11];
  const float* cls_w2 = (const float*)d_in[12];
  const float* cls_b2 = (const float*)d_in[13];

  float* out = (float*)d_out;   // [2048*1024 data_imputed | 2048*10 logits]
  char* wsb = (char*)d_ws;

  // ---- byte layout (peak 165,675,008 B = 158 MiB; round-2 proved ws >= 168,099,840 B) ----
  if (ws_size < 165675008ULL) return;  // graceful signature instead of OOB crash
  u16*   xmsu   = (u16*)(wsb + 0);              // [10*2048][1024] bf16      (40.0 MiB)
  u16*   w_d2   = (u16*)(wsb + 41943040);       // [3072][3*2048]            (36.0 MiB)
  u16*   hx3    = (u16*)(wsb + 79691776);       // he3/hd3 [2048][3*2048]    (24.0 MiB)
  float* odec   = (float*)(wsb + 104857600);    // [2048][3072] f32          (24.0 MiB)
  float* hc     = odec;                         // reuse  [2048][2048] f32
  u16*   data3  = (u16*)(wsb + 130023424);      // [2048][3*1024]            (12.0 MiB)
  u16*   imp3   = data3;                        // reuse (after z3c/w_d1 dead)
  u16*   z3c    = (u16*)(wsb + 130023424);      // [2048][3*256]  (in data3, post-enc1)
  u16*   w_d1   = (u16*)(wsb + 133169152);      // [2048][3*256]  (in data3, post-enc1)
  u16*   w_ec   = (u16*)(wsb + 142606336);      // w_e1 then w_c1 [2048][3*1024] (12.0 MiB)
  u16*   w_e2   = (u16*)(wsb + 155189248);      // [512][3*2048]             (6.0 MiB)
  float* logpz  = (float*)(wsb + 155189248);    // smalls overlay w_e2 (dead after enc2)
  float* logq   = (float*)(wsb + 155271168);
  float* lpxobs = (float*)(wsb + 155353088);
  float* impw   = (float*)(wsb + 155435008);
  float* out_enc= (float*)(wsb + 161480704);    // [2048][512] f32           (4.0 MiB)

  // key(42)=(0,42); k_eps=PRF(key,0), k_t=PRF(key,1); key_n=PRF(k_t,0), key_g=PRF(k_t,1)
  U2 ke = tf2x32(0u, 42u, 0u, 0u);
  U2 kt = tf2x32(0u, 42u, 0u, 1u);
  U2 kn = tf2x32(kt.a, kt.b, 0u, 0u);
  U2 kg = tf2x32(kt.a, kt.b, 0u, 1u);

  dim3 blk(256);
  // conversions needed before encoder
  k_aconv<<<8192, blk, 0, stream>>>(data, data3, 2097152, 10);
  k_wconv<<<dim3(32, 16), blk, 0, stream>>>(enc_w1, w_ec, 1024, 2048);
  k_wconv<<<dim3(8, 32),  blk, 0, stream>>>(enc_w2, w_e2, 2048, 512);
  k_wconv<<<dim3(48, 32), blk, 0, stream>>>(dec_w2, w_d2, 2048, 3072);

  // encoder
  gemm_s3<true,  true ><<<dim3(16, 16), blk, 0, stream>>>(data3, w_ec, enc_b1, nullptr, hx3, 2048, 10);
  gemm_s3<false, false><<<dim3(4, 16),  blk, 0, stream>>>(hx3, w_e2, enc_b2, out_enc, nullptr, 512, 11);

  // dec_w1 conversion into the (now dead) data3 region
  k_wconv<<<dim3(32, 4), blk, 0, stream>>>(dec_w1, w_d1, 256, 2048);

  // decoder: one l-chunk (M=2048) at a time
  for (int l = 0; l < 10; ++l) {
    k_eps_z<<<2048, blk, 0, stream>>>(out_enc, z3c, logpz, logq, l, ke.a, ke.b);
    gemm_s3<true,  true ><<<dim3(16, 16), blk, 0, stream>>>(z3c, w_d1, dec_b1, nullptr, hx3, 2048, 8);
    gemm_s3<false, false><<<dim3(24, 16), blk, 0, stream>>>(hx3, w_d2, dec_b2, odec, nullptr, 3072, 11);
    k_logpx_xms<<<2048, blk, 0, stream>>>(odec, data, mask, xmsu, lpxobs, l, kn.a, kn.b, kg.a, kg.b);
  }

  // importance weights + imputation (imp3 overwrites data3 region; z3c/w_d1 dead)
  k_impw<<<8, blk, 0, stream>>>(lpxobs, logpz, logq, impw);
  k_xm<<<8192, blk, 0, stream>>>(mask, data, impw, xmsu, imp3, out);

  // classifier (re-convert cls_w1 into w_ec slot)
  k_wconv<<<dim3(32, 16), blk, 0, stream>>>(cls_w1, w_ec, 1024, 2048);
  gemm_s3<true, false><<<dim3(16, 16), blk, 0, stream>>>(imp3, w_ec, cls_b1, hc, nullptr, 2048, 10);
  k_cls2<<<2048, blk, 0, stream>>>(hc, cls_w2, cls_b2, out + 2048 * 1024);
}

// Round 5
// 3207.713 us; speedup vs baseline: 1.5885x; 1.2811x over previous
//
#include <hip/hip_runtime.h>
#include <math.h>

typedef unsigned int u32;
typedef unsigned short u16;
typedef __attribute__((ext_vector_type(8))) short bf16x8;
typedef __attribute__((ext_vector_type(16))) float f32x16;

struct U2 { u32 a, b; };

// Threefry-2x32, 20 rounds — matches jax._src.prng.threefry2x32 exactly.
__host__ __device__ __forceinline__ U2 tf2x32(u32 k0, u32 k1, u32 c0, u32 c1) {
  u32 ks2 = k0 ^ k1 ^ 0x1BD11BDAu;
  u32 x0 = c0 + k0, x1 = c1 + k1;
#define TFR(r) { x0 += x1; x1 = (x1 << (r)) | (x1 >> (32 - (r))); x1 ^= x0; }
  TFR(13) TFR(15) TFR(26) TFR(6)
  x0 += k1; x1 += ks2 + 1u;
  TFR(17) TFR(29) TFR(16) TFR(24)
  x0 += ks2; x1 += k0 + 2u;
  TFR(13) TFR(15) TFR(26) TFR(6)
  x0 += k0; x1 += k1 + 3u;
  TFR(17) TFR(29) TFR(16) TFR(24)
  x0 += k1; x1 += ks2 + 4u;
  TFR(13) TFR(15) TFR(26) TFR(6)
  x0 += ks2; x1 += k0 + 5u;
#undef TFR
  return {x0, x1};
}

// jax_threefry_partitionable=True:
// random_bits(key,32,shape)[i] = b1^b2 at counter (0,i); split(key,n)[i] = pair at counter i.
__host__ __device__ __forceinline__ u32 prf32(u32 k0, u32 k1, u32 i) {
  U2 r = tf2x32(k0, k1, 0u, i);
  return r.a ^ r.b;
}

__device__ __forceinline__ float u01_from_bits(u32 bits) {
  u32 r = (bits >> 9) | 0x3f800000u;
  return __uint_as_float(r) - 1.0f;
}

// XLA ErfInv f32 (Giles polynomial)
__device__ __forceinline__ float erfinv_f32(float x) {
  float w = -log1pf(-x * x);
  float p;
  if (w < 5.0f) {
    w -= 2.5f;
    p = 2.81022636e-08f;
    p = fmaf(p, w, 3.43273939e-07f);
    p = fmaf(p, w, -3.5233877e-06f);
    p = fmaf(p, w, -4.39150654e-06f);
    p = fmaf(p, w, 0.00021858087f);
    p = fmaf(p, w, -0.00125372503f);
    p = fmaf(p, w, -0.00417768164f);
    p = fmaf(p, w, 0.246640727f);
    p = fmaf(p, w, 1.50140941f);
  } else {
    w = sqrtf(w) - 3.0f;
    p = -0.000200214257f;
    p = fmaf(p, w, 0.000100950558f);
    p = fmaf(p, w, 0.00134934322f);
    p = fmaf(p, w, -0.00367342844f);
    p = fmaf(p, w, 0.00573950773f);
    p = fmaf(p, w, -0.0076224613f);
    p = fmaf(p, w, 0.00943887047f);
    p = fmaf(p, w, 1.00167406f);
    p = fmaf(p, w, 2.83297682f);
  }
  return p * x;
}

__device__ __forceinline__ float normal_from_bits(u32 bits) {
  const float lo = -0.99999994f;
  float u = u01_from_bits(bits) * 2.0f + lo;
  u = fmaxf(lo, u);
  return 1.41421356237f * erfinv_f32(u);
}

__device__ __forceinline__ float softplus_f(float x) {
  return fmaxf(x, 0.0f) + log1pf(expf(-fabsf(x)));
}

// jax.random._gamma_one for alpha >= 1 (boost == 1), partitionable keys.
// Validated in rounds 2/4 (absmax 0.5/0.25).
__device__ float gamma_sample(u32 k0, u32 k1, float alpha) {
  U2 kk = tf2x32(k0, k1, 0u, 0u);   // key, subkey = split(key) [u_boost consumed]
  k0 = kk.a; k1 = kk.b;
  float d = alpha - 0.33333334f;
  float c = 0.33333334f / sqrtf(d);
  float X, V, U;
  do {
    U2 nk = tf2x32(k0, k1, 0u, 0u);
    U2 xk = tf2x32(k0, k1, 0u, 1u);
    U2 uk = tf2x32(k0, k1, 0u, 2u);
    k0 = nk.a; k1 = nk.b;
    u32 xk0 = xk.a, xk1 = xk.b;
    float x, v;
    do {
      U2 nxt = tf2x32(xk0, xk1, 0u, 0u);
      U2 sub = tf2x32(xk0, xk1, 0u, 1u);
      xk0 = nxt.a; xk1 = nxt.b;
      x = normal_from_bits(prf32(sub.a, sub.b, 0u));
      v = 1.0f + x * c;
    } while (v <= 0.0f);
    X = x * x;
    V = (v * v) * v;
    U = u01_from_bits(prf32(uk.a, uk.b, 0u));
  } while (U >= 1.0f - 0.0331f * (X * X) &&
           logf(U) >= 0.5f * X + d * ((1.0f - V) + logf(V)));
  return d * V;
}

// ---------------- bf16 split-3 helpers ----------------
__device__ __forceinline__ u16 f2bf(float f) {
  u32 u = __float_as_uint(f);
  u32 r = ((u >> 16) & 1u) + 0x7fffu;
  return (u16)((u + r) >> 16);
}
__device__ __forceinline__ float bf2f(u16 h) { return __uint_as_float(((u32)h) << 16); }

__device__ __forceinline__ void split3(float v, u16& h, u16& m, u16& lo) {
  h = f2bf(v); float r1 = v - bf2f(h);     // exact residual
  m = f2bf(r1); lo = f2bf(r1 - bf2f(m));
}

#define GLOAD16(gp, lp) __builtin_amdgcn_global_load_lds( \
    (const __attribute__((address_space(1))) void*)(gp),  \
    (__attribute__((address_space(3))) void*)(lp), 16, 0, 0)

// ---------------- split-3 bf16 MFMA GEMM (slot-major planes) ----------------
// A3 [M][3K] rm (planes h|m|l), B3T [N][3K] rm (planes h|m|l), bias[N] f32.
// Virtual K6=6K; slot s = vk/K: A-plane {h,h,m,h,l,m}, B-plane {h,m,h,l,h,m}
// -> products hh,hm,mh,hl,lh,mm (compensated f32 product to ~2^-24).
// 128x128 tile, BK=64, 4 waves, 32x32x16 bf16 MFMA, XOR-swizzled LDS (T2).
template<bool RELU, bool SIX>
__global__ __launch_bounds__(256, 3) void gemm_s3(const u16* __restrict__ A3,
                                                  const u16* __restrict__ B3T,
                                                  const float* __restrict__ bias,
                                                  float* __restrict__ Cf,
                                                  u16* __restrict__ C3,
                                                  int N, int kbits) {
  __shared__ u16 As[128 * 64];
  __shared__ u16 Bs[128 * 64];
  const int tid = threadIdx.x;
  const int l = tid & 63, w = tid >> 6;
  const int m0 = blockIdx.y * 128, n0 = blockIdx.x * 128;
  const int K3 = 3 << kbits;
  // staging: per-lane inverse-swizzled source column (16B blocks)
  const int srow = l >> 3;
  const int scol = ((l & 7) ^ srow) << 3;
  const u16* agr[4]; const u16* bgr[4]; u16* al[4]; u16* bl[4];
#pragma unroll
  for (int j = 0; j < 4; ++j) {
    int r = w * 32 + j * 8 + srow;
    agr[j] = A3 + (size_t)(m0 + r) * K3 + scol;
    bgr[j] = B3T + (size_t)(n0 + r) * K3 + scol;
    al[j] = &As[(w * 4 + j) * 512];
    bl[j] = &Bs[(w * 4 + j) * 512];
  }
  f32x16 acc[2][2] = {};
  const int fr = l & 31;
  const int wm = w >> 1, wn = w & 1;
  const int swz = (l & 7) << 4;
  const int hk16 = (l >> 5) << 4;
  const int nk = (6 << kbits) >> 6;
  const int kmask = (1 << kbits) - 1;
  for (int kt = 0; kt < nk; ++kt) {
    int vb = kt << 6;
    int s = vb >> kbits;
    int ko = vb & kmask;
    int pa = (int)((s == 2) | (s == 5)) + ((s == 4) << 1);
    int pb = (int)((s == 1) | (s == 5)) + ((s == 3) << 1);
    int ao = (pa << kbits) + ko;
    int bo = (pb << kbits) + ko;
    __syncthreads();   // previous tile consumed
#pragma unroll
    for (int j = 0; j < 4; ++j) {
      GLOAD16(agr[j] + ao, al[j]);
      GLOAD16(bgr[j] + bo, bl[j]);
    }
    __syncthreads();   // compiler drains vmcnt(0) before barrier: tile ready
#pragma unroll
    for (int ks = 0; ks < 4; ++ks) {
      bf16x8 af[2], bf[2];
#pragma unroll
      for (int mi = 0; mi < 2; ++mi) {
        int ar = wm * 64 + mi * 32 + fr;
        af[mi] = *(const bf16x8*)((const char*)As + ar * 128 + ((ks * 32 + hk16) ^ swz));
      }
#pragma unroll
      for (int ni = 0; ni < 2; ++ni) {
        int br = wn * 64 + ni * 32 + fr;
        bf[ni] = *(const bf16x8*)((const char*)Bs + br * 128 + ((ks * 32 + hk16) ^ swz));
      }
#pragma unroll
      for (int mi = 0; mi < 2; ++mi)
#pragma unroll
        for (int ni = 0; ni < 2; ++ni)
          acc[mi][ni] = __builtin_amdgcn_mfma_f32_32x32x16_bf16(af[mi], bf[ni], acc[mi][ni], 0, 0, 0);
    }
  }
  // epilogue: C/D layout col=lane&31, row=(r&3)+8*(r>>2)+4*(lane>>5)
#pragma unroll
  for (int mi = 0; mi < 2; ++mi)
#pragma unroll
  for (int ni = 0; ni < 2; ++ni) {
    int gcol = n0 + wn * 64 + ni * 32 + fr;
    float bsv = bias[gcol];
#pragma unroll
    for (int r = 0; r < 16; ++r) {
      int grow = m0 + wm * 64 + mi * 32 + (r & 3) + 8 * (r >> 2) + 4 * (l >> 5);
      float v = acc[mi][ni][r] + bsv;
      if (RELU) v = fmaxf(v, 0.0f);
      if (!SIX) {
        Cf[(size_t)grow * N + gcol] = v;
      } else {
        u16 h, mm, lo; split3(v, h, mm, lo);
        u16* q = C3 + (size_t)grow * 3 * N + gcol;
        q[0] = h; q[N] = mm; q[2 * N] = lo;
      }
    }
  }
}

// -------- weight conversion: W [K][N] f32 -> W3T [N][3K] bf16 planes --------
__global__ __launch_bounds__(256) void k_wconv(const float* __restrict__ W, u16* __restrict__ W3T,
                                               int K, int N) {
  __shared__ float t[64][65];
  const int k0 = blockIdx.y * 64, n0 = blockIdx.x * 64;
  const int tid = threadIdx.x;
  for (int i = tid; i < 4096; i += 256) {
    int kk = i >> 6, nn = i & 63;
    t[kk][nn] = W[(size_t)(k0 + kk) * N + (n0 + nn)];
  }
  __syncthreads();
  const int nn = tid >> 2, kc = (tid & 3) << 4;
  u16* base = W3T + (size_t)(n0 + nn) * 3 * K + (k0 + kc);
#pragma unroll
  for (int kk = 0; kk < 16; ++kk) {
    u16 h, m, lo; split3(t[kc + kk][nn], h, m, lo);
    base[kk] = h; base[K + kk] = m; base[2 * K + kk] = lo;
  }
}

// -------- activation conversion: X [rows][K] f32 -> X3 [rows][3K] planes --------
__global__ __launch_bounds__(256) void k_aconv(const float* __restrict__ X, u16* __restrict__ X3,
                                               int total, int kbits) {
  int i = blockIdx.x * 256 + threadIdx.x;
  if (i >= total) return;
  int K = 1 << kbits;
  int r = i >> kbits, k = i & (K - 1);
  u16 h, m, lo; split3(X[i], h, m, lo);
  u16* q = X3 + ((size_t)r * 3 << kbits) + k;
  q[0] = h; q[K] = m; q[2 * K] = lo;
}

// ------- eps/z for chunk batch: row = blockIdx.x in [0, NC*2048) -------
__global__ __launch_bounds__(256) void k_eps_z(const float* __restrict__ out_enc,
                                               u16* __restrict__ z3c,
                                               float* __restrict__ logpz,
                                               float* __restrict__ logq,
                                               int l0, u32 ke0, u32 ke1) {
  const int row = blockIdx.x;
  const int lb = l0 * 2048 + row;      // global (l,b) flat index
  const int b = row & 2047;
  const int d = threadIdx.x;
  const u32 m = ((u32)lb << 8) + (u32)d;
  float mu = out_enc[b * 512 + d];
  float sg = softplus_f(out_enc[b * 512 + 256 + d]);  // +1e-64 underflows in f32
  float e = normal_from_bits(prf32(ke0, ke1, m));
  float zz = mu + sg * e;
  u16 h, mm, lo; split3(zz, h, mm, lo);
  u16* q = z3c + row * 768 + d;
  q[0] = h; q[256] = mm; q[512] = lo;
  float t1 = -0.5f * e * e - logf(sg);
  float t2 = -0.5f * zz * zz;
#pragma unroll
  for (int o = 32; o; o >>= 1) { t1 += __shfl_down(t1, o); t2 += __shfl_down(t2, o); }
  __shared__ float sm1[4], sm2[4];
  int lane = d & 63, wv = d >> 6;
  if (!lane) { sm1[wv] = t1; sm2[wv] = t2; }
  __syncthreads();
  if (d == 0) {
    float a = sm1[0] + sm1[1] + sm1[2] + sm1[3];
    float qq = sm2[0] + sm2[1] + sm2[2] + sm2[3];
    logq[lb]  = a - 235.2482645003962f;   // 0.5*D*log(2*pi)
    logpz[lb] = qq - 235.2482645003962f;
  }
}

// ------- per-batch: logpxobs + t sampling + xms (bf16, missing entries) -------
__global__ __launch_bounds__(256) void k_logpx_xms(const float* __restrict__ odec,
                                                   const float* __restrict__ data,
                                                   const int* __restrict__ mask,
                                                   u16* __restrict__ xms,
                                                   float* __restrict__ lpxobs,
                                                   int l0, u32 kn0, u32 kn1, u32 kg0, u32 kg1) {
  const int row = blockIdx.x;
  const int lb = l0 * 2048 + row;
  const int b = row & 2047;
  const int tid = threadIdx.x;
  float lpsum = 0.0f;
  for (int j = 0; j < 4; ++j) {
    int p = tid + j * 256;
    float mean  = odec[(size_t)row * 3072 + p];
    float scale = softplus_f(odec[(size_t)row * 3072 + 1024 + p]) + 0.001f;
    float dfv   = softplus_f(odec[(size_t)row * 3072 + 2048 + p]) + 3.0f;
    u32 i = ((u32)lb << 10) + (u32)p;
    if (mask[b * 1024 + p]) {
      float x = data[b * 1024 + p];
      float y = (x - mean) / scale;
      float lp = lgammaf((dfv + 1.0f) * 0.5f) - lgammaf(dfv * 0.5f)
               - 0.5f * logf(dfv * 3.14159274f) - logf(scale)
               - 0.5f * (dfv + 1.0f) * log1pf(y * y / dfv);
      lpsum += lp;
    } else {
      float n = normal_from_bits(prf32(kn0, kn1, i));
      U2 gk = tf2x32(kg0, kg1, 0u, i);     // split(key_g, N)[i]
      float half_df = dfv * 0.5f;
      float g = gamma_sample(gk.a, gk.b, half_df);
      float t = n * sqrtf(half_df / g);
      xms[i] = f2bf(mean + scale * t);
    }
  }
#pragma unroll
  for (int o = 32; o; o >>= 1) lpsum += __shfl_down(lpsum, o);
  __shared__ float sm[4];
  int lane = tid & 63, wv = tid >> 6;
  if (!lane) sm[wv] = lpsum;
  __syncthreads();
  if (tid == 0) lpxobs[lb] = sm[0] + sm[1] + sm[2] + sm[3];
}

// --------------- importance weights: softmax over L=10 ---------------
__global__ __launch_bounds__(256) void k_impw(const float* __restrict__ lpx,
                                              const float* __restrict__ lpz,
                                              const float* __restrict__ lq,
                                              float* __restrict__ w) {
  int b = blockIdx.x * 256 + threadIdx.x;
  float s[10], mx = -INFINITY;
#pragma unroll
  for (int l = 0; l < 10; ++l) {
    s[l] = lpx[l * 2048 + b] + lpz[l * 2048 + b] - lq[l * 2048 + b];
    mx = fmaxf(mx, s[l]);
  }
  float se = 0.0f;
#pragma unroll
  for (int l = 0; l < 10; ++l) { s[l] = expf(s[l] - mx); se += s[l]; }
#pragma unroll
  for (int l = 0; l < 10; ++l) w[l * 2048 + b] = s[l] / se;
}

// ------- xm + data_imputed (+ 3-plane split for classifier input) -------
__global__ __launch_bounds__(256) void k_xm(const int* __restrict__ mask,
                                            const float* __restrict__ data,
                                            const float* __restrict__ impw,
                                            const u16* __restrict__ xms,
                                            u16* __restrict__ imp3,
                                            float* __restrict__ out) {
  int idx = blockIdx.x * 256 + threadIdx.x;
  int b = idx >> 10, p = idx & 1023;
  float o;
  if (mask[idx]) {
    o = data[idx];
  } else {
    float acc = 0.0f;
#pragma unroll
    for (int l = 0; l < 10; ++l)
      acc += impw[l * 2048 + b] * bf2f(xms[((size_t)l * 2048 + b) * 1024 + p]);
    o = acc;
  }
  out[idx] = o;
  u16 h, m, lo; split3(o, h, m, lo);
  u16* q = imp3 + (size_t)b * 3072 + p;
  q[0] = h; q[1024] = m; q[2048] = lo;
}

// --------------- classifier head: logits (N=10) ---------------
__global__ __launch_bounds__(256) void k_cls2(const float* __restrict__ hc,
                                              const float* __restrict__ w2,
                                              const float* __restrict__ b2,
                                              float* __restrict__ out) {
  int b = blockIdx.x, tid = threadIdx.x;
  float acc[10];
#pragma unroll
  for (int c = 0; c < 10; ++c) acc[c] = 0.0f;
  for (int k = tid; k < 2048; k += 256) {
    float h = hc[(size_t)b * 2048 + k];
#pragma unroll
    for (int c = 0; c < 10; ++c) acc[c] = fmaf(h, w2[k * 10 + c], acc[c]);
  }
  __shared__ float red[4][10];
  int lane = tid & 63, wv = tid >> 6;
#pragma unroll
  for (int c = 0; c < 10; ++c) {
    float v = acc[c];
#pragma unroll
    for (int o = 32; o; o >>= 1) v += __shfl_down(v, o);
    if (!lane) red[wv][c] = v;
  }
  __syncthreads();
  if (tid < 10) out[b * 10 + tid] = red[0][tid] + red[1][tid] + red[2][tid] + red[3][tid] + b2[tid];
}

extern "C" void kernel_launch(void* const* d_in, const int* in_sizes, int n_in,
                              void* d_out, int out_size, void* d_ws, size_t ws_size,
                              hipStream_t stream) {
  const float* data   = (const float*)d_in[0];
  const int*   mask   = (const int*)d_in[1];
  const float* enc_w1 = (const float*)d_in[2];
  const float* enc_b1 = (const float*)d_in[3];
  const float* enc_w2 = (const float*)d_in[4];
  const float* enc_b2 = (const float*)d_in[5];
  const float* dec_w1 = (const float*)d_in[6];
  const float* dec_b1 = (const float*)d_in[7];
  const float* dec_w2 = (const float*)d_in[8];
  const float* dec_b2 = (const float*)d_in[9];
  const float* cls_w1 = (const float*)d_in[10];
  const float* cls_b1 = (const float*)d_in[11];
  const float* cls_w2 = (const float*)d_in[12];
  const float* cls_b2 = (const float*)d_in[13];

  float* out = (float*)d_out;   // [2048*1024 data_imputed | 2048*10 logits]
  char* wsb = (char*)d_ws;

  if (ws_size < 165675008ULL) return;  // below proven-safe minimum: bail gracefully

  // 2-chunk decoder batching needs ~215.3 MiB; fall back to proven 158 MiB layout otherwise.
  const bool big = ws_size >= 225771520ULL;
  const int NC = big ? 2 : 1;

  u16 *xmsu, *w_d2, *w_d1, *hx3, *z3c, *data3, *imp3, *w_ec, *w_e2;
  float *odec, *hc, *logpz, *logq, *lpxobs, *impw, *out_enc;
  if (big) {
    xmsu   = (u16*)(wsb + 0);              // [10*2048][1024] bf16  (40 MiB)
    w_d2   = (u16*)(wsb + 41943040);       // [3072][3*2048]        (36 MiB)
    w_d1   = (u16*)(wsb + 79691776);       // [2048][3*256]         (3 MiB)
    hx3    = (u16*)(wsb + 82837504);       // [4096][3*2048]        (48 MiB)
    odec   = (float*)(wsb + 133169152);    // [4096][3072] f32      (48 MiB)
    z3c    = (u16*)(wsb + 183500800);      // [4096][3*256]         (6 MiB)
    data3  = (u16*)(wsb + 189792256);      // [2048][3*1024]        (12 MiB)
    w_ec   = (u16*)(wsb + 202375168);      // [2048][3*1024]        (12 MiB)
    w_e2   = (u16*)(wsb + 214958080);      // [512][3*2048]         (6 MiB)
    logpz  = (float*)(wsb + 221249536);
    logq   = (float*)(wsb + 221331456);
    lpxobs = (float*)(wsb + 221413376);
    impw   = (float*)(wsb + 221495296);
    out_enc= (float*)(wsb + 221577216);    // [2048][512] f32       (4 MiB)
  } else {
    xmsu   = (u16*)(wsb + 0);
    w_d2   = (u16*)(wsb + 41943040);
    hx3    = (u16*)(wsb + 79691776);       // [2048][3*2048]        (24 MiB)
    odec   = (float*)(wsb + 104857600);    // [2048][3072] f32      (24 MiB)
    data3  = (u16*)(wsb + 130023424);
    z3c    = (u16*)(wsb + 130023424);      // overlays data3 (post-enc1)
    w_d1   = (u16*)(wsb + 133169152);      // overlays data3 (post-enc1)
    w_ec   = (u16*)(wsb + 142606336);
    w_e2   = (u16*)(wsb + 155189248);
    logpz  = (float*)(wsb + 155189248);    // overlays w_e2 (dead after enc2)
    logq   = (float*)(wsb + 155271168);
    lpxobs = (float*)(wsb + 155353088);
    impw   = (float*)(wsb + 155435008);
    out_enc= (float*)(wsb + 161480704);
  }
  hc   = odec;    // reuse [2048][2048] f32
  imp3 = data3;   // reuse (z3c/w_d1 dead by then in small layout)

  // key(42)=(0,42); k_eps=PRF(key,0), k_t=PRF(key,1); key_n=PRF(k_t,0), key_g=PRF(k_t,1)
  U2 ke = tf2x32(0u, 42u, 0u, 0u);
  U2 kt = tf2x32(0u, 42u, 0u, 1u);
  U2 kn = tf2x32(kt.a, kt.b, 0u, 0u);
  U2 kg = tf2x32(kt.a, kt.b, 0u, 1u);

  dim3 blk(256);
  // conversions needed before encoder
  k_aconv<<<8192, blk, 0, stream>>>(data, data3, 2097152, 10);
  k_wconv<<<dim3(32, 16), blk, 0, stream>>>(enc_w1, w_ec, 1024, 2048);
  k_wconv<<<dim3(8, 32),  blk, 0, stream>>>(enc_w2, w_e2, 2048, 512);
  k_wconv<<<dim3(48, 32), blk, 0, stream>>>(dec_w2, w_d2, 2048, 3072);

  // encoder
  gemm_s3<true,  true ><<<dim3(16, 16), blk, 0, stream>>>(data3, w_ec, enc_b1, nullptr, hx3, 2048, 10);
  gemm_s3<false, false><<<dim3(4, 16),  blk, 0, stream>>>(hx3, w_e2, enc_b2, out_enc, nullptr, 512, 11);

  // dec_w1 conversion (in small layout its slot overlays data3, which is dead after enc1)
  k_wconv<<<dim3(32, 4), blk, 0, stream>>>(dec_w1, w_d1, 256, 2048);

  // decoder: NC l-chunks (M = NC*2048) per iteration
  for (int l0 = 0; l0 < 10; l0 += NC) {
    k_eps_z<<<2048 * NC, blk, 0, stream>>>(out_enc, z3c, logpz, logq, l0, ke.a, ke.b);
    gemm_s3<true,  true ><<<dim3(16, 16 * NC), blk, 0, stream>>>(z3c, w_d1, dec_b1, nullptr, hx3, 2048, 8);
    gemm_s3<false, false><<<dim3(24, 16 * NC), blk, 0, stream>>>(hx3, w_d2, dec_b2, odec, nullptr, 3072, 11);
    k_logpx_xms<<<2048 * NC, blk, 0, stream>>>(odec, data, mask, xmsu, lpxobs, l0, kn.a, kn.b, kg.a, kg.b);
  }

  // importance weights + imputation
  k_impw<<<8, blk, 0, stream>>>(lpxobs, logpz, logq, impw);
  k_xm<<<8192, blk, 0, stream>>>(mask, data, impw, xmsu, imp3, out);

  // classifier (re-convert cls_w1 into w_ec slot)
  k_wconv<<<dim3(32, 16), blk, 0, stream>>>(cls_w1, w_ec, 1024, 2048);
  gemm_s3<true, false><<<dim3(16, 16), blk, 0, stream>>>(imp3, w_ec, cls_b1, hc, nullptr, 2048, 10);
  k_cls2<<<2048, blk, 0, stream>>>(hc, cls_w2, cls_b2, out + 2048 * 1024);
}

// Round 6
// 2135.744 us; speedup vs baseline: 2.3858x; 1.5019x over previous
//
#include <hip/hip_runtime.h>
#include <math.h>

typedef unsigned int u32;
typedef unsigned short u16;
typedef __attribute__((ext_vector_type(8))) short bf16x8;
typedef __attribute__((ext_vector_type(16))) float f32x16;

struct U2 { u32 a, b; };

// Threefry-2x32, 20 rounds — matches jax._src.prng.threefry2x32 exactly.
__host__ __device__ __forceinline__ U2 tf2x32(u32 k0, u32 k1, u32 c0, u32 c1) {
  u32 ks2 = k0 ^ k1 ^ 0x1BD11BDAu;
  u32 x0 = c0 + k0, x1 = c1 + k1;
#define TFR(r) { x0 += x1; x1 = (x1 << (r)) | (x1 >> (32 - (r))); x1 ^= x0; }
  TFR(13) TFR(15) TFR(26) TFR(6)
  x0 += k1; x1 += ks2 + 1u;
  TFR(17) TFR(29) TFR(16) TFR(24)
  x0 += ks2; x1 += k0 + 2u;
  TFR(13) TFR(15) TFR(26) TFR(6)
  x0 += k0; x1 += k1 + 3u;
  TFR(17) TFR(29) TFR(16) TFR(24)
  x0 += k1; x1 += ks2 + 4u;
  TFR(13) TFR(15) TFR(26) TFR(6)
  x0 += ks2; x1 += k0 + 5u;
#undef TFR
  return {x0, x1};
}

// jax_threefry_partitionable=True:
// random_bits(key,32,shape)[i] = b1^b2 at counter (0,i); split(key,n)[i] = pair at counter i.
__host__ __device__ __forceinline__ u32 prf32(u32 k0, u32 k1, u32 i) {
  U2 r = tf2x32(k0, k1, 0u, i);
  return r.a ^ r.b;
}

__device__ __forceinline__ float u01_from_bits(u32 bits) {
  u32 r = (bits >> 9) | 0x3f800000u;
  return __uint_as_float(r) - 1.0f;
}

// XLA ErfInv f32 (Giles polynomial)
__device__ __forceinline__ float erfinv_f32(float x) {
  float w = -log1pf(-x * x);
  float p;
  if (w < 5.0f) {
    w -= 2.5f;
    p = 2.81022636e-08f;
    p = fmaf(p, w, 3.43273939e-07f);
    p = fmaf(p, w, -3.5233877e-06f);
    p = fmaf(p, w, -4.39150654e-06f);
    p = fmaf(p, w, 0.00021858087f);
    p = fmaf(p, w, -0.00125372503f);
    p = fmaf(p, w, -0.00417768164f);
    p = fmaf(p, w, 0.246640727f);
    p = fmaf(p, w, 1.50140941f);
  } else {
    w = sqrtf(w) - 3.0f;
    p = -0.000200214257f;
    p = fmaf(p, w, 0.000100950558f);
    p = fmaf(p, w, 0.00134934322f);
    p = fmaf(p, w, -0.00367342844f);
    p = fmaf(p, w, 0.00573950773f);
    p = fmaf(p, w, -0.0076224613f);
    p = fmaf(p, w, 0.00943887047f);
    p = fmaf(p, w, 1.00167406f);
    p = fmaf(p, w, 2.83297682f);
  }
  return p * x;
}

__device__ __forceinline__ float normal_from_bits(u32 bits) {
  const float lo = -0.99999994f;
  float u = u01_from_bits(bits) * 2.0f + lo;
  u = fmaxf(lo, u);
  return 1.41421356237f * erfinv_f32(u);
}

__device__ __forceinline__ float softplus_f(float x) {
  return fmaxf(x, 0.0f) + log1pf(expf(-fabsf(x)));
}

// jax.random._gamma_one for alpha >= 1 (boost == 1), partitionable keys.
// Validated rounds 2/4/5 (absmax 0.5/0.25/0.25).
__device__ float gamma_sample(u32 k0, u32 k1, float alpha) {
  U2 kk = tf2x32(k0, k1, 0u, 0u);   // key, subkey = split(key) [u_boost consumed]
  k0 = kk.a; k1 = kk.b;
  float d = alpha - 0.33333334f;
  float c = 0.33333334f / sqrtf(d);
  float X, V, U;
  do {
    U2 nk = tf2x32(k0, k1, 0u, 0u);
    U2 xk = tf2x32(k0, k1, 0u, 1u);
    U2 uk = tf2x32(k0, k1, 0u, 2u);
    k0 = nk.a; k1 = nk.b;
    u32 xk0 = xk.a, xk1 = xk.b;
    float x, v;
    do {
      U2 nxt = tf2x32(xk0, xk1, 0u, 0u);
      U2 sub = tf2x32(xk0, xk1, 0u, 1u);
      xk0 = nxt.a; xk1 = nxt.b;
      x = normal_from_bits(prf32(sub.a, sub.b, 0u));
      v = 1.0f + x * c;
    } while (v <= 0.0f);
    X = x * x;
    V = (v * v) * v;
    U = u01_from_bits(prf32(uk.a, uk.b, 0u));
  } while (U >= 1.0f - 0.0331f * (X * X) &&
           logf(U) >= 0.5f * X + d * ((1.0f - V) + logf(V)));
  return d * V;
}

// ---------------- bf16 split-2 helpers ----------------
__device__ __forceinline__ u16 f2bf(float f) {
  u32 u = __float_as_uint(f);
  u32 r = ((u >> 16) & 1u) + 0x7fffu;
  return (u16)((u + r) >> 16);
}
__device__ __forceinline__ float bf2f(u16 h) { return __uint_as_float(((u32)h) << 16); }

__device__ __forceinline__ void split2(float v, u16& h, u16& m) {
  h = f2bf(v);
  m = f2bf(v - bf2f(h));   // residual exact; |v-h-m| <= 2^-18 |v|
}

#define GLOAD16(gp, lp) __builtin_amdgcn_global_load_lds( \
    (const __attribute__((address_space(1))) void*)(gp),  \
    (__attribute__((address_space(3))) void*)(lp), 16, 0, 0)

// ---------------- split-2 bf16 MFMA GEMM (slot-major planes) ----------------
// A2 [M][2K] rm (planes h|m), B2T [N][2K] rm (planes h|m), bias[N] f32.
// Virtual K3=3K; slot s = vk/K: pa = s>>1 {h,h,m}, pb = s&1 {h,m,h}
// -> products hh,hm,mh (error ~3*2^-18, same order as f32-accum noise).
// 128x128 tile, BK=64, 4 waves, 32x32x16 bf16 MFMA, XOR-swizzled LDS (T2).
template<bool RELU, bool SIX>
__global__ __launch_bounds__(256, 3) void gemm_s3(const u16* __restrict__ A2,
                                                  const u16* __restrict__ B2T,
                                                  const float* __restrict__ bias,
                                                  float* __restrict__ Cf,
                                                  u16* __restrict__ C2,
                                                  int N, int kbits) {
  __shared__ u16 As[128 * 64];
  __shared__ u16 Bs[128 * 64];
  const int tid = threadIdx.x;
  const int l = tid & 63, w = tid >> 6;
  const int m0 = blockIdx.y * 128, n0 = blockIdx.x * 128;
  const int K2 = 2 << kbits;
  // staging: per-lane inverse-swizzled source column (16B blocks)
  const int srow = l >> 3;
  const int scol = ((l & 7) ^ srow) << 3;
  const u16* agr[4]; const u16* bgr[4]; u16* al[4]; u16* bl[4];
#pragma unroll
  for (int j = 0; j < 4; ++j) {
    int r = w * 32 + j * 8 + srow;
    agr[j] = A2 + (size_t)(m0 + r) * K2 + scol;
    bgr[j] = B2T + (size_t)(n0 + r) * K2 + scol;
    al[j] = &As[(w * 4 + j) * 512];
    bl[j] = &Bs[(w * 4 + j) * 512];
  }
  f32x16 acc[2][2] = {};
  const int fr = l & 31;
  const int wm = w >> 1, wn = w & 1;
  const int swz = (l & 7) << 4;
  const int hk16 = (l >> 5) << 4;
  const int nk = 3 << (kbits - 6);
  const int kmask = (1 << kbits) - 1;
  for (int kt = 0; kt < nk; ++kt) {
    int vb = kt << 6;
    int s = vb >> kbits;       // 0,1,2
    int ko = vb & kmask;
    int ao = ((s >> 1) << kbits) + ko;   // A plane {h,h,m}
    int bo = ((s & 1) << kbits) + ko;    // B plane {h,m,h}
    __syncthreads();   // previous tile consumed
#pragma unroll
    for (int j = 0; j < 4; ++j) {
      GLOAD16(agr[j] + ao, al[j]);
      GLOAD16(bgr[j] + bo, bl[j]);
    }
    __syncthreads();   // compiler drains vmcnt(0) before barrier: tile ready
#pragma unroll
    for (int ks = 0; ks < 4; ++ks) {
      bf16x8 af[2], bf[2];
#pragma unroll
      for (int mi = 0; mi < 2; ++mi) {
        int ar = wm * 64 + mi * 32 + fr;
        af[mi] = *(const bf16x8*)((const char*)As + ar * 128 + ((ks * 32 + hk16) ^ swz));
      }
#pragma unroll
      for (int ni = 0; ni < 2; ++ni) {
        int br = wn * 64 + ni * 32 + fr;
        bf[ni] = *(const bf16x8*)((const char*)Bs + br * 128 + ((ks * 32 + hk16) ^ swz));
      }
#pragma unroll
      for (int mi = 0; mi < 2; ++mi)
#pragma unroll
        for (int ni = 0; ni < 2; ++ni)
          acc[mi][ni] = __builtin_amdgcn_mfma_f32_32x32x16_bf16(af[mi], bf[ni], acc[mi][ni], 0, 0, 0);
    }
  }
  // epilogue: C/D layout col=lane&31, row=(r&3)+8*(r>>2)+4*(lane>>5)
#pragma unroll
  for (int mi = 0; mi < 2; ++mi)
#pragma unroll
  for (int ni = 0; ni < 2; ++ni) {
    int gcol = n0 + wn * 64 + ni * 32 + fr;
    float bsv = bias[gcol];
#pragma unroll
    for (int r = 0; r < 16; ++r) {
      int grow = m0 + wm * 64 + mi * 32 + (r & 3) + 8 * (r >> 2) + 4 * (l >> 5);
      float v = acc[mi][ni][r] + bsv;
      if (RELU) v = fmaxf(v, 0.0f);
      if (!SIX) {
        Cf[(size_t)grow * N + gcol] = v;
      } else {
        u16 h, mm; split2(v, h, mm);
        u16* q = C2 + (size_t)grow * 2 * N + gcol;
        q[0] = h; q[N] = mm;
      }
    }
  }
}

// -------- weight conversion: W [K][N] f32 -> W2T [N][2K] bf16 planes --------
__global__ __launch_bounds__(256) void k_wconv(const float* __restrict__ W, u16* __restrict__ W2T,
                                               int K, int N) {
  __shared__ float t[64][65];
  const int k0 = blockIdx.y * 64, n0 = blockIdx.x * 64;
  const int tid = threadIdx.x;
  for (int i = tid; i < 4096; i += 256) {
    int kk = i >> 6, nn = i & 63;
    t[kk][nn] = W[(size_t)(k0 + kk) * N + (n0 + nn)];
  }
  __syncthreads();
  const int nn = tid >> 2, kc = (tid & 3) << 4;
  u16* base = W2T + (size_t)(n0 + nn) * 2 * K + (k0 + kc);
#pragma unroll
  for (int kk = 0; kk < 16; ++kk) {
    u16 h, m; split2(t[kc + kk][nn], h, m);
    base[kk] = h; base[K + kk] = m;
  }
}

// -------- activation conversion: X [rows][K] f32 -> X2 [rows][2K] planes --------
__global__ __launch_bounds__(256) void k_aconv(const float* __restrict__ X, u16* __restrict__ X2,
                                               int total, int kbits) {
  int i = blockIdx.x * 256 + threadIdx.x;
  if (i >= total) return;
  int K = 1 << kbits;
  int r = i >> kbits, k = i & (K - 1);
  u16 h, m; split2(X[i], h, m);
  u16* q = X2 + ((size_t)r * 2 << kbits) + k;
  q[0] = h; q[K] = m;
}

// ------- eps/z for chunk batch: row = blockIdx.x in [0, NC*2048) -------
__global__ __launch_bounds__(256) void k_eps_z(const float* __restrict__ out_enc,
                                               u16* __restrict__ z2c,
                                               float* __restrict__ logpz,
                                               float* __restrict__ logq,
                                               int l0, u32 ke0, u32 ke1) {
  const int row = blockIdx.x;
  const int lb = l0 * 2048 + row;      // global (l,b) flat index
  const int b = row & 2047;
  const int d = threadIdx.x;
  const u32 m = ((u32)lb << 8) + (u32)d;
  float mu = out_enc[b * 512 + d];
  float sg = softplus_f(out_enc[b * 512 + 256 + d]);  // +1e-64 underflows in f32
  float e = normal_from_bits(prf32(ke0, ke1, m));
  float zz = mu + sg * e;
  u16 h, mm; split2(zz, h, mm);
  u16* q = z2c + row * 512 + d;
  q[0] = h; q[256] = mm;
  float t1 = -0.5f * e * e - logf(sg);
  float t2 = -0.5f * zz * zz;
#pragma unroll
  for (int o = 32; o; o >>= 1) { t1 += __shfl_down(t1, o); t2 += __shfl_down(t2, o); }
  __shared__ float sm1[4], sm2[4];
  int lane = d & 63, wv = d >> 6;
  if (!lane) { sm1[wv] = t1; sm2[wv] = t2; }
  __syncthreads();
  if (d == 0) {
    float a = sm1[0] + sm1[1] + sm1[2] + sm1[3];
    float qq = sm2[0] + sm2[1] + sm2[2] + sm2[3];
    logq[lb]  = a - 235.2482645003962f;   // 0.5*D*log(2*pi)
    logpz[lb] = qq - 235.2482645003962f;
  }
}

// ------- per-batch: logpxobs + t sampling + xms (bf16, missing entries) -------
__global__ __launch_bounds__(256) void k_logpx_xms(const float* __restrict__ odec,
                                                   const float* __restrict__ data,
                                                   const int* __restrict__ mask,
                                                   u16* __restrict__ xms,
                                                   float* __restrict__ lpxobs,
                                                   int l0, u32 kn0, u32 kn1, u32 kg0, u32 kg1) {
  const int row = blockIdx.x;
  const int lb = l0 * 2048 + row;
  const int b = row & 2047;
  const int tid = threadIdx.x;
  float lpsum = 0.0f;
  for (int j = 0; j < 4; ++j) {
    int p = tid + j * 256;
    float mean  = odec[(size_t)row * 3072 + p];
    float scale = softplus_f(odec[(size_t)row * 3072 + 1024 + p]) + 0.001f;
    float dfv   = softplus_f(odec[(size_t)row * 3072 + 2048 + p]) + 3.0f;
    u32 i = ((u32)lb << 10) + (u32)p;
    if (mask[b * 1024 + p]) {
      float x = data[b * 1024 + p];
      float y = (x - mean) / scale;
      float lp = lgammaf((dfv + 1.0f) * 0.5f) - lgammaf(dfv * 0.5f)
               - 0.5f * logf(dfv * 3.14159274f) - logf(scale)
               - 0.5f * (dfv + 1.0f) * log1pf(y * y / dfv);
      lpsum += lp;
    } else {
      float n = normal_from_bits(prf32(kn0, kn1, i));
      U2 gk = tf2x32(kg0, kg1, 0u, i);     // split(key_g, N)[i]
      float half_df = dfv * 0.5f;
      float g = gamma_sample(gk.a, gk.b, half_df);
      float t = n * sqrtf(half_df / g);
      xms[i] = f2bf(mean + scale * t);
    }
  }
#pragma unroll
  for (int o = 32; o; o >>= 1) lpsum += __shfl_down(lpsum, o);
  __shared__ float sm[4];
  int lane = tid & 63, wv = tid >> 6;
  if (!lane) sm[wv] = lpsum;
  __syncthreads();
  if (tid == 0) lpxobs[lb] = sm[0] + sm[1] + sm[2] + sm[3];
}

// --------------- importance weights: softmax over L=10 ---------------
__global__ __launch_bounds__(256) void k_impw(const float* __restrict__ lpx,
                                              const float* __restrict__ lpz,
                                              const float* __restrict__ lq,
                                              float* __restrict__ w) {
  int b = blockIdx.x * 256 + threadIdx.x;
  float s[10], mx = -INFINITY;
#pragma unroll
  for (int l = 0; l < 10; ++l) {
    s[l] = lpx[l * 2048 + b] + lpz[l * 2048 + b] - lq[l * 2048 + b];
    mx = fmaxf(mx, s[l]);
  }
  float se = 0.0f;
#pragma unroll
  for (int l = 0; l < 10; ++l) { s[l] = expf(s[l] - mx); se += s[l]; }
#pragma unroll
  for (int l = 0; l < 10; ++l) w[l * 2048 + b] = s[l] / se;
}

// ------- xm + data_imputed (+ 2-plane split for classifier input) -------
__global__ __launch_bounds__(256) void k_xm(const int* __restrict__ mask,
                                            const float* __restrict__ data,
                                            const float* __restrict__ impw,
                                            const u16* __restrict__ xms,
                                            u16* __restrict__ imp2,
                                            float* __restrict__ out) {
  int idx = blockIdx.x * 256 + threadIdx.x;
  int b = idx >> 10, p = idx & 1023;
  float o;
  if (mask[idx]) {
    o = data[idx];
  } else {
    float acc = 0.0f;
#pragma unroll
    for (int l = 0; l < 10; ++l)
      acc += impw[l * 2048 + b] * bf2f(xms[((size_t)l * 2048 + b) * 1024 + p]);
    o = acc;
  }
  out[idx] = o;
  u16 h, m; split2(o, h, m);
  u16* q = imp2 + (size_t)b * 2048 + p;
  q[0] = h; q[1024] = m;
}

// --------------- classifier head: logits (N=10) ---------------
__global__ __launch_bounds__(256) void k_cls2(const float* __restrict__ hc,
                                              const float* __restrict__ w2,
                                              const float* __restrict__ b2,
                                              float* __restrict__ out) {
  int b = blockIdx.x, tid = threadIdx.x;
  float acc[10];
#pragma unroll
  for (int c = 0; c < 10; ++c) acc[c] = 0.0f;
  for (int k = tid; k < 2048; k += 256) {
    float h = hc[(size_t)b * 2048 + k];
#pragma unroll
    for (int c = 0; c < 10; ++c) acc[c] = fmaf(h, w2[k * 10 + c], acc[c]);
  }
  __shared__ float red[4][10];
  int lane = tid & 63, wv = tid >> 6;
#pragma unroll
  for (int c = 0; c < 10; ++c) {
    float v = acc[c];
#pragma unroll
    for (int o = 32; o; o >>= 1) v += __shfl_down(v, o);
    if (!lane) red[wv][c] = v;
  }
  __syncthreads();
  if (tid < 10) out[b * 10 + tid] = red[0][tid] + red[1][tid] + red[2][tid] + red[3][tid] + b2[tid];
}

extern "C" void kernel_launch(void* const* d_in, const int* in_sizes, int n_in,
                              void* d_out, int out_size, void* d_ws, size_t ws_size,
                              hipStream_t stream) {
  const float* data   = (const float*)d_in[0];
  const int*   mask   = (const int*)d_in[1];
  const float* enc_w1 = (const float*)d_in[2];
  const float* enc_b1 = (const float*)d_in[3];
  const float* enc_w2 = (const float*)d_in[4];
  const float* enc_b2 = (const float*)d_in[5];
  const float* dec_w1 = (const float*)d_in[6];
  const float* dec_b1 = (const float*)d_in[7];
  const float* dec_w2 = (const float*)d_in[8];
  const float* dec_b2 = (const float*)d_in[9];
  const float* cls_w1 = (const float*)d_in[10];
  const float* cls_b1 = (const float*)d_in[11];
  const float* cls_w2 = (const float*)d_in[12];
  const float* cls_b2 = (const float*)d_in[13];

  float* out = (float*)d_out;   // [2048*1024 data_imputed | 2048*10 logits]
  char* wsb = (char*)d_ws;

  // Round-5 ran the big branch -> ws_size >= 225,771,520 proven. This layout: 174.3 MB.
  if (ws_size < 182779904ULL) return;

  u16*   xmsu   = (u16*)(wsb + 0);              // [10*2048][1024] bf16  (40 MiB)
  u16*   w_d2   = (u16*)(wsb + 41943040);       // [3072][2*2048]        (24 MiB)
  u16*   w_d1   = (u16*)(wsb + 67108864);       // [2048][2*256]         (2 MiB)
  u16*   hx2    = (u16*)(wsb + 69206016);       // [4096][2*2048]        (32 MiB)
  float* odec   = (float*)(wsb + 102760448);    // [4096][3072] f32      (48 MiB)
  u16*   z2c    = (u16*)(wsb + 153092096);      // [4096][2*256]         (4 MiB)
  u16*   data2  = (u16*)(wsb + 157286400);      // [2048][2*1024]        (8 MiB)
  u16*   w_ec   = (u16*)(wsb + 165675008);      // w_e1/w_c1 [2048][2*1024] (8 MiB)
  u16*   w_e2   = (u16*)(wsb + 174063616);      // [512][2*2048]         (4 MiB)
  float* logpz  = (float*)(wsb + 178257920);
  float* logq   = (float*)(wsb + 178339840);
  float* lpxobs = (float*)(wsb + 178421760);
  float* impw   = (float*)(wsb + 178503680);
  float* out_enc= (float*)(wsb + 178585600);    // [2048][512] f32       (4 MiB)
  float* hc     = odec;    // reuse [2048][2048] f32
  u16*   imp2   = data2;   // reuse

  // key(42)=(0,42); k_eps=PRF(key,0), k_t=PRF(key,1); key_n=PRF(k_t,0), key_g=PRF(k_t,1)
  U2 ke = tf2x32(0u, 42u, 0u, 0u);
  U2 kt = tf2x32(0u, 42u, 0u, 1u);
  U2 kn = tf2x32(kt.a, kt.b, 0u, 0u);
  U2 kg = tf2x32(kt.a, kt.b, 0u, 1u);

  dim3 blk(256);
  // conversions needed before encoder
  k_aconv<<<8192, blk, 0, stream>>>(data, data2, 2097152, 10);
  k_wconv<<<dim3(32, 16), blk, 0, stream>>>(enc_w1, w_ec, 1024, 2048);
  k_wconv<<<dim3(8, 32),  blk, 0, stream>>>(enc_w2, w_e2, 2048, 512);
  k_wconv<<<dim3(48, 32), blk, 0, stream>>>(dec_w2, w_d2, 2048, 3072);
  k_wconv<<<dim3(32, 4),  blk, 0, stream>>>(dec_w1, w_d1, 256, 2048);

  // encoder
  gemm_s3<true,  true ><<<dim3(16, 16), blk, 0, stream>>>(data2, w_ec, enc_b1, nullptr, hx2, 2048, 10);
  gemm_s3<false, false><<<dim3(4, 16),  blk, 0, stream>>>(hx2, w_e2, enc_b2, out_enc, nullptr, 512, 11);

  // decoder: 2 l-chunks (M = 4096) per iteration
  for (int l0 = 0; l0 < 10; l0 += 2) {
    k_eps_z<<<4096, blk, 0, stream>>>(out_enc, z2c, logpz, logq, l0, ke.a, ke.b);
    gemm_s3<true,  true ><<<dim3(16, 32), blk, 0, stream>>>(z2c, w_d1, dec_b1, nullptr, hx2, 2048, 8);
    gemm_s3<false, false><<<dim3(24, 32), blk, 0, stream>>>(hx2, w_d2, dec_b2, odec, nullptr, 3072, 11);
    k_logpx_xms<<<4096, blk, 0, stream>>>(odec, data, mask, xmsu, lpxobs, l0, kn.a, kn.b, kg.a, kg.b);
  }

  // importance weights + imputation
  k_impw<<<8, blk, 0, stream>>>(lpxobs, logpz, logq, impw);
  k_xm<<<8192, blk, 0, stream>>>(mask, data, impw, xmsu, imp2, out);

  // classifier (re-convert cls_w1 into w_ec slot)
  k_wconv<<<dim3(32, 16), blk, 0, stream>>>(cls_w1, w_ec, 1024, 2048);
  gemm_s3<true, false><<<dim3(16, 16), blk, 0, stream>>>(imp2, w_ec, cls_b1, hc, nullptr, 2048, 10);
  k_cls2<<<2048, blk, 0, stream>>>(hc, cls_w2, cls_b2, out + 2048 * 1024);
}

// Round 7
// 1985.268 us; speedup vs baseline: 2.5666x; 1.0758x over previous
//
#include <hip/hip_runtime.h>
#include <math.h>

typedef unsigned int u32;
typedef unsigned short u16;
typedef __attribute__((ext_vector_type(8))) short bf16x8;
typedef __attribute__((ext_vector_type(16))) float f32x16;

struct U2 { u32 a, b; };

// Threefry-2x32, 20 rounds — matches jax._src.prng.threefry2x32 exactly.
__host__ __device__ __forceinline__ U2 tf2x32(u32 k0, u32 k1, u32 c0, u32 c1) {
  u32 ks2 = k0 ^ k1 ^ 0x1BD11BDAu;
  u32 x0 = c0 + k0, x1 = c1 + k1;
#define TFR(r) { x0 += x1; x1 = (x1 << (r)) | (x1 >> (32 - (r))); x1 ^= x0; }
  TFR(13) TFR(15) TFR(26) TFR(6)
  x0 += k1; x1 += ks2 + 1u;
  TFR(17) TFR(29) TFR(16) TFR(24)
  x0 += ks2; x1 += k0 + 2u;
  TFR(13) TFR(15) TFR(26) TFR(6)
  x0 += k0; x1 += k1 + 3u;
  TFR(17) TFR(29) TFR(16) TFR(24)
  x0 += k1; x1 += ks2 + 4u;
  TFR(13) TFR(15) TFR(26) TFR(6)
  x0 += ks2; x1 += k0 + 5u;
#undef TFR
  return {x0, x1};
}

// jax_threefry_partitionable=True:
// random_bits(key,32,shape)[i] = b1^b2 at counter (0,i); split(key,n)[i] = pair at counter i.
__host__ __device__ __forceinline__ u32 prf32(u32 k0, u32 k1, u32 i) {
  U2 r = tf2x32(k0, k1, 0u, i);
  return r.a ^ r.b;
}

__device__ __forceinline__ float u01_from_bits(u32 bits) {
  u32 r = (bits >> 9) | 0x3f800000u;
  return __uint_as_float(r) - 1.0f;
}

// XLA ErfInv f32 (Giles polynomial)
__device__ __forceinline__ float erfinv_f32(float x) {
  float w = -log1pf(-x * x);
  float p;
  if (w < 5.0f) {
    w -= 2.5f;
    p = 2.81022636e-08f;
    p = fmaf(p, w, 3.43273939e-07f);
    p = fmaf(p, w, -3.5233877e-06f);
    p = fmaf(p, w, -4.39150654e-06f);
    p = fmaf(p, w, 0.00021858087f);
    p = fmaf(p, w, -0.00125372503f);
    p = fmaf(p, w, -0.00417768164f);
    p = fmaf(p, w, 0.246640727f);
    p = fmaf(p, w, 1.50140941f);
  } else {
    w = sqrtf(w) - 3.0f;
    p = -0.000200214257f;
    p = fmaf(p, w, 0.000100950558f);
    p = fmaf(p, w, 0.00134934322f);
    p = fmaf(p, w, -0.00367342844f);
    p = fmaf(p, w, 0.00573950773f);
    p = fmaf(p, w, -0.0076224613f);
    p = fmaf(p, w, 0.00943887047f);
    p = fmaf(p, w, 1.00167406f);
    p = fmaf(p, w, 2.83297682f);
  }
  return p * x;
}

__device__ __forceinline__ float normal_from_bits(u32 bits) {
  const float lo = -0.99999994f;
  float u = u01_from_bits(bits) * 2.0f + lo;
  u = fmaxf(lo, u);
  return 1.41421356237f * erfinv_f32(u);
}

__device__ __forceinline__ float softplus_f(float x) {
  return fmaxf(x, 0.0f) + log1pf(expf(-fabsf(x)));
}

// jax.random._gamma_one for alpha >= 1 (boost == 1), partitionable keys.
// Validated rounds 2/4/5/6 (absmax 0.5/0.25/0.25/0.25).
__device__ float gamma_sample(u32 k0, u32 k1, float alpha) {
  U2 kk = tf2x32(k0, k1, 0u, 0u);   // key, subkey = split(key) [u_boost consumed]
  k0 = kk.a; k1 = kk.b;
  float d = alpha - 0.33333334f;
  float c = 0.33333334f / sqrtf(d);
  float X, V, U;
  do {
    U2 nk = tf2x32(k0, k1, 0u, 0u);
    U2 xk = tf2x32(k0, k1, 0u, 1u);
    U2 uk = tf2x32(k0, k1, 0u, 2u);
    k0 = nk.a; k1 = nk.b;
    u32 xk0 = xk.a, xk1 = xk.b;
    float x, v;
    do {
      U2 nxt = tf2x32(xk0, xk1, 0u, 0u);
      U2 sub = tf2x32(xk0, xk1, 0u, 1u);
      xk0 = nxt.a; xk1 = nxt.b;
      x = normal_from_bits(prf32(sub.a, sub.b, 0u));
      v = 1.0f + x * c;
    } while (v <= 0.0f);
    X = x * x;
    V = (v * v) * v;
    U = u01_from_bits(prf32(uk.a, uk.b, 0u));
  } while (U >= 1.0f - 0.0331f * (X * X) &&
           logf(U) >= 0.5f * X + d * ((1.0f - V) + logf(V)));
  return d * V;
}

// ---------------- bf16 split-2 helpers ----------------
__device__ __forceinline__ u16 f2bf(float f) {
  u32 u = __float_as_uint(f);
  u32 r = ((u >> 16) & 1u) + 0x7fffu;
  return (u16)((u + r) >> 16);
}
__device__ __forceinline__ float bf2f(u16 h) { return __uint_as_float(((u32)h) << 16); }

__device__ __forceinline__ void split2(float v, u16& h, u16& m) {
  h = f2bf(v);
  m = f2bf(v - bf2f(h));   // residual exact; |v-h-m| <= 2^-18 |v|
}

#define GLOAD16(gp, lp) __builtin_amdgcn_global_load_lds( \
    (const __attribute__((address_space(1))) void*)(gp),  \
    (__attribute__((address_space(3))) void*)(lp), 16, 0, 0)

// ---------------- split-2 bf16 MFMA GEMM (slot-major planes) ----------------
// A2 [M][2K] rm (planes h|m), B2T [N][2K] rm (planes h|m), bias[N] f32.
// Virtual K3=3K; slot s = vk/K: pa = s>>1 {h,h,m}, pb = s&1 {h,m,h}
// -> products hh,hm,mh (error ~3*2^-18, same order as f32-accum noise).
// 128x128 tile, BK=64, 4 waves, 32x32x16 bf16 MFMA, XOR-swizzled LDS (T2).
template<bool RELU, bool SIX>
__global__ __launch_bounds__(256, 3) void gemm_s3(const u16* __restrict__ A2,
                                                  const u16* __restrict__ B2T,
                                                  const float* __restrict__ bias,
                                                  float* __restrict__ Cf,
                                                  u16* __restrict__ C2,
                                                  int N, int kbits) {
  __shared__ u16 As[128 * 64];
  __shared__ u16 Bs[128 * 64];
  const int tid = threadIdx.x;
  const int l = tid & 63, w = tid >> 6;
  const int m0 = blockIdx.y * 128, n0 = blockIdx.x * 128;
  const int K2 = 2 << kbits;
  // staging: per-lane inverse-swizzled source column (16B blocks)
  const int srow = l >> 3;
  const int scol = ((l & 7) ^ srow) << 3;
  const u16* agr[4]; const u16* bgr[4]; u16* al[4]; u16* bl[4];
#pragma unroll
  for (int j = 0; j < 4; ++j) {
    int r = w * 32 + j * 8 + srow;
    agr[j] = A2 + (size_t)(m0 + r) * K2 + scol;
    bgr[j] = B2T + (size_t)(n0 + r) * K2 + scol;
    al[j] = &As[(w * 4 + j) * 512];
    bl[j] = &Bs[(w * 4 + j) * 512];
  }
  f32x16 acc[2][2] = {};
  const int fr = l & 31;
  const int wm = w >> 1, wn = w & 1;
  const int swz = (l & 7) << 4;
  const int hk16 = (l >> 5) << 4;
  const int nk = 3 << (kbits - 6);
  const int kmask = (1 << kbits) - 1;
  for (int kt = 0; kt < nk; ++kt) {
    int vb = kt << 6;
    int s = vb >> kbits;       // 0,1,2
    int ko = vb & kmask;
    int ao = ((s >> 1) << kbits) + ko;   // A plane {h,h,m}
    int bo = ((s & 1) << kbits) + ko;    // B plane {h,m,h}
    __syncthreads();   // previous tile consumed
#pragma unroll
    for (int j = 0; j < 4; ++j) {
      GLOAD16(agr[j] + ao, al[j]);
      GLOAD16(bgr[j] + bo, bl[j]);
    }
    __syncthreads();   // compiler drains vmcnt(0) before barrier: tile ready
#pragma unroll
    for (int ks = 0; ks < 4; ++ks) {
      bf16x8 af[2], bf[2];
#pragma unroll
      for (int mi = 0; mi < 2; ++mi) {
        int ar = wm * 64 + mi * 32 + fr;
        af[mi] = *(const bf16x8*)((const char*)As + ar * 128 + ((ks * 32 + hk16) ^ swz));
      }
#pragma unroll
      for (int ni = 0; ni < 2; ++ni) {
        int br = wn * 64 + ni * 32 + fr;
        bf[ni] = *(const bf16x8*)((const char*)Bs + br * 128 + ((ks * 32 + hk16) ^ swz));
      }
#pragma unroll
      for (int mi = 0; mi < 2; ++mi)
#pragma unroll
        for (int ni = 0; ni < 2; ++ni)
          acc[mi][ni] = __builtin_amdgcn_mfma_f32_32x32x16_bf16(af[mi], bf[ni], acc[mi][ni], 0, 0, 0);
    }
  }
  // epilogue: C/D layout col=lane&31, row=(r&3)+8*(r>>2)+4*(lane>>5)
#pragma unroll
  for (int mi = 0; mi < 2; ++mi)
#pragma unroll
  for (int ni = 0; ni < 2; ++ni) {
    int gcol = n0 + wn * 64 + ni * 32 + fr;
    float bsv = bias[gcol];
#pragma unroll
    for (int r = 0; r < 16; ++r) {
      int grow = m0 + wm * 64 + mi * 32 + (r & 3) + 8 * (r >> 2) + 4 * (l >> 5);
      float v = acc[mi][ni][r] + bsv;
      if (RELU) v = fmaxf(v, 0.0f);
      if (!SIX) {
        Cf[(size_t)grow * N + gcol] = v;
      } else {
        u16 h, mm; split2(v, h, mm);
        u16* q = C2 + (size_t)grow * 2 * N + gcol;
        q[0] = h; q[N] = mm;
      }
    }
  }
}

// -------- weight conversion: W [K][N] f32 -> W2T [N][2K] bf16 planes --------
__global__ __launch_bounds__(256) void k_wconv(const float* __restrict__ W, u16* __restrict__ W2T,
                                               int K, int N) {
  __shared__ float t[64][65];
  const int k0 = blockIdx.y * 64, n0 = blockIdx.x * 64;
  const int tid = threadIdx.x;
  for (int i = tid; i < 4096; i += 256) {
    int kk = i >> 6, nn = i & 63;
    t[kk][nn] = W[(size_t)(k0 + kk) * N + (n0 + nn)];
  }
  __syncthreads();
  const int nn = tid >> 2, kc = (tid & 3) << 4;
  u16* base = W2T + (size_t)(n0 + nn) * 2 * K + (k0 + kc);
#pragma unroll
  for (int kk = 0; kk < 16; ++kk) {
    u16 h, m; split2(t[kc + kk][nn], h, m);
    base[kk] = h; base[K + kk] = m;
  }
}

// -------- activation conversion: X [rows][K] f32 -> X2 [rows][2K] planes --------
__global__ __launch_bounds__(256) void k_aconv(const float* __restrict__ X, u16* __restrict__ X2,
                                               int total, int kbits) {
  int i = blockIdx.x * 256 + threadIdx.x;
  if (i >= total) return;
  int K = 1 << kbits;
  int r = i >> kbits, k = i & (K - 1);
  u16 h, m; split2(X[i], h, m);
  u16* q = X2 + ((size_t)r * 2 << kbits) + k;
  q[0] = h; q[K] = m;
}

// -------- build per-row ascending list of missing p (mask constant over l) --------
__global__ __launch_bounds__(256) void k_build(const int* __restrict__ mask,
                                               u16* __restrict__ miss,
                                               int* __restrict__ nmiss) {
  const int b = blockIdx.x, tid = threadIdx.x;
  const int* mrow = mask + b * 1024;
  const int pb = tid * 4;
  int m0 = (mrow[pb] == 0), m1 = (mrow[pb + 1] == 0),
      m2 = (mrow[pb + 2] == 0), m3 = (mrow[pb + 3] == 0);
  int cnt = m0 + m1 + m2 + m3;
  __shared__ int sc[256];
  sc[tid] = cnt;
  __syncthreads();
  for (int off = 1; off < 256; off <<= 1) {
    int v = 0;
    if (tid >= off) v = sc[tid - off];
    __syncthreads();
    sc[tid] += v;
    __syncthreads();
  }
  int pos = sc[tid] - cnt;   // exclusive prefix
  u16* mr = miss + b * 1024;
  if (m0) mr[pos++] = (u16)pb;
  if (m1) mr[pos++] = (u16)(pb + 1);
  if (m2) mr[pos++] = (u16)(pb + 2);
  if (m3) mr[pos++] = (u16)(pb + 3);
  if (tid == 255) nmiss[b] = sc[255];
}

// ------- eps/z for chunk batch: row = blockIdx.x in [0, NC*2048) -------
__global__ __launch_bounds__(256) void k_eps_z(const float* __restrict__ out_enc,
                                               u16* __restrict__ z2c,
                                               float* __restrict__ logpz,
                                               float* __restrict__ logq,
                                               int l0, u32 ke0, u32 ke1) {
  const int row = blockIdx.x;
  const int lb = l0 * 2048 + row;      // global (l,b) flat index
  const int b = row & 2047;
  const int d = threadIdx.x;
  const u32 m = ((u32)lb << 8) + (u32)d;
  float mu = out_enc[b * 512 + d];
  float sg = softplus_f(out_enc[b * 512 + 256 + d]);  // +1e-64 underflows in f32
  float e = normal_from_bits(prf32(ke0, ke1, m));
  float zz = mu + sg * e;
  u16 h, mm; split2(zz, h, mm);
  u16* q = z2c + row * 512 + d;
  q[0] = h; q[256] = mm;
  float t1 = -0.5f * e * e - logf(sg);
  float t2 = -0.5f * zz * zz;
#pragma unroll
  for (int o = 32; o; o >>= 1) { t1 += __shfl_down(t1, o); t2 += __shfl_down(t2, o); }
  __shared__ float sm1[4], sm2[4];
  int lane = d & 63, wv = d >> 6;
  if (!lane) { sm1[wv] = t1; sm2[wv] = t2; }
  __syncthreads();
  if (d == 0) {
    float a = sm1[0] + sm1[1] + sm1[2] + sm1[3];
    float qq = sm2[0] + sm2[1] + sm2[2] + sm2[3];
    logq[lb]  = a - 235.2482645003962f;   // 0.5*D*log(2*pi)
    logpz[lb] = qq - 235.2482645003962f;
  }
}

// ------- per-chunk: logpxobs row sums, observed entries only -------
// Same p-iteration and reduction order as the round-6 fused kernel -> bit-identical lpxobs.
__global__ __launch_bounds__(256) void k_lpx(const float* __restrict__ odec,
                                             const float* __restrict__ data,
                                             const int* __restrict__ mask,
                                             float* __restrict__ lpxobs,
                                             int l0) {
  const int row = blockIdx.x;
  const int lb = l0 * 2048 + row;
  const int b = row & 2047;
  const int tid = threadIdx.x;
  float lpsum = 0.0f;
  for (int j = 0; j < 4; ++j) {
    int p = tid + j * 256;
    if (mask[b * 1024 + p]) {
      float mean  = odec[(size_t)row * 3072 + p];
      float scale = softplus_f(odec[(size_t)row * 3072 + 1024 + p]) + 0.001f;
      float dfv   = softplus_f(odec[(size_t)row * 3072 + 2048 + p]) + 3.0f;
      float x = data[b * 1024 + p];
      float y = (x - mean) / scale;
      float lp = lgammaf((dfv + 1.0f) * 0.5f) - lgammaf(dfv * 0.5f)
               - 0.5f * logf(dfv * 3.14159274f) - logf(scale)
               - 0.5f * (dfv + 1.0f) * log1pf(y * y / dfv);
      lpsum += lp;
    }
  }
#pragma unroll
  for (int o = 32; o; o >>= 1) lpsum += __shfl_down(lpsum, o);
  __shared__ float sm[4];
  int lane = tid & 63, wv = tid >> 6;
  if (!lane) sm[wv] = lpsum;
  __syncthreads();
  if (tid == 0) lpxobs[lb] = sm[0] + sm[1] + sm[2] + sm[3];
}

// ------- per-chunk: t sampling for missing entries only (compacted list) -------
__global__ __launch_bounds__(256) void k_sample(const float* __restrict__ odec,
                                                const u16* __restrict__ miss,
                                                const int* __restrict__ nmiss,
                                                u16* __restrict__ xms,
                                                int l0, u32 kn0, u32 kn1, u32 kg0, u32 kg1) {
  const int row = blockIdx.x;
  const int lb = l0 * 2048 + row;
  const int b = row & 2047;
  const int nm = nmiss[b];
  const u16* mr = miss + b * 1024;
  for (int t = threadIdx.x; t < nm; t += 256) {
    int p = mr[t];
    float mean  = odec[(size_t)row * 3072 + p];
    float scale = softplus_f(odec[(size_t)row * 3072 + 1024 + p]) + 0.001f;
    float dfv   = softplus_f(odec[(size_t)row * 3072 + 2048 + p]) + 3.0f;
    u32 i = ((u32)lb << 10) + (u32)p;
    float n = normal_from_bits(prf32(kn0, kn1, i));
    U2 gk = tf2x32(kg0, kg1, 0u, i);     // split(key_g, N)[i]
    float half_df = dfv * 0.5f;
    float g = gamma_sample(gk.a, gk.b, half_df);
    float tt = n * sqrtf(half_df / g);
    xms[i] = f2bf(mean + scale * tt);
  }
}

// --------------- importance weights: softmax over L=10 ---------------
__global__ __launch_bounds__(256) void k_impw(const float* __restrict__ lpx,
                                              const float* __restrict__ lpz,
                                              const float* __restrict__ lq,
                                              float* __restrict__ w) {
  int b = blockIdx.x * 256 + threadIdx.x;
  float s[10], mx = -INFINITY;
#pragma unroll
  for (int l = 0; l < 10; ++l) {
    s[l] = lpx[l * 2048 + b] + lpz[l * 2048 + b] - lq[l * 2048 + b];
    mx = fmaxf(mx, s[l]);
  }
  float se = 0.0f;
#pragma unroll
  for (int l = 0; l < 10; ++l) { s[l] = expf(s[l] - mx); se += s[l]; }
#pragma unroll
  for (int l = 0; l < 10; ++l) w[l * 2048 + b] = s[l] / se;
}

// ------- xm + data_imputed (+ 2-plane split for classifier input) -------
__global__ __launch_bounds__(256) void k_xm(const int* __restrict__ mask,
                                            const float* __restrict__ data,
                                            const float* __restrict__ impw,
                                            const u16* __restrict__ xms,
                                            u16* __restrict__ imp2,
                                            float* __restrict__ out) {
  int idx = blockIdx.x * 256 + threadIdx.x;
  int b = idx >> 10, p = idx & 1023;
  float o;
  if (mask[idx]) {
    o = data[idx];
  } else {
    float acc = 0.0f;
#pragma unroll
    for (int l = 0; l < 10; ++l)
      acc += impw[l * 2048 + b] * bf2f(xms[((size_t)l * 2048 + b) * 1024 + p]);
    o = acc;
  }
  out[idx] = o;
  u16 h, m; split2(o, h, m);
  u16* q = imp2 + (size_t)b * 2048 + p;
  q[0] = h; q[1024] = m;
}

// --------------- classifier head: logits (N=10) ---------------
__global__ __launch_bounds__(256) void k_cls2(const float* __restrict__ hc,
                                              const float* __restrict__ w2,
                                              const float* __restrict__ b2,
                                              float* __restrict__ out) {
  int b = blockIdx.x, tid = threadIdx.x;
  float acc[10];
#pragma unroll
  for (int c = 0; c < 10; ++c) acc[c] = 0.0f;
  for (int k = tid; k < 2048; k += 256) {
    float h = hc[(size_t)b * 2048 + k];
#pragma unroll
    for (int c = 0; c < 10; ++c) acc[c] = fmaf(h, w2[k * 10 + c], acc[c]);
  }
  __shared__ float red[4][10];
  int lane = tid & 63, wv = tid >> 6;
#pragma unroll
  for (int c = 0; c < 10; ++c) {
    float v = acc[c];
#pragma unroll
    for (int o = 32; o; o >>= 1) v += __shfl_down(v, o);
    if (!lane) red[wv][c] = v;
  }
  __syncthreads();
  if (tid < 10) out[b * 10 + tid] = red[0][tid] + red[1][tid] + red[2][tid] + red[3][tid] + b2[tid];
}

extern "C" void kernel_launch(void* const* d_in, const int* in_sizes, int n_in,
                              void* d_out, int out_size, void* d_ws, size_t ws_size,
                              hipStream_t stream) {
  const float* data   = (const float*)d_in[0];
  const int*   mask   = (const int*)d_in[1];
  const float* enc_w1 = (const float*)d_in[2];
  const float* enc_b1 = (const float*)d_in[3];
  const float* enc_w2 = (const float*)d_in[4];
  const float* enc_b2 = (const float*)d_in[5];
  const float* dec_w1 = (const float*)d_in[6];
  const float* dec_b1 = (const float*)d_in[7];
  const float* dec_w2 = (const float*)d_in[8];
  const float* dec_b2 = (const float*)d_in[9];
  const float* cls_w1 = (const float*)d_in[10];
  const float* cls_b1 = (const float*)d_in[11];
  const float* cls_w2 = (const float*)d_in[12];
  const float* cls_b2 = (const float*)d_in[13];

  float* out = (float*)d_out;   // [2048*1024 data_imputed | 2048*10 logits]
  char* wsb = (char*)d_ws;

  // Round-5 ran the big branch -> ws_size >= 225,771,520 proven. This layout: 178.4 MB.
  if (ws_size < 186982400ULL) return;

  u16*   xmsu   = (u16*)(wsb + 0);              // [10*2048][1024] bf16  (40 MiB)
  u16*   w_d2   = (u16*)(wsb + 41943040);       // [3072][2*2048]        (24 MiB)
  u16*   w_d1   = (u16*)(wsb + 67108864);       // [2048][2*256]         (2 MiB)
  u16*   hx2    = (u16*)(wsb + 69206016);       // [4096][2*2048]        (32 MiB)
  float* odec   = (float*)(wsb + 102760448);    // [4096][3072] f32      (48 MiB)
  u16*   z2c    = (u16*)(wsb + 153092096);      // [4096][2*256]         (4 MiB)
  u16*   data2  = (u16*)(wsb + 157286400);      // [2048][2*1024]        (8 MiB)
  u16*   w_ec   = (u16*)(wsb + 165675008);      // w_e1/w_c1 [2048][2*1024] (8 MiB)
  u16*   w_e2   = (u16*)(wsb + 174063616);      // [512][2*2048]         (4 MiB)
  float* logpz  = (float*)(wsb + 178257920);
  float* logq   = (float*)(wsb + 178339840);
  float* lpxobs = (float*)(wsb + 178421760);
  float* impw   = (float*)(wsb + 178503680);
  float* out_enc= (float*)(wsb + 178585600);    // [2048][512] f32       (4 MiB)
  u16*   miss   = (u16*)(wsb + 182779904);      // [2048][1024] u16      (4 MiB)
  int*   nmiss  = (int*)(wsb + 186974208);      // [2048] int
  float* hc     = odec;    // reuse [2048][2048] f32
  u16*   imp2   = data2;   // reuse

  // key(42)=(0,42); k_eps=PRF(key,0), k_t=PRF(key,1); key_n=PRF(k_t,0), key_g=PRF(k_t,1)
  U2 ke = tf2x32(0u, 42u, 0u, 0u);
  U2 kt = tf2x32(0u, 42u, 0u, 1u);
  U2 kn = tf2x32(kt.a, kt.b, 0u, 0u);
  U2 kg = tf2x32(kt.a, kt.b, 0u, 1u);

  dim3 blk(256);
  // conversions + mask compaction
  k_aconv<<<8192, blk, 0, stream>>>(data, data2, 2097152, 10);
  k_wconv<<<dim3(32, 16), blk, 0, stream>>>(enc_w1, w_ec, 1024, 2048);
  k_wconv<<<dim3(8, 32),  blk, 0, stream>>>(enc_w2, w_e2, 2048, 512);
  k_wconv<<<dim3(48, 32), blk, 0, stream>>>(dec_w2, w_d2, 2048, 3072);
  k_wconv<<<dim3(32, 4),  blk, 0, stream>>>(dec_w1, w_d1, 256, 2048);
  k_build<<<2048, blk, 0, stream>>>(mask, miss, nmiss);

  // encoder
  gemm_s3<true,  true ><<<dim3(16, 16), blk, 0, stream>>>(data2, w_ec, enc_b1, nullptr, hx2, 2048, 10);
  gemm_s3<false, false><<<dim3(4, 16),  blk, 0, stream>>>(hx2, w_e2, enc_b2, out_enc, nullptr, 512, 11);

  // decoder: 2 l-chunks (M = 4096) per iteration
  for (int l0 = 0; l0 < 10; l0 += 2) {
    k_eps_z<<<4096, blk, 0, stream>>>(out_enc, z2c, logpz, logq, l0, ke.a, ke.b);
    gemm_s3<true,  true ><<<dim3(16, 32), blk, 0, stream>>>(z2c, w_d1, dec_b1, nullptr, hx2, 2048, 8);
    gemm_s3<false, false><<<dim3(24, 32), blk, 0, stream>>>(hx2, w_d2, dec_b2, odec, nullptr, 3072, 11);
    k_lpx<<<4096, blk, 0, stream>>>(odec, data, mask, lpxobs, l0);
    k_sample<<<4096, blk, 0, stream>>>(odec, miss, nmiss, xmsu, l0, kn.a, kn.b, kg.a, kg.b);
  }

  // importance weights + imputation
  k_impw<<<8, blk, 0, stream>>>(lpxobs, logpz, logq, impw);
  k_xm<<<8192, blk, 0, stream>>>(mask, data, impw, xmsu, imp2, out);

  // classifier (re-convert cls_w1 into w_ec slot)
  k_wconv<<<dim3(32, 16), blk, 0, stream>>>(cls_w1, w_ec, 1024, 2048);
  gemm_s3<true, false><<<dim3(16, 16), blk, 0, stream>>>(imp2, w_ec, cls_b1, hc, nullptr, 2048, 10);
  k_cls2<<<2048, blk, 0, stream>>>(hc, cls_w2, cls_b2, out + 2048 * 1024);
}

// Round 8
// 1845.136 us; speedup vs baseline: 2.7616x; 1.0759x over previous
//
#include <hip/hip_runtime.h>
#include <math.h>

typedef unsigned int u32;
typedef unsigned short u16;
typedef __attribute__((ext_vector_type(8))) short bf16x8;
typedef __attribute__((ext_vector_type(16))) float f32x16;

struct U2 { u32 a, b; };

// Threefry-2x32, 20 rounds — matches jax._src.prng.threefry2x32 exactly.
__host__ __device__ __forceinline__ U2 tf2x32(u32 k0, u32 k1, u32 c0, u32 c1) {
  u32 ks2 = k0 ^ k1 ^ 0x1BD11BDAu;
  u32 x0 = c0 + k0, x1 = c1 + k1;
#define TFR(r) { x0 += x1; x1 = (x1 << (r)) | (x1 >> (32 - (r))); x1 ^= x0; }
  TFR(13) TFR(15) TFR(26) TFR(6)
  x0 += k1; x1 += ks2 + 1u;
  TFR(17) TFR(29) TFR(16) TFR(24)
  x0 += ks2; x1 += k0 + 2u;
  TFR(13) TFR(15) TFR(26) TFR(6)
  x0 += k0; x1 += k1 + 3u;
  TFR(17) TFR(29) TFR(16) TFR(24)
  x0 += k1; x1 += ks2 + 4u;
  TFR(13) TFR(15) TFR(26) TFR(6)
  x0 += ks2; x1 += k0 + 5u;
#undef TFR
  return {x0, x1};
}

// jax_threefry_partitionable=True:
// random_bits(key,32,shape)[i] = b1^b2 at counter (0,i); split(key,n)[i] = pair at counter i.
__host__ __device__ __forceinline__ u32 prf32(u32 k0, u32 k1, u32 i) {
  U2 r = tf2x32(k0, k1, 0u, i);
  return r.a ^ r.b;
}

__device__ __forceinline__ float u01_from_bits(u32 bits) {
  u32 r = (bits >> 9) | 0x3f800000u;
  return __uint_as_float(r) - 1.0f;
}

// XLA ErfInv f32 (Giles polynomial)
__device__ __forceinline__ float erfinv_f32(float x) {
  float w = -log1pf(-x * x);
  float p;
  if (w < 5.0f) {
    w -= 2.5f;
    p = 2.81022636e-08f;
    p = fmaf(p, w, 3.43273939e-07f);
    p = fmaf(p, w, -3.5233877e-06f);
    p = fmaf(p, w, -4.39150654e-06f);
    p = fmaf(p, w, 0.00021858087f);
    p = fmaf(p, w, -0.00125372503f);
    p = fmaf(p, w, -0.00417768164f);
    p = fmaf(p, w, 0.246640727f);
    p = fmaf(p, w, 1.50140941f);
  } else {
    w = sqrtf(w) - 3.0f;
    p = -0.000200214257f;
    p = fmaf(p, w, 0.000100950558f);
    p = fmaf(p, w, 0.00134934322f);
    p = fmaf(p, w, -0.00367342844f);
    p = fmaf(p, w, 0.00573950773f);
    p = fmaf(p, w, -0.0076224613f);
    p = fmaf(p, w, 0.00943887047f);
    p = fmaf(p, w, 1.00167406f);
    p = fmaf(p, w, 2.83297682f);
  }
  return p * x;
}

__device__ __forceinline__ float normal_from_bits(u32 bits) {
  const float lo = -0.99999994f;
  float u = u01_from_bits(bits) * 2.0f + lo;
  u = fmaxf(lo, u);
  return 1.41421356237f * erfinv_f32(u);
}

__device__ __forceinline__ float softplus_f(float x) {
  return fmaxf(x, 0.0f) + log1pf(expf(-fabsf(x)));
}

// One outer iteration of jax.random._gamma_one's rejection loop (exact op order).
struct GI { bool acc; float V; u32 k0, k1; };
__device__ __forceinline__ GI gamma_iter(u32 k0, u32 k1, float d, float c) {
  U2 nk = tf2x32(k0, k1, 0u, 0u);
  U2 xk = tf2x32(k0, k1, 0u, 1u);
  U2 uk = tf2x32(k0, k1, 0u, 2u);
  u32 xk0 = xk.a, xk1 = xk.b;
  float x, v;
  do {
    U2 nxt = tf2x32(xk0, xk1, 0u, 0u);
    U2 sub = tf2x32(xk0, xk1, 0u, 1u);
    xk0 = nxt.a; xk1 = nxt.b;
    x = normal_from_bits(prf32(sub.a, sub.b, 0u));
    v = 1.0f + x * c;
  } while (v <= 0.0f);
  float X = x * x;
  float V = (v * v) * v;
  float U = u01_from_bits(prf32(uk.a, uk.b, 0u));
  bool cont = (U >= 1.0f - 0.0331f * (X * X)) &&
              (logf(U) >= 0.5f * X + d * ((1.0f - V) + logf(V)));
  GI r; r.acc = !cont; r.V = V; r.k0 = nk.a; r.k1 = nk.b;
  return r;
}

// lnGamma(x+0.5) - lnGamma(x), x >= 1.5: three exact recurrence pushes + Stirling.
// abs error <= ~1.5e-5 (verified at x=1.5 vs lnG(2)-lnG(1.5)); common-mode in softmax.
__device__ __forceinline__ float lgamma_half_diff(float x) {
  float z = x + 3.0f;
  float num = x * (x + 1.0f) * (x + 2.0f);
  float den = (x + 0.5f) * (x + 1.5f) * (x + 2.5f);
  float zh = z + 0.5f;
  float iz = 1.0f / z, izh = 1.0f / zh;
  float corr = 0.0833333333f * (izh - iz)
             - 0.00277777778f * (izh * izh * izh - iz * iz * iz);
  return logf(num / den) + 0.5f * logf(z) + z * log1pf(0.5f * iz) - 0.5f + corr;
}

// ---------------- bf16 split-2 helpers ----------------
__device__ __forceinline__ u16 f2bf(float f) {
  u32 u = __float_as_uint(f);
  u32 r = ((u >> 16) & 1u) + 0x7fffu;
  return (u16)((u + r) >> 16);
}
__device__ __forceinline__ float bf2f(u16 h) { return __uint_as_float(((u32)h) << 16); }

__device__ __forceinline__ void split2(float v, u16& h, u16& m) {
  h = f2bf(v);
  m = f2bf(v - bf2f(h));   // residual exact; |v-h-m| <= 2^-18 |v|
}

#define GLOAD16(gp, lp) __builtin_amdgcn_global_load_lds( \
    (const __attribute__((address_space(1))) void*)(gp),  \
    (__attribute__((address_space(3))) void*)(lp), 16, 0, 0)

// ---------------- split-2 bf16 MFMA GEMM (slot-major planes) ----------------
// A2 [M][2K] rm (planes h|m), B2T [N][2K] rm (planes h|m), bias[N] f32.
// Virtual K3=3K; slot s = vk/K: pa = s>>1 {h,h,m}, pb = s&1 {h,m,h}
// -> products hh,hm,mh (error ~3*2^-18, same order as f32-accum noise).
// 128x128 tile, BK=64, 4 waves, 32x32x16 bf16 MFMA, XOR-swizzled LDS (T2).
template<bool RELU, bool SIX>
__global__ __launch_bounds__(256, 3) void gemm_s3(const u16* __restrict__ A2,
                                                  const u16* __restrict__ B2T,
                                                  const float* __restrict__ bias,
                                                  float* __restrict__ Cf,
                                                  u16* __restrict__ C2,
                                                  int N, int kbits) {
  __shared__ u16 As[128 * 64];
  __shared__ u16 Bs[128 * 64];
  const int tid = threadIdx.x;
  const int l = tid & 63, w = tid >> 6;
  const int m0 = blockIdx.y * 128, n0 = blockIdx.x * 128;
  const int K2 = 2 << kbits;
  // staging: per-lane inverse-swizzled source column (16B blocks)
  const int srow = l >> 3;
  const int scol = ((l & 7) ^ srow) << 3;
  const u16* agr[4]; const u16* bgr[4]; u16* al[4]; u16* bl[4];
#pragma unroll
  for (int j = 0; j < 4; ++j) {
    int r = w * 32 + j * 8 + srow;
    agr[j] = A2 + (size_t)(m0 + r) * K2 + scol;
    bgr[j] = B2T + (size_t)(n0 + r) * K2 + scol;
    al[j] = &As[(w * 4 + j) * 512];
    bl[j] = &Bs[(w * 4 + j) * 512];
  }
  f32x16 acc[2][2] = {};
  const int fr = l & 31;
  const int wm = w >> 1, wn = w & 1;
  const int swz = (l & 7) << 4;
  const int hk16 = (l >> 5) << 4;
  const int nk = 3 << (kbits - 6);
  const int kmask = (1 << kbits) - 1;
  for (int kt = 0; kt < nk; ++kt) {
    int vb = kt << 6;
    int s = vb >> kbits;       // 0,1,2
    int ko = vb & kmask;
    int ao = ((s >> 1) << kbits) + ko;   // A plane {h,h,m}
    int bo = ((s & 1) << kbits) + ko;    // B plane {h,m,h}
    __syncthreads();   // previous tile consumed
#pragma unroll
    for (int j = 0; j < 4; ++j) {
      GLOAD16(agr[j] + ao, al[j]);
      GLOAD16(bgr[j] + bo, bl[j]);
    }
    __syncthreads();   // compiler drains vmcnt(0) before barrier: tile ready
#pragma unroll
    for (int ks = 0; ks < 4; ++ks) {
      bf16x8 af[2], bf[2];
#pragma unroll
      for (int mi = 0; mi < 2; ++mi) {
        int ar = wm * 64 + mi * 32 + fr;
        af[mi] = *(const bf16x8*)((const char*)As + ar * 128 + ((ks * 32 + hk16) ^ swz));
      }
#pragma unroll
      for (int ni = 0; ni < 2; ++ni) {
        int br = wn * 64 + ni * 32 + fr;
        bf[ni] = *(const bf16x8*)((const char*)Bs + br * 128 + ((ks * 32 + hk16) ^ swz));
      }
#pragma unroll
      for (int mi = 0; mi < 2; ++mi)
#pragma unroll
        for (int ni = 0; ni < 2; ++ni)
          acc[mi][ni] = __builtin_amdgcn_mfma_f32_32x32x16_bf16(af[mi], bf[ni], acc[mi][ni], 0, 0, 0);
    }
  }
  // epilogue: C/D layout col=lane&31, row=(r&3)+8*(r>>2)+4*(lane>>5)
#pragma unroll
  for (int mi = 0; mi < 2; ++mi)
#pragma unroll
  for (int ni = 0; ni < 2; ++ni) {
    int gcol = n0 + wn * 64 + ni * 32 + fr;
    float bsv = bias[gcol];
#pragma unroll
    for (int r = 0; r < 16; ++r) {
      int grow = m0 + wm * 64 + mi * 32 + (r & 3) + 8 * (r >> 2) + 4 * (l >> 5);
      float v = acc[mi][ni][r] + bsv;
      if (RELU) v = fmaxf(v, 0.0f);
      if (!SIX) {
        Cf[(size_t)grow * N + gcol] = v;
      } else {
        u16 h, mm; split2(v, h, mm);
        u16* q = C2 + (size_t)grow * 2 * N + gcol;
        q[0] = h; q[N] = mm;
      }
    }
  }
}

// -------- weight conversion: W [K][N] f32 -> W2T [N][2K] bf16 planes --------
__global__ __launch_bounds__(256) void k_wconv(const float* __restrict__ W, u16* __restrict__ W2T,
                                               int K, int N) {
  __shared__ float t[64][65];
  const int k0 = blockIdx.y * 64, n0 = blockIdx.x * 64;
  const int tid = threadIdx.x;
  for (int i = tid; i < 4096; i += 256) {
    int kk = i >> 6, nn = i & 63;
    t[kk][nn] = W[(size_t)(k0 + kk) * N + (n0 + nn)];
  }
  __syncthreads();
  const int nn = tid >> 2, kc = (tid & 3) << 4;
  u16* base = W2T + (size_t)(n0 + nn) * 2 * K + (k0 + kc);
#pragma unroll
  for (int kk = 0; kk < 16; ++kk) {
    u16 h, m; split2(t[kc + kk][nn], h, m);
    base[kk] = h; base[K + kk] = m;
  }
}

// -------- activation conversion: X [rows][K] f32 -> X2 [rows][2K] planes --------
__global__ __launch_bounds__(256) void k_aconv(const float* __restrict__ X, u16* __restrict__ X2,
                                               int total, int kbits) {
  int i = blockIdx.x * 256 + threadIdx.x;
  if (i >= total) return;
  int K = 1 << kbits;
  int r = i >> kbits, k = i & (K - 1);
  u16 h, m; split2(X[i], h, m);
  u16* q = X2 + ((size_t)r * 2 << kbits) + k;
  q[0] = h; q[K] = m;
}

// -------- build per-row lists: missing p ascending at [0,nm), observed ascending at [nm,1024) --------
__global__ __launch_bounds__(256) void k_build(const int* __restrict__ mask,
                                               u16* __restrict__ lists,
                                               int* __restrict__ nmiss) {
  const int b = blockIdx.x, tid = threadIdx.x;
  const int* mrow = mask + b * 1024;
  const int pb = tid * 4;
  int m0 = (mrow[pb] == 0), m1 = (mrow[pb + 1] == 0),
      m2 = (mrow[pb + 2] == 0), m3 = (mrow[pb + 3] == 0);
  int cnt = m0 + m1 + m2 + m3;
  __shared__ int sc[256];
  sc[tid] = cnt;
  __syncthreads();
  for (int off = 1; off < 256; off <<= 1) {
    int v = 0;
    if (tid >= off) v = sc[tid - off];
    __syncthreads();
    sc[tid] += v;
    __syncthreads();
  }
  int pos = sc[tid] - cnt;        // exclusive miss prefix
  int nmT = sc[255];              // total missing in row
  u16* lr = lists + b * 1024;
  int mpos = pos;
  int opos = nmT + (pb - pos);    // observed exclusive prefix = pb - pos
  if (m0) lr[mpos++] = (u16)pb;       else lr[opos++] = (u16)pb;
  if (m1) lr[mpos++] = (u16)(pb + 1); else lr[opos++] = (u16)(pb + 1);
  if (m2) lr[mpos++] = (u16)(pb + 2); else lr[opos++] = (u16)(pb + 2);
  if (m3) lr[mpos++] = (u16)(pb + 3); else lr[opos++] = (u16)(pb + 3);
  if (tid == 255) nmiss[b] = nmT;
}

// ------- eps/z for chunk batch: row = blockIdx.x in [0, NC*2048) -------
__global__ __launch_bounds__(256) void k_eps_z(const float* __restrict__ out_enc,
                                               u16* __restrict__ z2c,
                                               float* __restrict__ logpz,
                                               float* __restrict__ logq,
                                               int l0, u32 ke0, u32 ke1) {
  const int row = blockIdx.x;
  const int lb = l0 * 2048 + row;      // global (l,b) flat index
  const int b = row & 2047;
  const int d = threadIdx.x;
  const u32 m = ((u32)lb << 8) + (u32)d;
  float mu = out_enc[b * 512 + d];
  float sg = softplus_f(out_enc[b * 512 + 256 + d]);  // +1e-64 underflows in f32
  float e = normal_from_bits(prf32(ke0, ke1, m));
  float zz = mu + sg * e;
  u16 h, mm; split2(zz, h, mm);
  u16* q = z2c + row * 512 + d;
  q[0] = h; q[256] = mm;
  float t1 = -0.5f * e * e - logf(sg);
  float t2 = -0.5f * zz * zz;
#pragma unroll
  for (int o = 32; o; o >>= 1) { t1 += __shfl_down(t1, o); t2 += __shfl_down(t2, o); }
  __shared__ float sm1[4], sm2[4];
  int lane = d & 63, wv = d >> 6;
  if (!lane) { sm1[wv] = t1; sm2[wv] = t2; }
  __syncthreads();
  if (d == 0) {
    float a = sm1[0] + sm1[1] + sm1[2] + sm1[3];
    float qq = sm2[0] + sm2[1] + sm2[2] + sm2[3];
    logq[lb]  = a - 235.2482645003962f;   // 0.5*D*log(2*pi)
    logpz[lb] = qq - 235.2482645003962f;
  }
}

// ------- per-chunk: logpxobs over observed list (all lanes active, lgamma-free) -------
__global__ __launch_bounds__(256) void k_lpx(const float* __restrict__ odec,
                                             const float* __restrict__ data,
                                             const u16* __restrict__ lists,
                                             const int* __restrict__ nmiss,
                                             float* __restrict__ lpxobs,
                                             int l0) {
  const int row = blockIdx.x;
  const int lb = l0 * 2048 + row;
  const int b = row & 2047;
  const int tid = threadIdx.x;
  const int nm = nmiss[b];
  const u16* orow = lists + b * 1024 + nm;
  const int no = 1024 - nm;
  float lpsum = 0.0f;
  for (int t = tid; t < no; t += 256) {
    int p = orow[t];
    float mean  = odec[(size_t)row * 3072 + p];
    float scale = softplus_f(odec[(size_t)row * 3072 + 1024 + p]) + 0.001f;
    float dfv   = softplus_f(odec[(size_t)row * 3072 + 2048 + p]) + 3.0f;
    float x = data[b * 1024 + p];
    float y = (x - mean) / scale;
    float lp = lgamma_half_diff(dfv * 0.5f)
             - 0.5f * logf(dfv * 3.14159274f) - logf(scale)
             - 0.5f * (dfv + 1.0f) * log1pf(y * y / dfv);
    lpsum += lp;
  }
#pragma unroll
  for (int o = 32; o; o >>= 1) lpsum += __shfl_down(lpsum, o);
  __shared__ float sm[4];
  int lane = tid & 63, wv = tid >> 6;
  if (!lane) sm[wv] = lpsum;
  __syncthreads();
  if (tid == 0) lpxobs[lb] = sm[0] + sm[1] + sm[2] + sm[3];
}

// ------- per-chunk: t sampling, retry-compacted to kill wave-max divergence -------
__global__ __launch_bounds__(256) void k_sample(const float* __restrict__ odec,
                                                const u16* __restrict__ lists,
                                                const int* __restrict__ nmiss,
                                                u16* __restrict__ xms,
                                                int l0, u32 kn0, u32 kn1, u32 kg0, u32 kg1) {
  const int row = blockIdx.x;
  const int lb = l0 * 2048 + row;
  const int b = row & 2047;
  const int nm = nmiss[b];
  const u16* mr = lists + b * 1024;
  __shared__ u32 qk0[1024], qk1[1024];
  __shared__ u16 qp[1024];
  __shared__ int qn;
  if (threadIdx.x == 0) qn = 0;
  __syncthreads();
  // pass 1: exactly one rejection iteration per sample (~97% accept)
  for (int t = threadIdx.x; t < nm; t += 256) {
    int p = mr[t];
    float mean  = odec[(size_t)row * 3072 + p];
    float scale = softplus_f(odec[(size_t)row * 3072 + 1024 + p]) + 0.001f;
    float dfv   = softplus_f(odec[(size_t)row * 3072 + 2048 + p]) + 3.0f;
    u32 i = ((u32)lb << 10) + (u32)p;
    float n = normal_from_bits(prf32(kn0, kn1, i));
    U2 gk = tf2x32(kg0, kg1, 0u, i);        // split(key_g, N)[i]
    U2 kk = tf2x32(gk.a, gk.b, 0u, 0u);     // boost split (u_boost consumed)
    float half_df = dfv * 0.5f;
    float d = half_df - 0.33333334f;
    float c = 0.33333334f / sqrtf(d);
    GI r = gamma_iter(kk.a, kk.b, d, c);
    if (r.acc) {
      float g = d * r.V;
      xms[i] = f2bf(mean + scale * (n * sqrtf(half_df / g)));
    } else {
      int s = atomicAdd(&qn, 1);
      qk0[s] = r.k0; qk1[s] = r.k1; qp[s] = (u16)p;
    }
  }
  __syncthreads();
  // pass 2: drain the small retry queue (~3% of samples)
  int n2 = qn;
  for (int t = threadIdx.x; t < n2; t += 256) {
    int p = qp[t];
    float mean  = odec[(size_t)row * 3072 + p];
    float scale = softplus_f(odec[(size_t)row * 3072 + 1024 + p]) + 0.001f;
    float dfv   = softplus_f(odec[(size_t)row * 3072 + 2048 + p]) + 3.0f;
    u32 i = ((u32)lb << 10) + (u32)p;
    float n = normal_from_bits(prf32(kn0, kn1, i));
    float half_df = dfv * 0.5f;
    float d = half_df - 0.33333334f;
    float c = 0.33333334f / sqrtf(d);
    u32 k0 = qk0[t], k1 = qk1[t];
    GI r;
    do { r = gamma_iter(k0, k1, d, c); k0 = r.k0; k1 = r.k1; } while (!r.acc);
    float g = d * r.V;
    xms[i] = f2bf(mean + scale * (n * sqrtf(half_df / g)));
  }
}

// --------------- importance weights: softmax over L=10 ---------------
__global__ __launch_bounds__(256) void k_impw(const float* __restrict__ lpx,
                                              const float* __restrict__ lpz,
                                              const float* __restrict__ lq,
                                              float* __restrict__ w) {
  int b = blockIdx.x * 256 + threadIdx.x;
  float s[10], mx = -INFINITY;
#pragma unroll
  for (int l = 0; l < 10; ++l) {
    s[l] = lpx[l * 2048 + b] + lpz[l * 2048 + b] - lq[l * 2048 + b];
    mx = fmaxf(mx, s[l]);
  }
  float se = 0.0f;
#pragma unroll
  for (int l = 0; l < 10; ++l) { s[l] = expf(s[l] - mx); se += s[l]; }
#pragma unroll
  for (int l = 0; l < 10; ++l) w[l * 2048 + b] = s[l] / se;
}

// ------- xm + data_imputed (+ 2-plane split for classifier input) -------
__global__ __launch_bounds__(256) void k_xm(const int* __restrict__ mask,
                                            const float* __restrict__ data,
                                            const float* __restrict__ impw,
                                            const u16* __restrict__ xms,
                                            u16* __restrict__ imp2,
                                            float* __restrict__ out) {
  int idx = blockIdx.x * 256 + threadIdx.x;
  int b = idx >> 10, p = idx & 1023;
  float o;
  if (mask[idx]) {
    o = data[idx];
  } else {
    float acc = 0.0f;
#pragma unroll
    for (int l = 0; l < 10; ++l)
      acc += impw[l * 2048 + b] * bf2f(xms[((size_t)l * 2048 + b) * 1024 + p]);
    o = acc;
  }
  out[idx] = o;
  u16 h, m; split2(o, h, m);
  u16* q = imp2 + (size_t)b * 2048 + p;
  q[0] = h; q[1024] = m;
}

// --------------- classifier head: logits (N=10) ---------------
__global__ __launch_bounds__(256) void k_cls2(const float* __restrict__ hc,
                                              const float* __restrict__ w2,
                                              const float* __restrict__ b2,
                                              float* __restrict__ out) {
  int b = blockIdx.x, tid = threadIdx.x;
  float acc[10];
#pragma unroll
  for (int c = 0; c < 10; ++c) acc[c] = 0.0f;
  for (int k = tid; k < 2048; k += 256) {
    float h = hc[(size_t)b * 2048 + k];
#pragma unroll
    for (int c = 0; c < 10; ++c) acc[c] = fmaf(h, w2[k * 10 + c], acc[c]);
  }
  __shared__ float red[4][10];
  int lane = tid & 63, wv = tid >> 6;
#pragma unroll
  for (int c = 0; c < 10; ++c) {
    float v = acc[c];
#pragma unroll
    for (int o = 32; o; o >>= 1) v += __shfl_down(v, o);
    if (!lane) red[wv][c] = v;
  }
  __syncthreads();
  if (tid < 10) out[b * 10 + tid] = red[0][tid] + red[1][tid] + red[2][tid] + red[3][tid] + b2[tid];
}

extern "C" void kernel_launch(void* const* d_in, const int* in_sizes, int n_in,
                              void* d_out, int out_size, void* d_ws, size_t ws_size,
                              hipStream_t stream) {
  const float* data   = (const float*)d_in[0];
  const int*   mask   = (const int*)d_in[1];
  const float* enc_w1 = (const float*)d_in[2];
  const float* enc_b1 = (const float*)d_in[3];
  const float* enc_w2 = (const float*)d_in[4];
  const float* enc_b2 = (const float*)d_in[5];
  const float* dec_w1 = (const float*)d_in[6];
  const float* dec_b1 = (const float*)d_in[7];
  const float* dec_w2 = (const float*)d_in[8];
  const float* dec_b2 = (const float*)d_in[9];
  const float* cls_w1 = (const float*)d_in[10];
  const float* cls_b1 = (const float*)d_in[11];
  const float* cls_w2 = (const float*)d_in[12];
  const float* cls_b2 = (const float*)d_in[13];

  float* out = (float*)d_out;   // [2048*1024 data_imputed | 2048*10 logits]
  char* wsb = (char*)d_ws;

  // Round-5 ran the big branch -> ws_size >= 225,771,520 proven. This layout: 178.4 MB.
  if (ws_size < 186982400ULL) return;

  u16*   xmsu   = (u16*)(wsb + 0);              // [10*2048][1024] bf16  (40 MiB)
  u16*   w_d2   = (u16*)(wsb + 41943040);       // [3072][2*2048]        (24 MiB)
  u16*   w_d1   = (u16*)(wsb + 67108864);       // [2048][2*256]         (2 MiB)
  u16*   hx2    = (u16*)(wsb + 69206016);       // [4096][2*2048]        (32 MiB)
  float* odec   = (float*)(wsb + 102760448);    // [4096][3072] f32      (48 MiB)
  u16*   z2c    = (u16*)(wsb + 153092096);      // [4096][2*256]         (4 MiB)
  u16*   data2  = (u16*)(wsb + 157286400);      // [2048][2*1024]        (8 MiB)
  u16*   w_ec   = (u16*)(wsb + 165675008);      // w_e1/w_c1 [2048][2*1024] (8 MiB)
  u16*   w_e2   = (u16*)(wsb + 174063616);      // [512][2*2048]         (4 MiB)
  float* logpz  = (float*)(wsb + 178257920);
  float* logq   = (float*)(wsb + 178339840);
  float* lpxobs = (float*)(wsb + 178421760);
  float* impw   = (float*)(wsb + 178503680);
  float* out_enc= (float*)(wsb + 178585600);    // [2048][512] f32       (4 MiB)
  u16*   lists  = (u16*)(wsb + 182779904);      // [2048][1024] u16: miss | obs (4 MiB)
  int*   nmiss  = (int*)(wsb + 186974208);      // [2048] int
  float* hc     = odec;    // reuse [2048][2048] f32
  u16*   imp2   = data2;   // reuse

  // key(42)=(0,42); k_eps=PRF(key,0), k_t=PRF(key,1); key_n=PRF(k_t,0), key_g=PRF(k_t,1)
  U2 ke = tf2x32(0u, 42u, 0u, 0u);
  U2 kt = tf2x32(0u, 42u, 0u, 1u);
  U2 kn = tf2x32(kt.a, kt.b, 0u, 0u);
  U2 kg = tf2x32(kt.a, kt.b, 0u, 1u);

  dim3 blk(256);
  // conversions + mask compaction
  k_aconv<<<8192, blk, 0, stream>>>(data, data2, 2097152, 10);
  k_wconv<<<dim3(32, 16), blk, 0, stream>>>(enc_w1, w_ec, 1024, 2048);
  k_wconv<<<dim3(8, 32),  blk, 0, stream>>>(enc_w2, w_e2, 2048, 512);
  k_wconv<<<dim3(48, 32), blk, 0, stream>>>(dec_w2, w_d2, 2048, 3072);
  k_wconv<<<dim3(32, 4),  blk, 0, stream>>>(dec_w1, w_d1, 256, 2048);
  k_build<<<2048, blk, 0, stream>>>(mask, lists, nmiss);

  // encoder
  gemm_s3<true,  true ><<<dim3(16, 16), blk, 0, stream>>>(data2, w_ec, enc_b1, nullptr, hx2, 2048, 10);
  gemm_s3<false, false><<<dim3(4, 16),  blk, 0, stream>>>(hx2, w_e2, enc_b2, out_enc, nullptr, 512, 11);

  // decoder: 2 l-chunks (M = 4096) per iteration
  for (int l0 = 0; l0 < 10; l0 += 2) {
    k_eps_z<<<4096, blk, 0, stream>>>(out_enc, z2c, logpz, logq, l0, ke.a, ke.b);
    gemm_s3<true,  true ><<<dim3(16, 32), blk, 0, stream>>>(z2c, w_d1, dec_b1, nullptr, hx2, 2048, 8);
    gemm_s3<false, false><<<dim3(24, 32), blk, 0, stream>>>(hx2, w_d2, dec_b2, odec, nullptr, 3072, 11);
    k_lpx<<<4096, blk, 0, stream>>>(odec, data, lists, nmiss, lpxobs, l0);
    k_sample<<<4096, blk, 0, stream>>>(odec, lists, nmiss, xmsu, l0, kn.a, kn.b, kg.a, kg.b);
  }

  // importance weights + imputation
  k_impw<<<8, blk, 0, stream>>>(lpxobs, logpz, logq, impw);
  k_xm<<<8192, blk, 0, stream>>>(mask, data, impw, xmsu, imp2, out);

  // classifier (re-convert cls_w1 into w_ec slot)
  k_wconv<<<dim3(32, 16), blk, 0, stream>>>(cls_w1, w_ec, 1024, 2048);
  gemm_s3<true, false><<<dim3(16, 16), blk, 0, stream>>>(imp2, w_ec, cls_b1, hc, nullptr, 2048, 10);
  k_cls2<<<2048, blk, 0, stream>>>(hc, cls_w2, cls_b2, out + 2048 * 1024);
}

// Round 9
// 1843.156 us; speedup vs baseline: 2.7645x; 1.0011x over previous
//
#include <hip/hip_runtime.h>
#include <math.h>

typedef unsigned int u32;
typedef unsigned short u16;
typedef __attribute__((ext_vector_type(8))) short bf16x8;
typedef __attribute__((ext_vector_type(16))) float f32x16;

struct U2 { u32 a, b; };

// Threefry-2x32, 20 rounds — matches jax._src.prng.threefry2x32 exactly.
__host__ __device__ __forceinline__ U2 tf2x32(u32 k0, u32 k1, u32 c0, u32 c1) {
  u32 ks2 = k0 ^ k1 ^ 0x1BD11BDAu;
  u32 x0 = c0 + k0, x1 = c1 + k1;
#define TFR(r) { x0 += x1; x1 = (x1 << (r)) | (x1 >> (32 - (r))); x1 ^= x0; }
  TFR(13) TFR(15) TFR(26) TFR(6)
  x0 += k1; x1 += ks2 + 1u;
  TFR(17) TFR(29) TFR(16) TFR(24)
  x0 += ks2; x1 += k0 + 2u;
  TFR(13) TFR(15) TFR(26) TFR(6)
  x0 += k0; x1 += k1 + 3u;
  TFR(17) TFR(29) TFR(16) TFR(24)
  x0 += k1; x1 += ks2 + 4u;
  TFR(13) TFR(15) TFR(26) TFR(6)
  x0 += ks2; x1 += k0 + 5u;
#undef TFR
  return {x0, x1};
}

// jax_threefry_partitionable=True:
// random_bits(key,32,shape)[i] = b1^b2 at counter (0,i); split(key,n)[i] = pair at counter i.
__host__ __device__ __forceinline__ u32 prf32(u32 k0, u32 k1, u32 i) {
  U2 r = tf2x32(k0, k1, 0u, i);
  return r.a ^ r.b;
}

__device__ __forceinline__ float u01_from_bits(u32 bits) {
  u32 r = (bits >> 9) | 0x3f800000u;
  return __uint_as_float(r) - 1.0f;
}

// XLA ErfInv f32 (Giles polynomial)
__device__ __forceinline__ float erfinv_f32(float x) {
  float w = -log1pf(-x * x);
  float p;
  if (w < 5.0f) {
    w -= 2.5f;
    p = 2.81022636e-08f;
    p = fmaf(p, w, 3.43273939e-07f);
    p = fmaf(p, w, -3.5233877e-06f);
    p = fmaf(p, w, -4.39150654e-06f);
    p = fmaf(p, w, 0.00021858087f);
    p = fmaf(p, w, -0.00125372503f);
    p = fmaf(p, w, -0.00417768164f);
    p = fmaf(p, w, 0.246640727f);
    p = fmaf(p, w, 1.50140941f);
  } else {
    w = sqrtf(w) - 3.0f;
    p = -0.000200214257f;
    p = fmaf(p, w, 0.000100950558f);
    p = fmaf(p, w, 0.00134934322f);
    p = fmaf(p, w, -0.00367342844f);
    p = fmaf(p, w, 0.00573950773f);
    p = fmaf(p, w, -0.0076224613f);
    p = fmaf(p, w, 0.00943887047f);
    p = fmaf(p, w, 1.00167406f);
    p = fmaf(p, w, 2.83297682f);
  }
  return p * x;
}

__device__ __forceinline__ float normal_from_bits(u32 bits) {
  const float lo = -0.99999994f;
  float u = u01_from_bits(bits) * 2.0f + lo;
  u = fmaxf(lo, u);
  return 1.41421356237f * erfinv_f32(u);
}

__device__ __forceinline__ float softplus_f(float x) {
  return fmaxf(x, 0.0f) + log1pf(expf(-fabsf(x)));
}

// One outer iteration of jax.random._gamma_one's rejection loop (exact op order).
struct GI { bool acc; float V; u32 k0, k1; };
__device__ __forceinline__ GI gamma_iter(u32 k0, u32 k1, float d, float c) {
  U2 nk = tf2x32(k0, k1, 0u, 0u);
  U2 xk = tf2x32(k0, k1, 0u, 1u);
  U2 uk = tf2x32(k0, k1, 0u, 2u);
  u32 xk0 = xk.a, xk1 = xk.b;
  float x, v;
  do {
    U2 nxt = tf2x32(xk0, xk1, 0u, 0u);
    U2 sub = tf2x32(xk0, xk1, 0u, 1u);
    xk0 = nxt.a; xk1 = nxt.b;
    x = normal_from_bits(prf32(sub.a, sub.b, 0u));
    v = 1.0f + x * c;
  } while (v <= 0.0f);
  float X = x * x;
  float V = (v * v) * v;
  float U = u01_from_bits(prf32(uk.a, uk.b, 0u));
  bool cont = (U >= 1.0f - 0.0331f * (X * X)) &&
              (logf(U) >= 0.5f * X + d * ((1.0f - V) + logf(V)));
  GI r; r.acc = !cont; r.V = V; r.k0 = nk.a; r.k1 = nk.b;
  return r;
}

// lnGamma(x+0.5) - lnGamma(x), x >= 1.5: three exact recurrence pushes + Stirling.
// abs error <= ~1.5e-5; common-mode across l in the softmax.
__device__ __forceinline__ float lgamma_half_diff(float x) {
  float z = x + 3.0f;
  float num = x * (x + 1.0f) * (x + 2.0f);
  float den = (x + 0.5f) * (x + 1.5f) * (x + 2.5f);
  float zh = z + 0.5f;
  float iz = 1.0f / z, izh = 1.0f / zh;
  float corr = 0.0833333333f * (izh - iz)
             - 0.00277777778f * (izh * izh * izh - iz * iz * iz);
  return logf(num / den) + 0.5f * logf(z) + z * log1pf(0.5f * iz) - 0.5f + corr;
}

// ---------------- bf16 split-2 helpers ----------------
__device__ __forceinline__ u16 f2bf(float f) {
  u32 u = __float_as_uint(f);
  u32 r = ((u >> 16) & 1u) + 0x7fffu;
  return (u16)((u + r) >> 16);
}
__device__ __forceinline__ float bf2f(u16 h) { return __uint_as_float(((u32)h) << 16); }

__device__ __forceinline__ void split2(float v, u16& h, u16& m) {
  h = f2bf(v);
  m = f2bf(v - bf2f(h));   // residual exact; |v-h-m| <= 2^-18 |v|
}

#define GLOAD16(gp, lp) __builtin_amdgcn_global_load_lds( \
    (const __attribute__((address_space(1))) void*)(gp),  \
    (__attribute__((address_space(3))) void*)(lp), 16, 0, 0)

// ---------------- split-2 bf16 MFMA GEMM (slot-major planes) ----------------
// A2 [M][2K] rm (planes h|m), B2T [N][2K] rm (planes h|m), bias[N] f32.
// Virtual K3=3K; slot s = vk/K: pa = s>>1 {h,h,m}, pb = s&1 {h,m,h}
// -> products hh,hm,mh (error ~3*2^-18, same order as f32-accum noise).
// 128x128 tile, BK=64, 4 waves, 32x32x16 bf16 MFMA, XOR-swizzled LDS (T2).
// SWZ: XCD-chunked blockIdx remap (requires nwg % 8 == 0).
template<bool RELU, bool SIX, bool SWZ>
__global__ __launch_bounds__(256, 4) void gemm_s3(const u16* __restrict__ A2,
                                                  const u16* __restrict__ B2T,
                                                  const float* __restrict__ bias,
                                                  float* __restrict__ Cf,
                                                  u16* __restrict__ C2,
                                                  int N, int kbits) {
  __shared__ u16 As[128 * 64];
  __shared__ u16 Bs[128 * 64];
  const int tid = threadIdx.x;
  const int l = tid & 63, w = tid >> 6;
  int bx = blockIdx.x, by = blockIdx.y;
  if (SWZ) {
    int nx = gridDim.x;
    int wg = by * nx + bx;
    int per = (nx * gridDim.y) >> 3;       // blocks per XCD
    int sw = (wg & 7) * per + (wg >> 3);   // bijective when nwg%8==0
    bx = sw % nx; by = sw / nx;
  }
  const int m0 = by * 128, n0 = bx * 128;
  const int K2 = 2 << kbits;
  // staging: per-lane inverse-swizzled source column (16B blocks)
  const int srow = l >> 3;
  const int scol = ((l & 7) ^ srow) << 3;
  const u16* agr[4]; const u16* bgr[4]; u16* al[4]; u16* bl[4];
#pragma unroll
  for (int j = 0; j < 4; ++j) {
    int r = w * 32 + j * 8 + srow;
    agr[j] = A2 + (size_t)(m0 + r) * K2 + scol;
    bgr[j] = B2T + (size_t)(n0 + r) * K2 + scol;
    al[j] = &As[(w * 4 + j) * 512];
    bl[j] = &Bs[(w * 4 + j) * 512];
  }
  f32x16 acc[2][2] = {};
  const int fr = l & 31;
  const int wm = w >> 1, wn = w & 1;
  const int swz = (l & 7) << 4;
  const int hk16 = (l >> 5) << 4;
  const int nk = 3 << (kbits - 6);
  const int kmask = (1 << kbits) - 1;
  for (int kt = 0; kt < nk; ++kt) {
    int vb = kt << 6;
    int s = vb >> kbits;       // 0,1,2
    int ko = vb & kmask;
    int ao = ((s >> 1) << kbits) + ko;   // A plane {h,h,m}
    int bo = ((s & 1) << kbits) + ko;    // B plane {h,m,h}
    __syncthreads();   // previous tile consumed
#pragma unroll
    for (int j = 0; j < 4; ++j) {
      GLOAD16(agr[j] + ao, al[j]);
      GLOAD16(bgr[j] + bo, bl[j]);
    }
    __syncthreads();   // compiler drains vmcnt(0) before barrier: tile ready
#pragma unroll
    for (int ks = 0; ks < 4; ++ks) {
      bf16x8 af[2], bf[2];
#pragma unroll
      for (int mi = 0; mi < 2; ++mi) {
        int ar = wm * 64 + mi * 32 + fr;
        af[mi] = *(const bf16x8*)((const char*)As + ar * 128 + ((ks * 32 + hk16) ^ swz));
      }
#pragma unroll
      for (int ni = 0; ni < 2; ++ni) {
        int br = wn * 64 + ni * 32 + fr;
        bf[ni] = *(const bf16x8*)((const char*)Bs + br * 128 + ((ks * 32 + hk16) ^ swz));
      }
#pragma unroll
      for (int mi = 0; mi < 2; ++mi)
#pragma unroll
        for (int ni = 0; ni < 2; ++ni)
          acc[mi][ni] = __builtin_amdgcn_mfma_f32_32x32x16_bf16(af[mi], bf[ni], acc[mi][ni], 0, 0, 0);
    }
  }
  // epilogue: C/D layout col=lane&31, row=(r&3)+8*(r>>2)+4*(lane>>5)
#pragma unroll
  for (int mi = 0; mi < 2; ++mi)
#pragma unroll
  for (int ni = 0; ni < 2; ++ni) {
    int gcol = n0 + wn * 64 + ni * 32 + fr;
    float bsv = bias[gcol];
#pragma unroll
    for (int r = 0; r < 16; ++r) {
      int grow = m0 + wm * 64 + mi * 32 + (r & 3) + 8 * (r >> 2) + 4 * (l >> 5);
      float v = acc[mi][ni][r] + bsv;
      if (RELU) v = fmaxf(v, 0.0f);
      if (!SIX) {
        Cf[(size_t)grow * N + gcol] = v;
      } else {
        u16 h, mm; split2(v, h, mm);
        u16* q = C2 + (size_t)grow * 2 * N + gcol;
        q[0] = h; q[N] = mm;
      }
    }
  }
}

// -------- weight conversion: W [K][N] f32 -> W2T [N][2K] bf16 planes --------
__global__ __launch_bounds__(256) void k_wconv(const float* __restrict__ W, u16* __restrict__ W2T,
                                               int K, int N) {
  __shared__ float t[64][65];
  const int k0 = blockIdx.y * 64, n0 = blockIdx.x * 64;
  const int tid = threadIdx.x;
  for (int i = tid; i < 4096; i += 256) {
    int kk = i >> 6, nn = i & 63;
    t[kk][nn] = W[(size_t)(k0 + kk) * N + (n0 + nn)];
  }
  __syncthreads();
  const int nn = tid >> 2, kc = (tid & 3) << 4;
  u16* base = W2T + (size_t)(n0 + nn) * 2 * K + (k0 + kc);
#pragma unroll
  for (int kk = 0; kk < 16; ++kk) {
    u16 h, m; split2(t[kc + kk][nn], h, m);
    base[kk] = h; base[K + kk] = m;
  }
}

// -------- activation conversion: X [rows][K] f32 -> X2 [rows][2K] planes --------
__global__ __launch_bounds__(256) void k_aconv(const float* __restrict__ X, u16* __restrict__ X2,
                                               int total, int kbits) {
  int i = blockIdx.x * 256 + threadIdx.x;
  if (i >= total) return;
  int K = 1 << kbits;
  int r = i >> kbits, k = i & (K - 1);
  u16 h, m; split2(X[i], h, m);
  u16* q = X2 + ((size_t)r * 2 << kbits) + k;
  q[0] = h; q[K] = m;
}

// -------- build per-row lists: missing p ascending at [0,nm), observed ascending at [nm,1024) --------
__global__ __launch_bounds__(256) void k_build(const int* __restrict__ mask,
                                               u16* __restrict__ lists,
                                               int* __restrict__ nmiss) {
  const int b = blockIdx.x, tid = threadIdx.x;
  const int* mrow = mask + b * 1024;
  const int pb = tid * 4;
  int m0 = (mrow[pb] == 0), m1 = (mrow[pb + 1] == 0),
      m2 = (mrow[pb + 2] == 0), m3 = (mrow[pb + 3] == 0);
  int cnt = m0 + m1 + m2 + m3;
  __shared__ int sc[256];
  sc[tid] = cnt;
  __syncthreads();
  for (int off = 1; off < 256; off <<= 1) {
    int v = 0;
    if (tid >= off) v = sc[tid - off];
    __syncthreads();
    sc[tid] += v;
    __syncthreads();
  }
  int pos = sc[tid] - cnt;        // exclusive miss prefix
  int nmT = sc[255];              // total missing in row
  u16* lr = lists + b * 1024;
  int mpos = pos;
  int opos = nmT + (pb - pos);    // observed exclusive prefix = pb - pos
  if (m0) lr[mpos++] = (u16)pb;       else lr[opos++] = (u16)pb;
  if (m1) lr[mpos++] = (u16)(pb + 1); else lr[opos++] = (u16)(pb + 1);
  if (m2) lr[mpos++] = (u16)(pb + 2); else lr[opos++] = (u16)(pb + 2);
  if (m3) lr[mpos++] = (u16)(pb + 3); else lr[opos++] = (u16)(pb + 3);
  if (tid == 255) nmiss[b] = nmT;
}

// ------- eps/z for ALL 20480 (l,b) rows in one launch -------
__global__ __launch_bounds__(256) void k_eps_z(const float* __restrict__ out_enc,
                                               u16* __restrict__ z2all,
                                               float* __restrict__ logpz,
                                               float* __restrict__ logq,
                                               u32 ke0, u32 ke1) {
  const int lb = blockIdx.x;           // global (l,b) flat index, 0..20479
  const int b = lb & 2047;
  const int d = threadIdx.x;
  const u32 m = ((u32)lb << 8) + (u32)d;
  float mu = out_enc[b * 512 + d];
  float sg = softplus_f(out_enc[b * 512 + 256 + d]);  // +1e-64 underflows in f32
  float e = normal_from_bits(prf32(ke0, ke1, m));
  float zz = mu + sg * e;
  u16 h, mm; split2(zz, h, mm);
  u16* q = z2all + (size_t)lb * 512 + d;
  q[0] = h; q[256] = mm;
  float t1 = -0.5f * e * e - logf(sg);
  float t2 = -0.5f * zz * zz;
#pragma unroll
  for (int o = 32; o; o >>= 1) { t1 += __shfl_down(t1, o); t2 += __shfl_down(t2, o); }
  __shared__ float sm1[4], sm2[4];
  int lane = d & 63, wv = d >> 6;
  if (!lane) { sm1[wv] = t1; sm2[wv] = t2; }
  __syncthreads();
  if (d == 0) {
    float a = sm1[0] + sm1[1] + sm1[2] + sm1[3];
    float qq = sm2[0] + sm2[1] + sm2[2] + sm2[3];
    logq[lb]  = a - 235.2482645003962f;   // 0.5*D*log(2*pi)
    logpz[lb] = qq - 235.2482645003962f;
  }
}

// ------- per-chunk fused: logpxobs (observed list) + t sampling (missing list) -------
__global__ __launch_bounds__(256) void k_post(const float* __restrict__ odec,
                                              const float* __restrict__ data,
                                              const u16* __restrict__ lists,
                                              const int* __restrict__ nmiss,
                                              float* __restrict__ lpxobs,
                                              u16* __restrict__ xms,
                                              int l0, u32 kn0, u32 kn1, u32 kg0, u32 kg1) {
  const int row = blockIdx.x;
  const int lb = l0 * 2048 + row;
  const int b = row & 2047;
  const int tid = threadIdx.x;
  const int nm = nmiss[b];
  __shared__ u32 qk0[1024], qk1[1024];
  __shared__ u16 qp[1024];
  __shared__ int qn;
  __shared__ float sm[4];
  if (tid == 0) qn = 0;
  // ---- part A: logpxobs over observed list (all lanes active, lgamma-free) ----
  const u16* orow = lists + b * 1024 + nm;
  const int no = 1024 - nm;
  float lpsum = 0.0f;
  for (int t = tid; t < no; t += 256) {
    int p = orow[t];
    float mean  = odec[(size_t)row * 3072 + p];
    float scale = softplus_f(odec[(size_t)row * 3072 + 1024 + p]) + 0.001f;
    float dfv   = softplus_f(odec[(size_t)row * 3072 + 2048 + p]) + 3.0f;
    float x = data[b * 1024 + p];
    float y = (x - mean) / scale;
    lpsum += lgamma_half_diff(dfv * 0.5f)
           - 0.5f * logf(dfv * 3.14159274f) - logf(scale)
           - 0.5f * (dfv + 1.0f) * log1pf(y * y / dfv);
  }
#pragma unroll
  for (int o = 32; o; o >>= 1) lpsum += __shfl_down(lpsum, o);
  int lane = tid & 63, wv = tid >> 6;
  if (!lane) sm[wv] = lpsum;
  __syncthreads();                       // sm ready; also publishes qn=0
  if (tid == 0) lpxobs[lb] = sm[0] + sm[1] + sm[2] + sm[3];
  // ---- part B: sampling, retry-compacted (pass 1: one iteration each) ----
  const u16* mr = lists + b * 1024;
  for (int t = tid; t < nm; t += 256) {
    int p = mr[t];
    float mean  = odec[(size_t)row * 3072 + p];
    float scale = softplus_f(odec[(size_t)row * 3072 + 1024 + p]) + 0.001f;
    float dfv   = softplus_f(odec[(size_t)row * 3072 + 2048 + p]) + 3.0f;
    u32 i = ((u32)lb << 10) + (u32)p;
    float n = normal_from_bits(prf32(kn0, kn1, i));
    U2 gk = tf2x32(kg0, kg1, 0u, i);        // split(key_g, N)[i]
    U2 kk = tf2x32(gk.a, gk.b, 0u, 0u);     // boost split (u_boost consumed)
    float half_df = dfv * 0.5f;
    float d = half_df - 0.33333334f;
    float c = 0.33333334f / sqrtf(d);
    GI r = gamma_iter(kk.a, kk.b, d, c);
    if (r.acc) {
      float g = d * r.V;
      xms[i] = f2bf(mean + scale * (n * sqrtf(half_df / g)));
    } else {
      int s = atomicAdd(&qn, 1);
      qk0[s] = r.k0; qk1[s] = r.k1; qp[s] = (u16)p;
    }
  }
  __syncthreads();
  // pass 2: drain the small retry queue (~3% of samples)
  int n2 = qn;
  for (int t = tid; t < n2; t += 256) {
    int p = qp[t];
    float mean  = odec[(size_t)row * 3072 + p];
    float scale = softplus_f(odec[(size_t)row * 3072 + 1024 + p]) + 0.001f;
    float dfv   = softplus_f(odec[(size_t)row * 3072 + 2048 + p]) + 3.0f;
    u32 i = ((u32)lb << 10) + (u32)p;
    float n = normal_from_bits(prf32(kn0, kn1, i));
    float half_df = dfv * 0.5f;
    float d = half_df - 0.33333334f;
    float c = 0.33333334f / sqrtf(d);
    u32 k0 = qk0[t], k1 = qk1[t];
    GI r;
    do { r = gamma_iter(k0, k1, d, c); k0 = r.k0; k1 = r.k1; } while (!r.acc);
    float g = d * r.V;
    xms[i] = f2bf(mean + scale * (n * sqrtf(half_df / g)));
  }
}

// --------------- importance weights: softmax over L=10 ---------------
__global__ __launch_bounds__(256) void k_impw(const float* __restrict__ lpx,
                                              const float* __restrict__ lpz,
                                              const float* __restrict__ lq,
                                              float* __restrict__ w) {
  int b = blockIdx.x * 256 + threadIdx.x;
  float s[10], mx = -INFINITY;
#pragma unroll
  for (int l = 0; l < 10; ++l) {
    s[l] = lpx[l * 2048 + b] + lpz[l * 2048 + b] - lq[l * 2048 + b];
    mx = fmaxf(mx, s[l]);
  }
  float se = 0.0f;
#pragma unroll
  for (int l = 0; l < 10; ++l) { s[l] = expf(s[l] - mx); se += s[l]; }
#pragma unroll
  for (int l = 0; l < 10; ++l) w[l * 2048 + b] = s[l] / se;
}

// ------- xm + data_imputed (+ 2-plane split for classifier input) -------
__global__ __launch_bounds__(256) void k_xm(const int* __restrict__ mask,
                                            const float* __restrict__ data,
                                            const float* __restrict__ impw,
                                            const u16* __restrict__ xms,
                                            u16* __restrict__ imp2,
                                            float* __restrict__ out) {
  int idx = blockIdx.x * 256 + threadIdx.x;
  int b = idx >> 10, p = idx & 1023;
  float o;
  if (mask[idx]) {
    o = data[idx];
  } else {
    float acc = 0.0f;
#pragma unroll
    for (int l = 0; l < 10; ++l)
      acc += impw[l * 2048 + b] * bf2f(xms[((size_t)l * 2048 + b) * 1024 + p]);
    o = acc;
  }
  out[idx] = o;
  u16 h, m; split2(o, h, m);
  u16* q = imp2 + (size_t)b * 2048 + p;
  q[0] = h; q[1024] = m;
}

// --------------- classifier head: logits (N=10) ---------------
__global__ __launch_bounds__(256) void k_cls2(const float* __restrict__ hc,
                                              const float* __restrict__ w2,
                                              const float* __restrict__ b2,
                                              float* __restrict__ out) {
  int b = blockIdx.x, tid = threadIdx.x;
  float acc[10];
#pragma unroll
  for (int c = 0; c < 10; ++c) acc[c] = 0.0f;
  for (int k = tid; k < 2048; k += 256) {
    float h = hc[(size_t)b * 2048 + k];
#pragma unroll
    for (int c = 0; c < 10; ++c) acc[c] = fmaf(h, w2[k * 10 + c], acc[c]);
  }
  __shared__ float red[4][10];
  int lane = tid & 63, wv = tid >> 6;
#pragma unroll
  for (int c = 0; c < 10; ++c) {
    float v = acc[c];
#pragma unroll
    for (int o = 32; o; o >>= 1) v += __shfl_down(v, o);
    if (!lane) red[wv][c] = v;
  }
  __syncthreads();
  if (tid < 10) out[b * 10 + tid] = red[0][tid] + red[1][tid] + red[2][tid] + red[3][tid] + b2[tid];
}

extern "C" void kernel_launch(void* const* d_in, const int* in_sizes, int n_in,
                              void* d_out, int out_size, void* d_ws, size_t ws_size,
                              hipStream_t stream) {
  const float* data   = (const float*)d_in[0];
  const int*   mask   = (const int*)d_in[1];
  const float* enc_w1 = (const float*)d_in[2];
  const float* enc_b1 = (const float*)d_in[3];
  const float* enc_w2 = (const float*)d_in[4];
  const float* enc_b2 = (const float*)d_in[5];
  const float* dec_w1 = (const float*)d_in[6];
  const float* dec_b1 = (const float*)d_in[7];
  const float* dec_w2 = (const float*)d_in[8];
  const float* dec_b2 = (const float*)d_in[9];
  const float* cls_w1 = (const float*)d_in[10];
  const float* cls_b1 = (const float*)d_in[11];
  const float* cls_w2 = (const float*)d_in[12];
  const float* cls_b2 = (const float*)d_in[13];

  float* out = (float*)d_out;   // [2048*1024 data_imputed | 2048*10 logits]
  char* wsb = (char*)d_ws;

  // Round-5 proved ws_size >= 225,771,520. This layout: 207,953,920 B.
  if (ws_size < 207953920ULL) return;

  u16*   xmsu   = (u16*)(wsb + 0);              // [10*2048][1024] bf16  (40 MiB)
  u16*   w_d2   = (u16*)(wsb + 41943040);       // [3072][2*2048]        (24 MiB)
  u16*   w_d1   = (u16*)(wsb + 67108864);       // [2048][2*256]         (2 MiB)
  u16*   hx2    = (u16*)(wsb + 69206016);       // [4096][2*2048]        (32 MiB)
  float* odec   = (float*)(wsb + 102760448);    // [4096][3072] f32      (48 MiB)
  u16*   data2  = (u16*)(wsb + 157286400);      // [2048][2*1024]        (8 MiB)
  u16*   w_ec   = (u16*)(wsb + 165675008);      // w_e1/w_c1 [2048][2*1024] (8 MiB)
  u16*   w_e2   = (u16*)(wsb + 174063616);      // [512][2*2048]         (4 MiB)
  float* logpz  = (float*)(wsb + 178257920);
  float* logq   = (float*)(wsb + 178339840);
  float* lpxobs = (float*)(wsb + 178421760);
  float* impw   = (float*)(wsb + 178503680);
  float* out_enc= (float*)(wsb + 178585600);    // [2048][512] f32       (4 MiB)
  u16*   lists  = (u16*)(wsb + 182779904);      // [2048][1024] u16: miss | obs (4 MiB)
  int*   nmiss  = (int*)(wsb + 186974208);      // [2048] int
  u16*   z2all  = (u16*)(wsb + 186982400);      // [20480][512] u16      (20 MiB)
  float* hc     = odec;    // reuse [2048][2048] f32
  u16*   imp2   = data2;   // reuse

  // key(42)=(0,42); k_eps=PRF(key,0), k_t=PRF(key,1); key_n=PRF(k_t,0), key_g=PRF(k_t,1)
  U2 ke = tf2x32(0u, 42u, 0u, 0u);
  U2 kt = tf2x32(0u, 42u, 0u, 1u);
  U2 kn = tf2x32(kt.a, kt.b, 0u, 0u);
  U2 kg = tf2x32(kt.a, kt.b, 0u, 1u);

  dim3 blk(256);
  // conversions + mask compaction
  k_aconv<<<8192, blk, 0, stream>>>(data, data2, 2097152, 10);
  k_wconv<<<dim3(32, 16), blk, 0, stream>>>(enc_w1, w_ec, 1024, 2048);
  k_wconv<<<dim3(8, 32),  blk, 0, stream>>>(enc_w2, w_e2, 2048, 512);
  k_wconv<<<dim3(48, 32), blk, 0, stream>>>(dec_w2, w_d2, 2048, 3072);
  k_wconv<<<dim3(32, 4),  blk, 0, stream>>>(dec_w1, w_d1, 256, 2048);
  k_build<<<2048, blk, 0, stream>>>(mask, lists, nmiss);

  // encoder
  gemm_s3<true,  true,  false><<<dim3(16, 16), blk, 0, stream>>>(data2, w_ec, enc_b1, nullptr, hx2, 2048, 10);
  gemm_s3<false, false, false><<<dim3(4, 16),  blk, 0, stream>>>(hx2, w_e2, enc_b2, out_enc, nullptr, 512, 11);

  // all eps/z + logpz/logq in one launch
  k_eps_z<<<20480, blk, 0, stream>>>(out_enc, z2all, logpz, logq, ke.a, ke.b);

  // decoder: 2 l-chunks (M = 4096) per iteration
  for (int l0 = 0; l0 < 10; l0 += 2) {
    gemm_s3<true,  true,  false><<<dim3(16, 32), blk, 0, stream>>>(z2all + (size_t)l0 * 2048 * 512, w_d1, dec_b1, nullptr, hx2, 2048, 8);
    gemm_s3<false, false, true ><<<dim3(24, 32), blk, 0, stream>>>(hx2, w_d2, dec_b2, odec, nullptr, 3072, 11);
    k_post<<<4096, blk, 0, stream>>>(odec, data, lists, nmiss, lpxobs, xmsu, l0, kn.a, kn.b, kg.a, kg.b);
  }

  // importance weights + imputation
  k_impw<<<8, blk, 0, stream>>>(lpxobs, logpz, logq, impw);
  k_xm<<<8192, blk, 0, stream>>>(mask, data, impw, xmsu, imp2, out);

  // classifier (re-convert cls_w1 into w_ec slot)
  k_wconv<<<dim3(32, 16), blk, 0, stream>>>(cls_w1, w_ec, 1024, 2048);
  gemm_s3<true, false, false><<<dim3(16, 16), blk, 0, stream>>>(imp2, w_ec, cls_b1, hc, nullptr, 2048, 10);
  k_cls2<<<2048, blk, 0, stream>>>(hc, cls_w2, cls_b2, out + 2048 * 1024);
}

// Round 10
// 1785.651 us; speedup vs baseline: 2.8536x; 1.0322x over previous
//
#include <hip/hip_runtime.h>
#include <math.h>

typedef unsigned int u32;
typedef unsigned short u16;
typedef __attribute__((ext_vector_type(8))) short bf16x8;
typedef __attribute__((ext_vector_type(16))) float f32x16;

struct U2 { u32 a, b; };

// Threefry-2x32, 20 rounds — matches jax._src.prng.threefry2x32 exactly.
__host__ __device__ __forceinline__ U2 tf2x32(u32 k0, u32 k1, u32 c0, u32 c1) {
  u32 ks2 = k0 ^ k1 ^ 0x1BD11BDAu;
  u32 x0 = c0 + k0, x1 = c1 + k1;
#define TFR(r) { x0 += x1; x1 = (x1 << (r)) | (x1 >> (32 - (r))); x1 ^= x0; }
  TFR(13) TFR(15) TFR(26) TFR(6)
  x0 += k1; x1 += ks2 + 1u;
  TFR(17) TFR(29) TFR(16) TFR(24)
  x0 += ks2; x1 += k0 + 2u;
  TFR(13) TFR(15) TFR(26) TFR(6)
  x0 += k0; x1 += k1 + 3u;
  TFR(17) TFR(29) TFR(16) TFR(24)
  x0 += k1; x1 += ks2 + 4u;
  TFR(13) TFR(15) TFR(26) TFR(6)
  x0 += ks2; x1 += k0 + 5u;
#undef TFR
  return {x0, x1};
}

// jax_threefry_partitionable=True:
// random_bits(key,32,shape)[i] = b1^b2 at counter (0,i); split(key,n)[i] = pair at counter i.
__host__ __device__ __forceinline__ u32 prf32(u32 k0, u32 k1, u32 i) {
  U2 r = tf2x32(k0, k1, 0u, i);
  return r.a ^ r.b;
}

__device__ __forceinline__ float u01_from_bits(u32 bits) {
  u32 r = (bits >> 9) | 0x3f800000u;
  return __uint_as_float(r) - 1.0f;
}

// XLA ErfInv f32 (Giles polynomial)
__device__ __forceinline__ float erfinv_f32(float x) {
  float w = -log1pf(-x * x);
  float p;
  if (w < 5.0f) {
    w -= 2.5f;
    p = 2.81022636e-08f;
    p = fmaf(p, w, 3.43273939e-07f);
    p = fmaf(p, w, -3.5233877e-06f);
    p = fmaf(p, w, -4.39150654e-06f);
    p = fmaf(p, w, 0.00021858087f);
    p = fmaf(p, w, -0.00125372503f);
    p = fmaf(p, w, -0.00417768164f);
    p = fmaf(p, w, 0.246640727f);
    p = fmaf(p, w, 1.50140941f);
  } else {
    w = sqrtf(w) - 3.0f;
    p = -0.000200214257f;
    p = fmaf(p, w, 0.000100950558f);
    p = fmaf(p, w, 0.00134934322f);
    p = fmaf(p, w, -0.00367342844f);
    p = fmaf(p, w, 0.00573950773f);
    p = fmaf(p, w, -0.0076224613f);
    p = fmaf(p, w, 0.00943887047f);
    p = fmaf(p, w, 1.00167406f);
    p = fmaf(p, w, 2.83297682f);
  }
  return p * x;
}

__device__ __forceinline__ float normal_from_bits(u32 bits) {
  const float lo = -0.99999994f;
  float u = u01_from_bits(bits) * 2.0f + lo;
  u = fmaxf(lo, u);
  return 1.41421356237f * erfinv_f32(u);
}

__device__ __forceinline__ float softplus_f(float x) {
  return fmaxf(x, 0.0f) + log1pf(expf(-fabsf(x)));
}

// One outer iteration of jax.random._gamma_one's rejection loop (exact op order).
struct GI { bool acc; float V; u32 k0, k1; };
__device__ __forceinline__ GI gamma_iter(u32 k0, u32 k1, float d, float c) {
  U2 nk = tf2x32(k0, k1, 0u, 0u);
  U2 xk = tf2x32(k0, k1, 0u, 1u);
  U2 uk = tf2x32(k0, k1, 0u, 2u);
  u32 xk0 = xk.a, xk1 = xk.b;
  float x, v;
  do {
    U2 nxt = tf2x32(xk0, xk1, 0u, 0u);
    U2 sub = tf2x32(xk0, xk1, 0u, 1u);
    xk0 = nxt.a; xk1 = nxt.b;
    x = normal_from_bits(prf32(sub.a, sub.b, 0u));
    v = 1.0f + x * c;
  } while (v <= 0.0f);
  float X = x * x;
  float V = (v * v) * v;
  float U = u01_from_bits(prf32(uk.a, uk.b, 0u));
  bool cont = (U >= 1.0f - 0.0331f * (X * X)) &&
              (logf(U) >= 0.5f * X + d * ((1.0f - V) + logf(V)));
  GI r; r.acc = !cont; r.V = V; r.k0 = nk.a; r.k1 = nk.b;
  return r;
}

// lnGamma(x+0.5) - lnGamma(x), x >= 1.5: three exact recurrence pushes + Stirling.
// abs error <= ~1.5e-5; common-mode across l in the softmax.
__device__ __forceinline__ float lgamma_half_diff(float x) {
  float z = x + 3.0f;
  float num = x * (x + 1.0f) * (x + 2.0f);
  float den = (x + 0.5f) * (x + 1.5f) * (x + 2.5f);
  float zh = z + 0.5f;
  float iz = 1.0f / z, izh = 1.0f / zh;
  float corr = 0.0833333333f * (izh - iz)
             - 0.00277777778f * (izh * izh * izh - iz * iz * iz);
  return logf(num / den) + 0.5f * logf(z) + z * log1pf(0.5f * iz) - 0.5f + corr;
}

// ---------------- bf16 split-2 helpers ----------------
__device__ __forceinline__ u16 f2bf(float f) {
  u32 u = __float_as_uint(f);
  u32 r = ((u >> 16) & 1u) + 0x7fffu;
  return (u16)((u + r) >> 16);
}
__device__ __forceinline__ float bf2f(u16 h) { return __uint_as_float(((u32)h) << 16); }

__device__ __forceinline__ void split2(float v, u16& h, u16& m) {
  h = f2bf(v);
  m = f2bf(v - bf2f(h));   // residual exact; |v-h-m| <= 2^-18 |v|
}

#define GLOAD16(gp, lp) __builtin_amdgcn_global_load_lds( \
    (const __attribute__((address_space(1))) void*)(gp),  \
    (__attribute__((address_space(3))) void*)(lp), 16, 0, 0)

// ---------------- split-2 bf16 MFMA GEMM (slot-major planes) ----------------
// A2 [M][2K] rm (planes h|m), B2T [N][2K] rm (planes h|m), bias[N] f32.
// Virtual K3=3K; slot s = vk/K: pa = s>>1 {h,h,m}, pb = s&1 {h,m,h}.
// 128x128 tile, BK=64, 4 waves, 32x32x16 bf16 MFMA, XOR-swizzled LDS (T2).
// SWZ: XCD-chunked blockIdx remap (nwg % 8 == 0 required).
// PARTIAL: split-K — blockIdx.z computes k-tiles [z*tpp, (z+1)*tpp), writes raw
// f32 partial at Cf + z*M*N (no bias/relu/split); k_red combines.
template<bool RELU, bool SIX, bool SWZ, bool PARTIAL>
__global__ __launch_bounds__(256, 4) void gemm_s3(const u16* __restrict__ A2,
                                                  const u16* __restrict__ B2T,
                                                  const float* __restrict__ bias,
                                                  float* __restrict__ Cf,
                                                  u16* __restrict__ C2,
                                                  int N, int kbits, int tpp) {
  __shared__ u16 As[128 * 64];
  __shared__ u16 Bs[128 * 64];
  const int tid = threadIdx.x;
  const int l = tid & 63, w = tid >> 6;
  int bx = blockIdx.x, by = blockIdx.y;
  if (SWZ) {
    int nx = gridDim.x;
    int wg = by * nx + bx;
    int per = (nx * gridDim.y) >> 3;       // blocks per XCD
    int sw = (wg & 7) * per + (wg >> 3);   // bijective when nwg%8==0
    bx = sw % nx; by = sw / nx;
  }
  const int m0 = by * 128, n0 = bx * 128;
  const int K2 = 2 << kbits;
  // staging: per-lane inverse-swizzled source column (16B blocks)
  const int srow = l >> 3;
  const int scol = ((l & 7) ^ srow) << 3;
  const u16* agr[4]; const u16* bgr[4]; u16* al[4]; u16* bl[4];
#pragma unroll
  for (int j = 0; j < 4; ++j) {
    int r = w * 32 + j * 8 + srow;
    agr[j] = A2 + (size_t)(m0 + r) * K2 + scol;
    bgr[j] = B2T + (size_t)(n0 + r) * K2 + scol;
    al[j] = &As[(w * 4 + j) * 512];
    bl[j] = &Bs[(w * 4 + j) * 512];
  }
  f32x16 acc[2][2] = {};
  const int fr = l & 31;
  const int wm = w >> 1, wn = w & 1;
  const int swz = (l & 7) << 4;
  const int hk16 = (l >> 5) << 4;
  int kt0 = 0, ktend = 3 << (kbits - 6);
  float* CfW = Cf;
  if (PARTIAL) {
    kt0 = blockIdx.z * tpp;
    ktend = kt0 + tpp;
    CfW = Cf + (size_t)blockIdx.z * ((size_t)gridDim.y * 128) * N;
  }
  const int kmask = (1 << kbits) - 1;
  for (int kt = kt0; kt < ktend; ++kt) {
    int vb = kt << 6;
    int s = vb >> kbits;       // 0,1,2
    int ko = vb & kmask;
    int ao = ((s >> 1) << kbits) + ko;   // A plane {h,h,m}
    int bo = ((s & 1) << kbits) + ko;    // B plane {h,m,h}
    __syncthreads();   // previous tile consumed
#pragma unroll
    for (int j = 0; j < 4; ++j) {
      GLOAD16(agr[j] + ao, al[j]);
      GLOAD16(bgr[j] + bo, bl[j]);
    }
    __syncthreads();   // compiler drains vmcnt(0) before barrier: tile ready
#pragma unroll
    for (int ks = 0; ks < 4; ++ks) {
      bf16x8 af[2], bf[2];
#pragma unroll
      for (int mi = 0; mi < 2; ++mi) {
        int ar = wm * 64 + mi * 32 + fr;
        af[mi] = *(const bf16x8*)((const char*)As + ar * 128 + ((ks * 32 + hk16) ^ swz));
      }
#pragma unroll
      for (int ni = 0; ni < 2; ++ni) {
        int br = wn * 64 + ni * 32 + fr;
        bf[ni] = *(const bf16x8*)((const char*)Bs + br * 128 + ((ks * 32 + hk16) ^ swz));
      }
#pragma unroll
      for (int mi = 0; mi < 2; ++mi)
#pragma unroll
        for (int ni = 0; ni < 2; ++ni)
          acc[mi][ni] = __builtin_amdgcn_mfma_f32_32x32x16_bf16(af[mi], bf[ni], acc[mi][ni], 0, 0, 0);
    }
  }
  // epilogue: C/D layout col=lane&31, row=(r&3)+8*(r>>2)+4*(lane>>5)
#pragma unroll
  for (int mi = 0; mi < 2; ++mi)
#pragma unroll
  for (int ni = 0; ni < 2; ++ni) {
    int gcol = n0 + wn * 64 + ni * 32 + fr;
    float bsv = PARTIAL ? 0.0f : bias[gcol];
#pragma unroll
    for (int r = 0; r < 16; ++r) {
      int grow = m0 + wm * 64 + mi * 32 + (r & 3) + 8 * (r >> 2) + 4 * (l >> 5);
      float v = acc[mi][ni][r] + bsv;
      if (RELU) v = fmaxf(v, 0.0f);
      if (PARTIAL || !SIX) {
        CfW[(size_t)grow * N + gcol] = v;
      } else {
        u16 h, mm; split2(v, h, mm);
        u16* q = C2 + (size_t)grow * 2 * N + gcol;
        q[0] = h; q[N] = mm;
      }
    }
  }
}

// -------- split-K reduce: sum NP partials + bias, relu, write f32 or split-2 --------
template<bool RELU, bool SIX>
__global__ __launch_bounds__(256) void k_red(const float* __restrict__ P, int NP,
                                             size_t pstride, const float* __restrict__ bias,
                                             float* __restrict__ Cf, u16* __restrict__ C2,
                                             int nbits) {
  int idx = blockIdx.x * 256 + threadIdx.x;
  int N = 1 << nbits;
  int row = idx >> nbits, col = idx & (N - 1);
  float v = 0.0f;
  for (int p = 0; p < NP; ++p) v += P[(size_t)p * pstride + idx];
  v += bias[col];
  if (RELU) v = fmaxf(v, 0.0f);
  if (!SIX) {
    Cf[idx] = v;
  } else {
    u16 h, m; split2(v, h, m);
    C2[(size_t)row * 2 * N + col] = h;
    C2[(size_t)row * 2 * N + N + col] = m;
  }
}

// -------- weight conversion: W [K][N] f32 -> W2T [N][2K] bf16 planes --------
__global__ __launch_bounds__(256) void k_wconv(const float* __restrict__ W, u16* __restrict__ W2T,
                                               int K, int N) {
  __shared__ float t[64][65];
  const int k0 = blockIdx.y * 64, n0 = blockIdx.x * 64;
  const int tid = threadIdx.x;
  for (int i = tid; i < 4096; i += 256) {
    int kk = i >> 6, nn = i & 63;
    t[kk][nn] = W[(size_t)(k0 + kk) * N + (n0 + nn)];
  }
  __syncthreads();
  const int nn = tid >> 2, kc = (tid & 3) << 4;
  u16* base = W2T + (size_t)(n0 + nn) * 2 * K + (k0 + kc);
#pragma unroll
  for (int kk = 0; kk < 16; ++kk) {
    u16 h, m; split2(t[kc + kk][nn], h, m);
    base[kk] = h; base[K + kk] = m;
  }
}

// -------- activation conversion: X [rows][K] f32 -> X2 [rows][2K] planes --------
__global__ __launch_bounds__(256) void k_aconv(const float* __restrict__ X, u16* __restrict__ X2,
                                               int total, int kbits) {
  int i = blockIdx.x * 256 + threadIdx.x;
  if (i >= total) return;
  int K = 1 << kbits;
  int r = i >> kbits, k = i & (K - 1);
  u16 h, m; split2(X[i], h, m);
  u16* q = X2 + ((size_t)r * 2 << kbits) + k;
  q[0] = h; q[K] = m;
}

// -------- build per-row lists: missing p ascending at [0,nm), observed ascending at [nm,1024) --------
__global__ __launch_bounds__(256) void k_build(const int* __restrict__ mask,
                                               u16* __restrict__ lists,
                                               int* __restrict__ nmiss) {
  const int b = blockIdx.x, tid = threadIdx.x;
  const int* mrow = mask + b * 1024;
  const int pb = tid * 4;
  int m0 = (mrow[pb] == 0), m1 = (mrow[pb + 1] == 0),
      m2 = (mrow[pb + 2] == 0), m3 = (mrow[pb + 3] == 0);
  int cnt = m0 + m1 + m2 + m3;
  __shared__ int sc[256];
  sc[tid] = cnt;
  __syncthreads();
  for (int off = 1; off < 256; off <<= 1) {
    int v = 0;
    if (tid >= off) v = sc[tid - off];
    __syncthreads();
    sc[tid] += v;
    __syncthreads();
  }
  int pos = sc[tid] - cnt;        // exclusive miss prefix
  int nmT = sc[255];              // total missing in row
  u16* lr = lists + b * 1024;
  int mpos = pos;
  int opos = nmT + (pb - pos);    // observed exclusive prefix = pb - pos
  if (m0) lr[mpos++] = (u16)pb;       else lr[opos++] = (u16)pb;
  if (m1) lr[mpos++] = (u16)(pb + 1); else lr[opos++] = (u16)(pb + 1);
  if (m2) lr[mpos++] = (u16)(pb + 2); else lr[opos++] = (u16)(pb + 2);
  if (m3) lr[mpos++] = (u16)(pb + 3); else lr[opos++] = (u16)(pb + 3);
  if (tid == 255) nmiss[b] = nmT;
}

// ------- eps/z: wave-per-row, 4 rows per 256-thread block, in-wave reduce -------
__global__ __launch_bounds__(256) void k_eps_z(const float* __restrict__ out_enc,
                                               u16* __restrict__ z2all,
                                               float* __restrict__ logpz,
                                               float* __restrict__ logq,
                                               u32 ke0, u32 ke1) {
  const int lb = blockIdx.x * 4 + (threadIdx.x >> 6);   // row 0..20479
  const int lane = threadIdx.x & 63;
  const int b = lb & 2047;
  float t1 = 0.0f, t2 = 0.0f;
  u16* zrow = z2all + (size_t)lb * 512;
#pragma unroll
  for (int j = 0; j < 4; ++j) {
    int d = lane + j * 64;
    u32 m = ((u32)lb << 8) + (u32)d;
    float mu = out_enc[b * 512 + d];
    float sg = softplus_f(out_enc[b * 512 + 256 + d]);  // +1e-64 underflows in f32
    float e = normal_from_bits(prf32(ke0, ke1, m));
    float zz = mu + sg * e;
    u16 h, mm; split2(zz, h, mm);
    zrow[d] = h; zrow[256 + d] = mm;
    t1 += -0.5f * e * e - logf(sg);
    t2 += -0.5f * zz * zz;
  }
#pragma unroll
  for (int o = 32; o; o >>= 1) { t1 += __shfl_down(t1, o); t2 += __shfl_down(t2, o); }
  if (lane == 0) {
    logq[lb]  = t1 - 235.2482645003962f;   // 0.5*D*log(2*pi)
    logpz[lb] = t2 - 235.2482645003962f;
  }
}

// ------- per-chunk fused: logpxobs (observed list) + t sampling (missing list) -------
__global__ __launch_bounds__(256) void k_post(const float* __restrict__ odec,
                                              const float* __restrict__ data,
                                              const u16* __restrict__ lists,
                                              const int* __restrict__ nmiss,
                                              float* __restrict__ lpxobs,
                                              u16* __restrict__ xms,
                                              int l0, u32 kn0, u32 kn1, u32 kg0, u32 kg1) {
  const int row = blockIdx.x;
  const int lb = l0 * 2048 + row;
  const int b = row & 2047;
  const int tid = threadIdx.x;
  const int nm = nmiss[b];
  __shared__ u32 qk0[1024], qk1[1024];
  __shared__ u16 qp[1024];
  __shared__ int qn;
  __shared__ float sm[4];
  if (tid == 0) qn = 0;
  // ---- part A: logpxobs over observed list (all lanes active, lgamma-free) ----
  const u16* orow = lists + b * 1024 + nm;
  const int no = 1024 - nm;
  float lpsum = 0.0f;
  for (int t = tid; t < no; t += 256) {
    int p = orow[t];
    float mean  = odec[(size_t)row * 3072 + p];
    float scale = softplus_f(odec[(size_t)row * 3072 + 1024 + p]) + 0.001f;
    float dfv   = softplus_f(odec[(size_t)row * 3072 + 2048 + p]) + 3.0f;
    float x = data[b * 1024 + p];
    float y = (x - mean) / scale;
    lpsum += lgamma_half_diff(dfv * 0.5f)
           - 0.5f * logf(dfv * 3.14159274f) - logf(scale)
           - 0.5f * (dfv + 1.0f) * log1pf(y * y / dfv);
  }
#pragma unroll
  for (int o = 32; o; o >>= 1) lpsum += __shfl_down(lpsum, o);
  int lane = tid & 63, wv = tid >> 6;
  if (!lane) sm[wv] = lpsum;
  __syncthreads();                       // sm ready; also publishes qn=0
  if (tid == 0) lpxobs[lb] = sm[0] + sm[1] + sm[2] + sm[3];
  // ---- part B: sampling, retry-compacted (pass 1: one iteration each) ----
  const u16* mr = lists + b * 1024;
  for (int t = tid; t < nm; t += 256) {
    int p = mr[t];
    float mean  = odec[(size_t)row * 3072 + p];
    float scale = softplus_f(odec[(size_t)row * 3072 + 1024 + p]) + 0.001f;
    float dfv   = softplus_f(odec[(size_t)row * 3072 + 2048 + p]) + 3.0f;
    u32 i = ((u32)lb << 10) + (u32)p;
    float n = normal_from_bits(prf32(kn0, kn1, i));
    U2 gk = tf2x32(kg0, kg1, 0u, i);        // split(key_g, N)[i]
    U2 kk = tf2x32(gk.a, gk.b, 0u, 0u);     // boost split (u_boost consumed)
    float half_df = dfv * 0.5f;
    float d = half_df - 0.33333334f;
    float c = 0.33333334f / sqrtf(d);
    GI r = gamma_iter(kk.a, kk.b, d, c);
    if (r.acc) {
      float g = d * r.V;
      xms[i] = f2bf(mean + scale * (n * sqrtf(half_df / g)));
    } else {
      int s = atomicAdd(&qn, 1);
      qk0[s] = r.k0; qk1[s] = r.k1; qp[s] = (u16)p;
    }
  }
  __syncthreads();
  // pass 2: drain the small retry queue (~3% of samples)
  int n2 = qn;
  for (int t = tid; t < n2; t += 256) {
    int p = qp[t];
    float mean  = odec[(size_t)row * 3072 + p];
    float scale = softplus_f(odec[(size_t)row * 3072 + 1024 + p]) + 0.001f;
    float dfv   = softplus_f(odec[(size_t)row * 3072 + 2048 + p]) + 3.0f;
    u32 i = ((u32)lb << 10) + (u32)p;
    float n = normal_from_bits(prf32(kn0, kn1, i));
    float half_df = dfv * 0.5f;
    float d = half_df - 0.33333334f;
    float c = 0.33333334f / sqrtf(d);
    u32 k0 = qk0[t], k1 = qk1[t];
    GI r;
    do { r = gamma_iter(k0, k1, d, c); k0 = r.k0; k1 = r.k1; } while (!r.acc);
    float g = d * r.V;
    xms[i] = f2bf(mean + scale * (n * sqrtf(half_df / g)));
  }
}

// --------------- importance weights: softmax over L=10 ---------------
__global__ __launch_bounds__(256) void k_impw(const float* __restrict__ lpx,
                                              const float* __restrict__ lpz,
                                              const float* __restrict__ lq,
                                              float* __restrict__ w) {
  int b = blockIdx.x * 256 + threadIdx.x;
  float s[10], mx = -INFINITY;
#pragma unroll
  for (int l = 0; l < 10; ++l) {
    s[l] = lpx[l * 2048 + b] + lpz[l * 2048 + b] - lq[l * 2048 + b];
    mx = fmaxf(mx, s[l]);
  }
  float se = 0.0f;
#pragma unroll
  for (int l = 0; l < 10; ++l) { s[l] = expf(s[l] - mx); se += s[l]; }
#pragma unroll
  for (int l = 0; l < 10; ++l) w[l * 2048 + b] = s[l] / se;
}

// ------- xm + data_imputed (+ 2-plane split for classifier input) -------
__global__ __launch_bounds__(256) void k_xm(const int* __restrict__ mask,
                                            const float* __restrict__ data,
                                            const float* __restrict__ impw,
                                            const u16* __restrict__ xms,
                                            u16* __restrict__ imp2,
                                            float* __restrict__ out) {
  int idx = blockIdx.x * 256 + threadIdx.x;
  int b = idx >> 10, p = idx & 1023;
  float o;
  if (mask[idx]) {
    o = data[idx];
  } else {
    float acc = 0.0f;
#pragma unroll
    for (int l = 0; l < 10; ++l)
      acc += impw[l * 2048 + b] * bf2f(xms[((size_t)l * 2048 + b) * 1024 + p]);
    o = acc;
  }
  out[idx] = o;
  u16 h, m; split2(o, h, m);
  u16* q = imp2 + (size_t)b * 2048 + p;
  q[0] = h; q[1024] = m;
}

// --------------- classifier head: logits (N=10) ---------------
__global__ __launch_bounds__(256) void k_cls2(const float* __restrict__ hc,
                                              const float* __restrict__ w2,
                                              const float* __restrict__ b2,
                                              float* __restrict__ out) {
  int b = blockIdx.x, tid = threadIdx.x;
  float acc[10];
#pragma unroll
  for (int c = 0; c < 10; ++c) acc[c] = 0.0f;
  for (int k = tid; k < 2048; k += 256) {
    float h = hc[(size_t)b * 2048 + k];
#pragma unroll
    for (int c = 0; c < 10; ++c) acc[c] = fmaf(h, w2[k * 10 + c], acc[c]);
  }
  __shared__ float red[4][10];
  int lane = tid & 63, wv = tid >> 6;
#pragma unroll
  for (int c = 0; c < 10; ++c) {
    float v = acc[c];
#pragma unroll
    for (int o = 32; o; o >>= 1) v += __shfl_down(v, o);
    if (!lane) red[wv][c] = v;
  }
  __syncthreads();
  if (tid < 10) out[b * 10 + tid] = red[0][tid] + red[1][tid] + red[2][tid] + red[3][tid] + b2[tid];
}

extern "C" void kernel_launch(void* const* d_in, const int* in_sizes, int n_in,
                              void* d_out, int out_size, void* d_ws, size_t ws_size,
                              hipStream_t stream) {
  const float* data   = (const float*)d_in[0];
  const int*   mask   = (const int*)d_in[1];
  const float* enc_w1 = (const float*)d_in[2];
  const float* enc_b1 = (const float*)d_in[3];
  const float* enc_w2 = (const float*)d_in[4];
  const float* enc_b2 = (const float*)d_in[5];
  const float* dec_w1 = (const float*)d_in[6];
  const float* dec_b1 = (const float*)d_in[7];
  const float* dec_w2 = (const float*)d_in[8];
  const float* dec_b2 = (const float*)d_in[9];
  const float* cls_w1 = (const float*)d_in[10];
  const float* cls_b1 = (const float*)d_in[11];
  const float* cls_w2 = (const float*)d_in[12];
  const float* cls_b2 = (const float*)d_in[13];

  float* out = (float*)d_out;   // [2048*1024 data_imputed | 2048*10 logits]
  char* wsb = (char*)d_ws;

  // Round-5 proved ws_size >= 225,771,520. This layout: 207,953,920 B.
  if (ws_size < 207953920ULL) return;

  u16*   xmsu   = (u16*)(wsb + 0);              // [10*2048][1024] bf16  (40 MiB)
  u16*   w_d2   = (u16*)(wsb + 41943040);       // [3072][2*2048]        (24 MiB)
  u16*   w_d1   = (u16*)(wsb + 67108864);       // [2048][2*256]         (2 MiB)
  u16*   hx2    = (u16*)(wsb + 69206016);       // [4096][2*2048]        (32 MiB)
  float* odec   = (float*)(wsb + 102760448);    // [4096][3072] f32      (48 MiB)
  u16*   data2  = (u16*)(wsb + 157286400);      // [2048][2*1024]        (8 MiB)
  u16*   w_ec   = (u16*)(wsb + 165675008);      // w_e1/w_c1 [2048][2*1024] (8 MiB)
  u16*   w_e2   = (u16*)(wsb + 174063616);      // [512][2*2048]         (4 MiB)
  float* logpz  = (float*)(wsb + 178257920);
  float* logq   = (float*)(wsb + 178339840);
  float* lpxobs = (float*)(wsb + 178421760);
  float* impw   = (float*)(wsb + 178503680);
  float* out_enc= (float*)(wsb + 178585600);    // [2048][512] f32       (4 MiB)
  u16*   lists  = (u16*)(wsb + 182779904);      // [2048][1024] u16: miss | obs (4 MiB)
  int*   nmiss  = (int*)(wsb + 186974208);      // [2048] int
  u16*   z2all  = (u16*)(wsb + 186982400);      // [20480][512] u16      (20 MiB)
  float* hc     = odec;    // reuse [2048][2048] f32
  u16*   imp2   = data2;   // reuse
  // split-K partial overlays (each dead-region at time of use):
  float* penc1  = odec;                         // 3 x [2048][2048] f32 = 48 MiB (odec dead pre-decoder)
  float* penc2  = (float*)z2all;                // 4 x [2048][512]  f32 = 16 MiB (z2all written later)
  float* pcls   = (float*)wsb;                  // 3 x [2048][2048] f32 = 48 MiB (xmsu/w_d2 dead post-k_xm)

  // key(42)=(0,42); k_eps=PRF(key,0), k_t=PRF(key,1); key_n=PRF(k_t,0), key_g=PRF(k_t,1)
  U2 ke = tf2x32(0u, 42u, 0u, 0u);
  U2 kt = tf2x32(0u, 42u, 0u, 1u);
  U2 kn = tf2x32(kt.a, kt.b, 0u, 0u);
  U2 kg = tf2x32(kt.a, kt.b, 0u, 1u);

  dim3 blk(256);
  // conversions + mask compaction
  k_aconv<<<8192, blk, 0, stream>>>(data, data2, 2097152, 10);
  k_wconv<<<dim3(32, 16), blk, 0, stream>>>(enc_w1, w_ec, 1024, 2048);
  k_wconv<<<dim3(8, 32),  blk, 0, stream>>>(enc_w2, w_e2, 2048, 512);
  k_wconv<<<dim3(48, 32), blk, 0, stream>>>(dec_w2, w_d2, 2048, 3072);
  k_wconv<<<dim3(32, 4),  blk, 0, stream>>>(dec_w1, w_d1, 256, 2048);
  k_build<<<2048, blk, 0, stream>>>(mask, lists, nmiss);

  // encoder (split-K: enc1 3 parts of 16 k-tiles; enc2 4 parts of 24 k-tiles)
  gemm_s3<false, false, false, true><<<dim3(16, 16, 3), blk, 0, stream>>>(data2, w_ec, enc_b1, penc1, nullptr, 2048, 10, 16);
  k_red<true, true><<<16384, blk, 0, stream>>>(penc1, 3, (size_t)2048 * 2048, enc_b1, nullptr, hx2, 11);
  gemm_s3<false, false, false, true><<<dim3(4, 16, 4), blk, 0, stream>>>(hx2, w_e2, enc_b2, penc2, nullptr, 512, 11, 24);
  k_red<false, false><<<4096, blk, 0, stream>>>(penc2, 4, (size_t)2048 * 512, enc_b2, out_enc, nullptr, 9);

  // all eps/z + logpz/logq (wave-per-row, 4 rows/block)
  k_eps_z<<<5120, blk, 0, stream>>>(out_enc, z2all, logpz, logq, ke.a, ke.b);

  // decoder: 2 l-chunks (M = 4096) per iteration
  for (int l0 = 0; l0 < 10; l0 += 2) {
    gemm_s3<true,  true,  false, false><<<dim3(16, 32), blk, 0, stream>>>(z2all + (size_t)l0 * 2048 * 512, w_d1, dec_b1, nullptr, hx2, 2048, 8, 0);
    gemm_s3<false, false, true,  false><<<dim3(24, 32), blk, 0, stream>>>(hx2, w_d2, dec_b2, odec, nullptr, 3072, 11, 0);
    k_post<<<4096, blk, 0, stream>>>(odec, data, lists, nmiss, lpxobs, xmsu, l0, kn.a, kn.b, kg.a, kg.b);
  }

  // importance weights + imputation
  k_impw<<<8, blk, 0, stream>>>(lpxobs, logpz, logq, impw);
  k_xm<<<8192, blk, 0, stream>>>(mask, data, impw, xmsu, imp2, out);

  // classifier (split-K: 3 parts; partials overlay xmsu/w_d2, dead now)
  k_wconv<<<dim3(32, 16), blk, 0, stream>>>(cls_w1, w_ec, 1024, 2048);
  gemm_s3<false, false, false, true><<<dim3(16, 16, 3), blk, 0, stream>>>(imp2, w_ec, cls_b1, pcls, nullptr, 2048, 10, 16);
  k_red<true, false><<<16384, blk, 0, stream>>>(pcls, 3, (size_t)2048 * 2048, cls_b1, hc, nullptr, 11);
  k_cls2<<<2048, blk, 0, stream>>>(hc, cls_w2, cls_b2, out + 2048 * 1024);
}